// Round 1
// baseline (1767.663 us; speedup 1.0000x reference)
//
#include <hip/hip_runtime.h>
#include <math.h>

#define T_LEN 215
#define B_N   128
#define DINP  36
#define GCH   860
#define D_TR  160
#define HD    40
#define D_FIN 196
#define TKB   128

// ---------------- small fused kernels ----------------

__global__ __launch_bounds__(256) void k_emb(const float* __restrict__ st,
    const float* __restrict__ ew, const float* __restrict__ eb, float* __restrict__ emb) {
  int idx = blockIdx.x * 256 + threadIdx.x;
  if (idx >= B_N * DINP) return;
  int b = idx / DINP, i = idx % DINP;
  float s = eb[i];
  #pragma unroll
  for (int k = 0; k < 9; k++) s = fmaf(st[b * 9 + k], ew[i * 9 + k], s);
  emb[idx] = s;
}

__global__ __launch_bounds__(256) void k_pe(const float* __restrict__ times, float* __restrict__ pe) {
  int idx = blockIdx.x * 256 + threadIdx.x;
  if (idx >= T_LEN * B_N) return;
  float tm = times[idx];
  #pragma unroll
  for (int k = 0; k < 8; k++) {
    float ts = powf(215.0f, (float)k * (1.0f / 7.0f));
    float sc = tm / ts;
    pe[(size_t)idx * 16 + k]     = sinf(sc);
    pe[(size_t)idx * 16 + 8 + k] = cosf(sc);
  }
}

// xb[b,i,4t+j] = relu(src[t,b,i] * R_u[4i+j])
__global__ __launch_bounds__(256) void k_xb(const float* __restrict__ src,
    const float* __restrict__ R_u, float* __restrict__ xb) {
  int idx = blockIdx.x * 256 + threadIdx.x;
  if (idx >= B_N * DINP * T_LEN) return;
  int t = idx % T_LEN;
  int i = (idx / T_LEN) % DINP;
  int b = idx / (T_LEN * DINP);
  float v = src[((size_t)t * B_N + b) * 72 + i];
  float4 r = ((const float4*)R_u)[i];
  float4 o;
  o.x = fmaxf(v * r.x, 0.f); o.y = fmaxf(v * r.y, 0.f);
  o.z = fmaxf(v * r.z, 0.f); o.w = fmaxf(v * r.w, 0.f);
  ((float4*)(xb + ((size_t)b * DINP + i) * GCH))[t] = o;
}

// s1[b,n] = (1/36) sum_i V1[b*36+i, n]
__global__ __launch_bounds__(256) void k_red_s1(const float* __restrict__ V1, float* __restrict__ s1) {
  int idx = blockIdx.x * 256 + threadIdx.x;
  if (idx >= B_N * GCH) return;
  int b = idx / GCH, n = idx % GCH;
  float s = 0.f;
  #pragma unroll 4
  for (int i = 0; i < DINP; i++) s += V1[((size_t)b * DINP + i) * GCH + n];
  s1[idx] = s * (1.0f / 36.0f);
}

// x[t,b,d<144] = v2[b, 4t + (d&3)];  x[t,b,144+j] = pe[t,b,j]
__global__ __launch_bounds__(256) void k_buildx(const float* __restrict__ v2,
    const float* __restrict__ pe, float* __restrict__ x) {
  int idx = blockIdx.x * 256 + threadIdx.x;
  if (idx >= T_LEN * B_N * 40) return;
  int c = idx % 40;
  int r = idx / 40;            // r = t*B + b
  int t = r / B_N, b = r % B_N;
  float4 f;
  if (c < 36) f = *(const float4*)&v2[(size_t)b * GCH + 4 * t];
  else        f = *(const float4*)&pe[(size_t)r * 16 + (c - 36) * 4];
  ((float4*)(x + (size_t)r * D_TR))[c] = f;
}

// ---------------- generic fp32 GEMM: C = act(A[M,K] @ W[N,K]^T + bias) ----------------
// BM=BN=128, BK=16, 256 threads, 8x8 micro-tile. M must be a multiple of 128.
template <int RELU>
__global__ __launch_bounds__(256) void gemm_nt(const float* __restrict__ A,
    const float* __restrict__ W, const float* __restrict__ bias, float* __restrict__ C,
    int M, int N, int K) {
  __shared__ float As[16][132];
  __shared__ float Ws[16][132];
  const int tid = threadIdx.x;
  const int tx = tid & 15, ty = tid >> 4;
  const int m0 = blockIdx.y * 128, n0 = blockIdx.x * 128;
  float acc[8][8];
  #pragma unroll
  for (int i = 0; i < 8; i++)
    #pragma unroll
    for (int j = 0; j < 8; j++) acc[i][j] = 0.f;

  const int kc = tid & 15;
  const int rb = tid >> 4;
  const int nkt = (K + 15) >> 4;
  for (int kt = 0; kt < nkt; ++kt) {
    const int gk = kt * 16 + kc;
    const bool kin = gk < K;
    #pragma unroll
    for (int p = 0; p < 8; p++) {
      int r = rb + p * 16;
      As[kc][r] = kin ? A[(size_t)(m0 + r) * K + gk] : 0.f;
      int gn = n0 + r;
      Ws[kc][r] = (kin && gn < N) ? W[(size_t)gn * K + gk] : 0.f;
    }
    __syncthreads();
    #pragma unroll
    for (int kk = 0; kk < 16; kk++) {
      float4 a0 = *(const float4*)&As[kk][ty * 4];
      float4 a1 = *(const float4*)&As[kk][64 + ty * 4];
      float4 b0 = *(const float4*)&Ws[kk][tx * 4];
      float4 b1 = *(const float4*)&Ws[kk][64 + tx * 4];
      float av[8] = {a0.x, a0.y, a0.z, a0.w, a1.x, a1.y, a1.z, a1.w};
      float bv[8] = {b0.x, b0.y, b0.z, b0.w, b1.x, b1.y, b1.z, b1.w};
      #pragma unroll
      for (int i = 0; i < 8; i++)
        #pragma unroll
        for (int j = 0; j < 8; j++) acc[i][j] = fmaf(av[i], bv[j], acc[i][j]);
    }
    __syncthreads();
  }
  #pragma unroll
  for (int i = 0; i < 8; i++) {
    int gm = m0 + ((i < 4) ? (ty * 4 + i) : (64 + ty * 4 + i - 4));
    #pragma unroll
    for (int j = 0; j < 8; j++) {
      int gn = n0 + ((j < 4) ? (tx * 4 + j) : (64 + tx * 4 + j - 4));
      if (gn < N) {
        float v = acc[i][j] + (bias ? bias[gn] : 0.f);
        if (RELU) v = fmaxf(v, 0.f);
        C[(size_t)gm * N + gn] = v;
      }
    }
  }
}

// ---------------- attention: one block per (b,h), online softmax, K/V chunked in LDS ----------------
__global__ __launch_bounds__(256) void k_attn(const float* __restrict__ qkv,
    const int* __restrict__ lengths, float* __restrict__ o) {
  __shared__ float klds[TKB * HD];
  __shared__ float vlds[TKB * HD];
  const int b = blockIdx.x >> 2, h = blockIdx.x & 3;
  int L = lengths[b];
  if (L > T_LEN) L = T_LEN;
  const int tq = threadIdx.x;
  float q[HD], acc[HD];
  float m = -INFINITY, l = 0.f;
  if (tq < T_LEN) {
    const float* qp = qkv + ((size_t)tq * B_N + b) * 480 + h * HD;
    #pragma unroll
    for (int d = 0; d < HD; d++) { q[d] = qp[d] * 0.15811388300841898f; acc[d] = 0.f; }
  }
  for (int c0 = 0; c0 < L; c0 += TKB) {
    const int cn = min(TKB, L - c0);
    __syncthreads();
    for (int idx = threadIdx.x; idx < cn * HD; idx += 256) {
      int tk = idx / HD, d = idx % HD;
      size_t base = ((size_t)(c0 + tk) * B_N + b) * 480 + 160 + h * HD + d;
      klds[idx] = qkv[base];
      vlds[idx] = qkv[base + 160];
    }
    __syncthreads();
    if (tq < T_LEN) {
      for (int tk = 0; tk < cn; ++tk) {
        const float* kp = &klds[tk * HD];
        float s = 0.f;
        #pragma unroll
        for (int d = 0; d < HD; d++) s = fmaf(q[d], kp[d], s);
        const float* vp = &vlds[tk * HD];
        if (s > m) {
          float f = __expf(m - s);
          m = s;
          l = fmaf(l, f, 1.f);
          #pragma unroll
          for (int d = 0; d < HD; d++) acc[d] = fmaf(acc[d], f, vp[d]);
        } else {
          float p = __expf(s - m);
          l += p;
          #pragma unroll
          for (int d = 0; d < HD; d++) acc[d] = fmaf(p, vp[d], acc[d]);
        }
      }
    }
  }
  if (tq < T_LEN) {
    float inv = 1.0f / l;
    float* op = o + ((size_t)tq * B_N + b) * D_TR + h * HD;
    #pragma unroll
    for (int d = 0; d < HD; d++) op[d] = acc[d] * inv;
  }
}

// ---------------- fused residual + LayerNorm, wave per 160-elem row, in-place on x ----------------
__global__ __launch_bounds__(256) void k_lnres(float* __restrict__ x,
    const float* __restrict__ delta, const float* __restrict__ gam, const float* __restrict__ bet) {
  int wid = (blockIdx.x * 256 + threadIdx.x) >> 6;
  int lane = threadIdx.x & 63;
  if (wid >= T_LEN * B_N) return;
  float* xr = x + (size_t)wid * D_TR;
  const float* dr = delta + (size_t)wid * D_TR;
  float a0 = xr[lane] + dr[lane];
  float a1 = xr[lane + 64] + dr[lane + 64];
  float a2 = (lane < 32) ? (xr[lane + 128] + dr[lane + 128]) : 0.f;
  float s = a0 + a1 + a2;
  #pragma unroll
  for (int off = 32; off; off >>= 1) s += __shfl_xor(s, off, 64);
  float mu = s * (1.0f / 160.0f);
  float d0 = a0 - mu, d1 = a1 - mu, d2 = (lane < 32) ? (a2 - mu) : 0.f;
  float sq = d0 * d0 + d1 * d1 + d2 * d2;
  #pragma unroll
  for (int off = 32; off; off >>= 1) sq += __shfl_xor(sq, off, 64);
  float rstd = rsqrtf(sq * (1.0f / 160.0f) + 1e-5f);
  xr[lane]      = d0 * rstd * gam[lane] + bet[lane];
  xr[lane + 64] = d1 * rstd * gam[lane + 64] + bet[lane + 64];
  if (lane < 32) xr[lane + 128] = d2 * rstd * gam[lane + 128] + bet[lane + 128];
}

// ---------------- masked mean over time + concat emb -> feat (B,196) ----------------
__global__ __launch_bounds__(256) void k_agg(const float* __restrict__ x,
    const int* __restrict__ lengths, const float* __restrict__ emb, float* __restrict__ feat) {
  int b = blockIdx.x, d = threadIdx.x;
  int L = lengths[b];
  if (L > T_LEN) L = T_LEN;
  if (d < D_TR) {
    float s = 0.f;
    for (int t = 0; t < L; t++) s += x[((size_t)t * B_N + b) * D_TR + d];
    feat[b * D_FIN + d] = s / (float)(L + 1);
  } else if (d < D_FIN) {
    feat[b * D_FIN + d] = emb[b * DINP + (d - D_TR)];
  }
}

// ---------------- final tiny classifier + distance constant ----------------
__global__ __launch_bounds__(256) void k_final(const float* __restrict__ m1,
    const float* __restrict__ w2, const float* __restrict__ b2, float* __restrict__ out) {
  int tid = threadIdx.x;
  int b = tid >> 1, c = tid & 1;
  float s = b2[c];
  for (int k = 0; k < D_FIN; k++) s = fmaf(m1[b * D_FIN + k], w2[c * D_FIN + k], s);
  out[tid] = s;
  if (tid == 0) out[256] = 0.f;  // distance == 0 exactly (all-ones edge weights)
}

// ---------------- launch ----------------
extern "C" void kernel_launch(void* const* d_in, const int* in_sizes, int n_in,
                              void* d_out, int out_size, void* d_ws, size_t ws_size,
                              hipStream_t stream) {
  const float* src   = (const float*)d_in[0];
  const float* stat  = (const float*)d_in[1];
  const float* times = (const float*)d_in[2];
  const int*   lens  = (const int*)d_in[3];
  const float* R_u   = (const float*)d_in[4];
  const float* emb_w = (const float*)d_in[5];
  const float* emb_b = (const float*)d_in[6];
  const float* Wv1   = (const float*)d_in[7];
  const float* bv1   = (const float*)d_in[8];
  const float* Wv2   = (const float*)d_in[9];
  const float* bv2   = (const float*)d_in[10];
  const float* ipw   = (const float*)d_in[11];
  const float* ipb   = (const float*)d_in[12];
  const float* ow    = (const float*)d_in[13];
  const float* ob    = (const float*)d_in[14];
  const float* l1w   = (const float*)d_in[15];
  const float* l1b   = (const float*)d_in[16];
  const float* l2w   = (const float*)d_in[17];
  const float* l2b   = (const float*)d_in[18];
  const float* ln1s  = (const float*)d_in[19];
  const float* ln1bb = (const float*)d_in[20];
  const float* ln2s  = (const float*)d_in[21];
  const float* ln2bb = (const float*)d_in[22];
  const float* m1w   = (const float*)d_in[23];
  const float* m1b   = (const float*)d_in[24];
  const float* m2w   = (const float*)d_in[25];
  const float* m2b   = (const float*)d_in[26];
  float* out = (float*)d_out;
  float* ws  = (float*)d_ws;

  // workspace layout (floats); total ~27.1M floats = ~103.5 MB
  float* x    = ws;                       // 4,403,200  (T,B,160) persistent
  float* pe   = x + 4403200;              // 440,320
  float* s1   = pe + 440320;              // 110,080
  float* v2   = s1 + 110080;              // 110,080
  float* emb  = v2 + 110080;              // 4,608
  float* feat = emb + 4608;               // 25,088
  float* m1o  = feat + 25088;             // 25,088
  float* big  = m1o + 25088;
  float* xb   = big;                      // 3,962,880
  float* V1   = big + 3962880;            // 3,962,880
  float* qkv  = big;                      // 13,209,600 (reuses xb/V1 after graph phase)
  float* obuf = big + 13209600;           // 4,403,200
  float* t1   = obuf + 4403200;           // 4,403,200
  float* ffb  = big;                      // 3,522,560  (reuses qkv region after attn)

  k_emb<<<18, 256, 0, stream>>>(stat, emb_w, emb_b, emb);
  k_pe<<<108, 256, 0, stream>>>(times, pe);
  k_xb<<<3870, 256, 0, stream>>>(src, R_u, xb);

  // V1 = relu(xb @ Wv1^T + bv1) : (4608,860)x(860,860)
  gemm_nt<1><<<dim3(7, 36), 256, 0, stream>>>(xb, Wv1, bv1, V1, 4608, 860, 860);
  k_red_s1<<<430, 256, 0, stream>>>(V1, s1);
  // v2 = relu(s1 @ Wv2^T + bv2) : (128,860)x(860,860)
  gemm_nt<1><<<dim3(7, 1), 256, 0, stream>>>(s1, Wv2, bv2, v2, 128, 860, 860);
  k_buildx<<<4300, 256, 0, stream>>>(v2, pe, x);

  for (int l = 0; l < 2; l++) {
    gemm_nt<0><<<dim3(4, 215), 256, 0, stream>>>(x, ipw + (size_t)l * 76800, ipb + l * 480,
                                                 qkv, 27520, 480, 160);
    k_attn<<<512, 256, 0, stream>>>(qkv, lens, obuf);
    gemm_nt<0><<<dim3(2, 215), 256, 0, stream>>>(obuf, ow + (size_t)l * 25600, ob + l * 160,
                                                 t1, 27520, 160, 160);
    k_lnres<<<6880, 256, 0, stream>>>(x, t1, ln1s + l * 160, ln1bb + l * 160);
    gemm_nt<1><<<dim3(1, 215), 256, 0, stream>>>(x, l1w + (size_t)l * 20480, l1b + l * 128,
                                                 ffb, 27520, 128, 160);
    gemm_nt<0><<<dim3(2, 215), 256, 0, stream>>>(ffb, l2w + (size_t)l * 20480, l2b + l * 160,
                                                 t1, 27520, 160, 128);
    k_lnres<<<6880, 256, 0, stream>>>(x, t1, ln2s + l * 160, ln2bb + l * 160);
  }

  k_agg<<<128, 256, 0, stream>>>(x, lens, emb, feat);
  gemm_nt<1><<<dim3(2, 1), 256, 0, stream>>>(feat, m1w, m1b, m1o, 128, 196, 196);
  k_final<<<1, 256, 0, stream>>>(m1o, m2w, m2b, out);
}

// Round 2
// 594.944 us; speedup vs baseline: 2.9711x; 2.9711x over previous
//
#include <hip/hip_runtime.h>
#include <math.h>

#define T_LEN 215
#define B_N   128
#define DINP  36
#define D_TR  160
#define HD    40
#define D_FIN 196
#define TKB   128
#define KPG   864   // 860 padded to mult of 32

typedef __attribute__((ext_vector_type(8))) short short8v;
typedef __attribute__((ext_vector_type(4))) float f32x4;

__device__ __forceinline__ ushort f2bf(float x) {
  union { float f; unsigned u; } c; c.f = x;
  unsigned r = c.u + 0x7fffu + ((c.u >> 16) & 1u);
  return (ushort)(r >> 16);
}

// ---------------- conversions ----------------
__global__ __launch_bounds__(256) void k_conv(const float* __restrict__ s,
    ushort* __restrict__ d, int n) {
  int i = blockIdx.x * 256 + threadIdx.x;
  if (i < n) d[i] = f2bf(s[i]);
}

// 860x860 fp32 -> 864x864 bf16 zero-padded
__global__ __launch_bounds__(256) void k_convpad(const float* __restrict__ s,
    ushort* __restrict__ d) {
  int i = blockIdx.x * 256 + threadIdx.x;
  if (i >= KPG * KPG) return;
  int n = i / KPG, k = i % KPG;
  d[i] = (n < 860 && k < 860) ? f2bf(s[n * 860 + k]) : (ushort)0;
}

__global__ __launch_bounds__(256) void k_zero(float* __restrict__ p, int n) {
  int i = blockIdx.x * 256 + threadIdx.x;
  if (i < n) p[i] = 0.f;
}

// ---------------- small fused kernels ----------------
__global__ __launch_bounds__(256) void k_emb(const float* __restrict__ st,
    const float* __restrict__ ew, const float* __restrict__ eb, float* __restrict__ emb) {
  int idx = blockIdx.x * 256 + threadIdx.x;
  if (idx >= B_N * DINP) return;
  int b = idx / DINP, i = idx % DINP;
  float s = eb[i];
  #pragma unroll
  for (int k = 0; k < 9; k++) s = fmaf(st[b * 9 + k], ew[i * 9 + k], s);
  emb[idx] = s;
}

__global__ __launch_bounds__(256) void k_pe(const float* __restrict__ times, float* __restrict__ pe) {
  int idx = blockIdx.x * 256 + threadIdx.x;
  if (idx >= T_LEN * B_N) return;
  float tm = times[idx];
  #pragma unroll
  for (int k = 0; k < 8; k++) {
    float ts = powf(215.0f, (float)k * (1.0f / 7.0f));
    float sc = tm / ts;
    pe[(size_t)idx * 16 + k]     = sinf(sc);
    pe[(size_t)idx * 16 + 8 + k] = cosf(sc);
  }
}

// xb16[b,i, 4t+j] = bf16(relu(src[t,b,i]*R_u[4i+j])), stride KPG, zero-pad cols 860..863
__global__ __launch_bounds__(256) void k_xb16(const float* __restrict__ src,
    const float* __restrict__ R_u, ushort* __restrict__ xb16) {
  int idx = blockIdx.x * 256 + threadIdx.x;
  if (idx >= B_N * DINP * T_LEN) return;
  int t = idx % T_LEN;
  int i = (idx / T_LEN) % DINP;
  int b = idx / (T_LEN * DINP);
  float v = src[((size_t)t * B_N + b) * 72 + i];
  float4 r = ((const float4*)R_u)[i];
  ushort4 o;
  o.x = f2bf(fmaxf(v * r.x, 0.f)); o.y = f2bf(fmaxf(v * r.y, 0.f));
  o.z = f2bf(fmaxf(v * r.z, 0.f)); o.w = f2bf(fmaxf(v * r.w, 0.f));
  ushort* row = xb16 + (size_t)(b * DINP + i) * KPG;
  *(ushort4*)(row + 4 * t) = o;
  if (t == 0) { ushort4 z = {0, 0, 0, 0}; *(ushort4*)(row + 860) = z; }
}

// s1_16[b,n] = bf16( (1/36) sum_i V1[b*36+i, n] ), stride KPG, zero-pad
__global__ __launch_bounds__(256) void k_red_s1(const float* __restrict__ V1, ushort* __restrict__ s1) {
  int idx = blockIdx.x * 256 + threadIdx.x;
  if (idx >= B_N * KPG) return;
  int b = idx / KPG, n = idx % KPG;
  float s = 0.f;
  if (n < 860) {
    #pragma unroll 4
    for (int i = 0; i < DINP; i++) s += V1[((size_t)b * DINP + i) * 860 + n];
    s *= (1.0f / 36.0f);
  }
  s1[idx] = (n < 860) ? f2bf(s) : (ushort)0;
}

// x[t,b,*] (fp32 + bf16) from relu(v2acc + bv2) and pe
__global__ __launch_bounds__(256) void k_buildx(const float* __restrict__ v2acc,
    const float* __restrict__ bv2, const float* __restrict__ pe,
    float* __restrict__ x, ushort* __restrict__ x16) {
  int idx = blockIdx.x * 256 + threadIdx.x;
  if (idx >= T_LEN * B_N * 40) return;
  int c = idx % 40;
  int r = idx / 40;            // r = t*B + b
  int t = r / B_N, b = r % B_N;
  float4 f;
  if (c < 36) {
    float4 a = *(const float4*)&v2acc[(size_t)b * KPG + 4 * t];
    float4 bb = *(const float4*)&bv2[4 * t];
    f.x = fmaxf(a.x + bb.x, 0.f); f.y = fmaxf(a.y + bb.y, 0.f);
    f.z = fmaxf(a.z + bb.z, 0.f); f.w = fmaxf(a.w + bb.w, 0.f);
  } else {
    f = *(const float4*)&pe[(size_t)r * 16 + (c - 36) * 4];
  }
  ((float4*)(x + (size_t)r * D_TR))[c] = f;
  ushort4 h = {f2bf(f.x), f2bf(f.y), f2bf(f.z), f2bf(f.w)};
  *(ushort4*)(x16 + (size_t)r * D_TR + 4 * c) = h;
}

// ---------------- bf16 MFMA GEMM: C = act(A[M,KP] @ W[N,KP]^T + bias) ----------------
// BM=128, BN=32, BK=32, 256 threads (4 waves). M%128==0, N%32==0 (store guard via ncols).
// SPLIT: atomicAdd fp32 partials (no bias/act), grid.z = #splits. WMODE 0: fp32 C, 1: bf16 C.
template <int RELU, int SPLIT, int WMODE>
__global__ __launch_bounds__(256) void gemm_bf16(const ushort* __restrict__ A,
    const ushort* __restrict__ W, const float* __restrict__ bias, void* __restrict__ Cv,
    int KP, int ldc, int ncols, int kts) {
  __shared__ ushort As[128 * 32];
  __shared__ ushort Ws[32 * 32];
  const int tid = threadIdx.x;
  const int wave = tid >> 6, lane = tid & 63;
  const int lr = lane & 15, hi = lane >> 4;
  const int m0 = blockIdx.y * 128, n0 = blockIdx.x * 32;
  const int kt0 = blockIdx.z * kts;

  f32x4 acc00 = {0.f, 0.f, 0.f, 0.f}, acc01 = acc00, acc10 = acc00, acc11 = acc00;

  // staging: A = 512 chunks of 16B (2/thread), W = 128 chunks (tid<128)
  const int ar0 = tid >> 2, as0 = tid & 3;
  const size_t abase0 = (size_t)(m0 + ar0) * KP;
  const size_t abase1 = (size_t)(m0 + ar0 + 64) * KP;
  const int awb0 = ar0 * 64 + ((as0 * 16) ^ ((ar0 & 3) << 4));
  const int awb1 = (ar0 + 64) * 64 + ((as0 * 16) ^ (((ar0 + 64) & 3) << 4));
  const size_t bbase = (size_t)(n0 + ar0) * KP;   // valid when tid<128 (row<32)
  const int bwb = ar0 * 64 + ((as0 * 16) ^ ((ar0 & 3) << 4));

  // fragment read offsets (bytes)
  const int arow0 = wave * 32 + lr, arow1 = arow0 + 16;
  const int arb0 = arow0 * 64 + ((hi * 16) ^ ((arow0 & 3) << 4));
  const int arb1 = arow1 * 64 + ((hi * 16) ^ ((arow1 & 3) << 4));
  const int brb0 = lr * 64 + ((hi * 16) ^ ((lr & 3) << 4));
  const int brb1 = (lr + 16) * 64 + ((hi * 16) ^ (((lr + 16) & 3) << 4));

  for (int kt = 0; kt < kts; ++kt) {
    const int k0 = (kt0 + kt) * 32;
    uint4 va0 = *(const uint4*)(A + abase0 + k0 + as0 * 8);
    uint4 va1 = *(const uint4*)(A + abase1 + k0 + as0 * 8);
    uint4 vb;
    if (tid < 128) vb = *(const uint4*)(W + bbase + k0 + as0 * 8);
    if (kt) __syncthreads();
    *(uint4*)((char*)As + awb0) = va0;
    *(uint4*)((char*)As + awb1) = va1;
    if (tid < 128) *(uint4*)((char*)Ws + bwb) = vb;
    __syncthreads();
    short8v a0 = *(const short8v*)((const char*)As + arb0);
    short8v a1 = *(const short8v*)((const char*)As + arb1);
    short8v b0 = *(const short8v*)((const char*)Ws + brb0);
    short8v b1 = *(const short8v*)((const char*)Ws + brb1);
    acc00 = __builtin_amdgcn_mfma_f32_16x16x32_bf16(a0, b0, acc00, 0, 0, 0);
    acc01 = __builtin_amdgcn_mfma_f32_16x16x32_bf16(a0, b1, acc01, 0, 0, 0);
    acc10 = __builtin_amdgcn_mfma_f32_16x16x32_bf16(a1, b0, acc10, 0, 0, 0);
    acc11 = __builtin_amdgcn_mfma_f32_16x16x32_bf16(a1, b1, acc11, 0, 0, 0);
  }

  const int gcol0 = n0 + lr, gcol1 = n0 + 16 + lr;
  const int grow0 = m0 + wave * 32 + hi * 4;

  #pragma unroll
  for (int f = 0; f < 4; f++) {
    f32x4 v = (f == 0) ? acc00 : (f == 1) ? acc01 : (f == 2) ? acc10 : acc11;
    int col = (f & 1) ? gcol1 : gcol0;
    int row = grow0 + ((f >> 1) ? 16 : 0);
    if (col < ncols) {
      if (SPLIT) {
        #pragma unroll
        for (int r = 0; r < 4; r++)
          atomicAdd((float*)Cv + (size_t)(row + r) * ldc + col, v[r]);
      } else {
        float bb = bias ? bias[col] : 0.f;
        #pragma unroll
        for (int r = 0; r < 4; r++) {
          float xv = v[r] + bb;
          if (RELU) xv = fmaxf(xv, 0.f);
          if (WMODE == 0) ((float*)Cv)[(size_t)(row + r) * ldc + col] = xv;
          else            ((ushort*)Cv)[(size_t)(row + r) * ldc + col] = f2bf(xv);
        }
      }
    }
  }
}

// ---------------- attention (fp32), writes bf16 output ----------------
__global__ __launch_bounds__(256) void k_attn(const float* __restrict__ qkv,
    const int* __restrict__ lengths, ushort* __restrict__ o16) {
  __shared__ float klds[TKB * HD];
  __shared__ float vlds[TKB * HD];
  const int b = blockIdx.x >> 2, h = blockIdx.x & 3;
  int L = lengths[b];
  if (L > T_LEN) L = T_LEN;
  const int tq = threadIdx.x;
  float q[HD], acc[HD];
  float m = -INFINITY, l = 0.f;
  if (tq < T_LEN) {
    const float* qp = qkv + ((size_t)tq * B_N + b) * 480 + h * HD;
    #pragma unroll
    for (int d = 0; d < HD; d++) { q[d] = qp[d] * 0.15811388300841898f; acc[d] = 0.f; }
  }
  for (int c0 = 0; c0 < L; c0 += TKB) {
    const int cn = min(TKB, L - c0);
    __syncthreads();
    for (int idx = threadIdx.x; idx < cn * HD; idx += 256) {
      int tk = idx / HD, d = idx % HD;
      size_t base = ((size_t)(c0 + tk) * B_N + b) * 480 + 160 + h * HD + d;
      klds[idx] = qkv[base];
      vlds[idx] = qkv[base + 160];
    }
    __syncthreads();
    if (tq < T_LEN) {
      for (int tk = 0; tk < cn; ++tk) {
        const float* kp = &klds[tk * HD];
        float s = 0.f;
        #pragma unroll
        for (int d = 0; d < HD; d++) s = fmaf(q[d], kp[d], s);
        const float* vp = &vlds[tk * HD];
        if (s > m) {
          float f = __expf(m - s);
          m = s;
          l = fmaf(l, f, 1.f);
          #pragma unroll
          for (int d = 0; d < HD; d++) acc[d] = fmaf(acc[d], f, vp[d]);
        } else {
          float p = __expf(s - m);
          l += p;
          #pragma unroll
          for (int d = 0; d < HD; d++) acc[d] = fmaf(p, vp[d], acc[d]);
        }
      }
    }
  }
  if (tq < T_LEN) {
    float inv = 1.0f / l;
    ushort* op = o16 + ((size_t)tq * B_N + b) * D_TR + h * HD;
    #pragma unroll
    for (int d = 0; d < HD; d++) op[d] = f2bf(acc[d] * inv);
  }
}

// ---------------- fused residual + LayerNorm (writes fp32 x and bf16 x16) ----------------
__global__ __launch_bounds__(256) void k_lnres(float* __restrict__ x,
    const float* __restrict__ delta, const float* __restrict__ gam,
    const float* __restrict__ bet, ushort* __restrict__ x16) {
  int wid = (blockIdx.x * 256 + threadIdx.x) >> 6;
  int lane = threadIdx.x & 63;
  if (wid >= T_LEN * B_N) return;
  float* xr = x + (size_t)wid * D_TR;
  ushort* hr = x16 + (size_t)wid * D_TR;
  const float* dr = delta + (size_t)wid * D_TR;
  float a0 = xr[lane] + dr[lane];
  float a1 = xr[lane + 64] + dr[lane + 64];
  float a2 = (lane < 32) ? (xr[lane + 128] + dr[lane + 128]) : 0.f;
  float s = a0 + a1 + a2;
  #pragma unroll
  for (int off = 32; off; off >>= 1) s += __shfl_xor(s, off, 64);
  float mu = s * (1.0f / 160.0f);
  float d0 = a0 - mu, d1 = a1 - mu, d2 = (lane < 32) ? (a2 - mu) : 0.f;
  float sq = d0 * d0 + d1 * d1 + d2 * d2;
  #pragma unroll
  for (int off = 32; off; off >>= 1) sq += __shfl_xor(sq, off, 64);
  float rstd = rsqrtf(sq * (1.0f / 160.0f) + 1e-5f);
  float o0 = d0 * rstd * gam[lane] + bet[lane];
  float o1 = d1 * rstd * gam[lane + 64] + bet[lane + 64];
  xr[lane] = o0;      hr[lane] = f2bf(o0);
  xr[lane + 64] = o1; hr[lane + 64] = f2bf(o1);
  if (lane < 32) {
    float o2 = d2 * rstd * gam[lane + 128] + bet[lane + 128];
    xr[lane + 128] = o2; hr[lane + 128] = f2bf(o2);
  }
}

// ---------------- masked mean + concat emb ----------------
__global__ __launch_bounds__(256) void k_agg(const float* __restrict__ x,
    const int* __restrict__ lengths, const float* __restrict__ emb, float* __restrict__ feat) {
  int b = blockIdx.x, d = threadIdx.x;
  int L = lengths[b];
  if (L > T_LEN) L = T_LEN;
  if (d < D_TR) {
    float s = 0.f;
    for (int t = 0; t < L; t++) s += x[((size_t)t * B_N + b) * D_TR + d];
    feat[b * D_FIN + d] = s / (float)(L + 1);
  } else if (d < D_FIN) {
    feat[b * D_FIN + d] = emb[b * DINP + (d - D_TR)];
  }
}

// ---------------- fp32 GEMM (kept for tiny final mlp1) ----------------
template <int RELU>
__global__ __launch_bounds__(256) void gemm_nt(const float* __restrict__ A,
    const float* __restrict__ W, const float* __restrict__ bias, float* __restrict__ C,
    int M, int N, int K) {
  __shared__ float As[16][132];
  __shared__ float Ws[16][132];
  const int tid = threadIdx.x;
  const int tx = tid & 15, ty = tid >> 4;
  const int m0 = blockIdx.y * 128, n0 = blockIdx.x * 128;
  float acc[8][8];
  #pragma unroll
  for (int i = 0; i < 8; i++)
    #pragma unroll
    for (int j = 0; j < 8; j++) acc[i][j] = 0.f;
  const int kc = tid & 15;
  const int rb = tid >> 4;
  const int nkt = (K + 15) >> 4;
  for (int kt = 0; kt < nkt; ++kt) {
    const int gk = kt * 16 + kc;
    const bool kin = gk < K;
    #pragma unroll
    for (int p = 0; p < 8; p++) {
      int r = rb + p * 16;
      As[kc][r] = kin ? A[(size_t)(m0 + r) * K + gk] : 0.f;
      int gn = n0 + r;
      Ws[kc][r] = (kin && gn < N) ? W[(size_t)gn * K + gk] : 0.f;
    }
    __syncthreads();
    #pragma unroll
    for (int kk = 0; kk < 16; kk++) {
      float4 a0 = *(const float4*)&As[kk][ty * 4];
      float4 a1 = *(const float4*)&As[kk][64 + ty * 4];
      float4 b0 = *(const float4*)&Ws[kk][tx * 4];
      float4 b1 = *(const float4*)&Ws[kk][64 + tx * 4];
      float av[8] = {a0.x, a0.y, a0.z, a0.w, a1.x, a1.y, a1.z, a1.w};
      float bv[8] = {b0.x, b0.y, b0.z, b0.w, b1.x, b1.y, b1.z, b1.w};
      #pragma unroll
      for (int i = 0; i < 8; i++)
        #pragma unroll
        for (int j = 0; j < 8; j++) acc[i][j] = fmaf(av[i], bv[j], acc[i][j]);
    }
    __syncthreads();
  }
  #pragma unroll
  for (int i = 0; i < 8; i++) {
    int gm = m0 + ((i < 4) ? (ty * 4 + i) : (64 + ty * 4 + i - 4));
    #pragma unroll
    for (int j = 0; j < 8; j++) {
      int gn = n0 + ((j < 4) ? (tx * 4 + j) : (64 + tx * 4 + j - 4));
      if (gn < N) {
        float v = acc[i][j] + (bias ? bias[gn] : 0.f);
        if (RELU) v = fmaxf(v, 0.f);
        C[(size_t)gm * N + gn] = v;
      }
    }
  }
}

__global__ __launch_bounds__(256) void k_final(const float* __restrict__ m1,
    const float* __restrict__ w2, const float* __restrict__ b2, float* __restrict__ out) {
  int tid = threadIdx.x;
  int b = tid >> 1, c = tid & 1;
  float s = b2[c];
  for (int k = 0; k < D_FIN; k++) s = fmaf(m1[b * D_FIN + k], w2[c * D_FIN + k], s);
  out[tid] = s;
  if (tid == 0) out[256] = 0.f;  // distance == 0 exactly
}

// ---------------- launch ----------------
extern "C" void kernel_launch(void* const* d_in, const int* in_sizes, int n_in,
                              void* d_out, int out_size, void* d_ws, size_t ws_size,
                              hipStream_t stream) {
  const float* src   = (const float*)d_in[0];
  const float* stat  = (const float*)d_in[1];
  const float* times = (const float*)d_in[2];
  const int*   lens  = (const int*)d_in[3];
  const float* R_u   = (const float*)d_in[4];
  const float* emb_w = (const float*)d_in[5];
  const float* emb_b = (const float*)d_in[6];
  const float* Wv1   = (const float*)d_in[7];
  const float* bv1   = (const float*)d_in[8];
  const float* Wv2   = (const float*)d_in[9];
  const float* bv2   = (const float*)d_in[10];
  const float* ipw   = (const float*)d_in[11];
  const float* ipb   = (const float*)d_in[12];
  const float* ow    = (const float*)d_in[13];
  const float* ob    = (const float*)d_in[14];
  const float* l1w   = (const float*)d_in[15];
  const float* l1b   = (const float*)d_in[16];
  const float* l2w   = (const float*)d_in[17];
  const float* l2b   = (const float*)d_in[18];
  const float* ln1s  = (const float*)d_in[19];
  const float* ln1bb = (const float*)d_in[20];
  const float* ln2s  = (const float*)d_in[21];
  const float* ln2bb = (const float*)d_in[22];
  const float* m1w   = (const float*)d_in[23];
  const float* m1b   = (const float*)d_in[24];
  const float* m2w   = (const float*)d_in[25];
  const float* m2b   = (const float*)d_in[26];
  float* out = (float*)d_out;

  // ---- workspace layout (bytes), total ~94.3 MB ----
  char* p = (char*)d_ws;
  float*  x      = (float*)p;   p += 17612800;  // 27520 x 160 fp32
  ushort* x16    = (ushort*)p;  p += 8806400;   // 27520 x 160 bf16
  float*  pe     = (float*)p;   p += 1761280;
  float*  emb    = (float*)p;   p += 18432;
  float*  feat   = (float*)p;   p += 100352;
  float*  m1o    = (float*)p;   p += 100352;
  float*  v2acc  = (float*)p;   p += 442368;    // 128 x 864 fp32
  ushort* s1b    = (ushort*)p;  p += 221184;    // 128 x 864 bf16
  ushort* obuf16 = (ushort*)p;  p += 8806400;   // 27520 x 160 bf16
  ushort* wv1b   = (ushort*)p;  p += 1492992;   // 864 x 864 bf16
  ushort* wv2b   = (ushort*)p;  p += 1492992;
  ushort* ipwb   = (ushort*)p;  p += 307200;    // 2 x 480 x 160
  ushort* owb    = (ushort*)p;  p += 102400;    // 2 x 160 x 160
  ushort* l1wb   = (ushort*)p;  p += 81920;     // 2 x 128 x 160
  ushort* l2wb   = (ushort*)p;  p += 81920;     // 2 x 160 x 128
  char*   R2     = p;                           // 52,838,400 B shared region
  ushort* xb16   = (ushort*)R2;                 // phase A: 4608 x 864 bf16
  float*  V1     = (float*)(R2 + 7962624);      // phase A: 4608 x 860 fp32
  float*  qkvb   = (float*)R2;                  // phase B: 27520 x 480 fp32
  float*  t1     = (float*)R2;                  // post-attn: 27520 x 160 fp32
  ushort* ffb16  = (ushort*)(R2 + 17612800);    // 27520 x 128 bf16

  // weight conversions
  k_convpad<<<2916, 256, 0, stream>>>(Wv1, wv1b);
  k_convpad<<<2916, 256, 0, stream>>>(Wv2, wv2b);
  k_conv<<<600, 256, 0, stream>>>(ipw, ipwb, 153600);
  k_conv<<<200, 256, 0, stream>>>(ow, owb, 51200);
  k_conv<<<160, 256, 0, stream>>>(l1w, l1wb, 40960);
  k_conv<<<160, 256, 0, stream>>>(l2w, l2wb, 40960);

  k_emb<<<18, 256, 0, stream>>>(stat, emb_w, emb_b, emb);
  k_pe<<<108, 256, 0, stream>>>(times, pe);
  k_xb16<<<3870, 256, 0, stream>>>(src, R_u, xb16);

  // V1 = relu(xb @ Wv1^T + bv1)
  gemm_bf16<1, 0, 0><<<dim3(27, 36, 1), 256, 0, stream>>>(xb16, wv1b, bv1, V1, KPG, 860, 860, 27);
  k_red_s1<<<432, 256, 0, stream>>>(V1, s1b);
  // v2acc = s1 @ Wv2^T  (split-K=3, atomics; bias+relu folded into buildx)
  k_zero<<<432, 256, 0, stream>>>(v2acc, 110592);
  gemm_bf16<0, 1, 0><<<dim3(27, 1, 3), 256, 0, stream>>>(s1b, wv2b, nullptr, v2acc, KPG, KPG, KPG, 9);
  k_buildx<<<4300, 256, 0, stream>>>(v2acc, bv2, pe, x, x16);

  for (int l = 0; l < 2; l++) {
    gemm_bf16<0, 0, 0><<<dim3(15, 215, 1), 256, 0, stream>>>(
        x16, ipwb + (size_t)l * 76800, ipb + l * 480, qkvb, 160, 480, 480, 5);
    k_attn<<<512, 256, 0, stream>>>(qkvb, lens, obuf16);
    gemm_bf16<0, 0, 0><<<dim3(5, 215, 1), 256, 0, stream>>>(
        obuf16, owb + (size_t)l * 25600, ob + l * 160, t1, 160, 160, 160, 5);
    k_lnres<<<6880, 256, 0, stream>>>(x, t1, ln1s + l * 160, ln1bb + l * 160, x16);
    gemm_bf16<1, 0, 1><<<dim3(4, 215, 1), 256, 0, stream>>>(
        x16, l1wb + (size_t)l * 20480, l1b + l * 128, ffb16, 160, 128, 128, 5);
    gemm_bf16<0, 0, 0><<<dim3(5, 215, 1), 256, 0, stream>>>(
        ffb16, l2wb + (size_t)l * 20480, l2b + l * 160, t1, 128, 160, 160, 4);
    k_lnres<<<6880, 256, 0, stream>>>(x, t1, ln2s + l * 160, ln2bb + l * 160, x16);
  }

  k_agg<<<128, 256, 0, stream>>>(x, lens, emb, feat);
  gemm_nt<1><<<dim3(2, 1), 256, 0, stream>>>(feat, m1w, m1b, m1o, 128, 196, 196);
  k_final<<<1, 256, 0, stream>>>(m1o, m2w, m2b, out);
}

// Round 3
// 498.117 us; speedup vs baseline: 3.5487x; 1.1944x over previous
//
#include <hip/hip_runtime.h>
#include <math.h>

#define T_LEN 215
#define B_N   128
#define DINP  36
#define D_TR  160
#define HD    40
#define D_FIN 196
#define AKV   128
#define KPG   864   // 860 padded to mult of 32

typedef __attribute__((ext_vector_type(8))) short short8v;
typedef __attribute__((ext_vector_type(4))) float f32x4;

__device__ __forceinline__ ushort f2bf(float x) {
  union { float f; unsigned u; } c; c.f = x;
  unsigned r = c.u + 0x7fffu + ((c.u >> 16) & 1u);
  return (ushort)(r >> 16);
}

// ---------------- fused weight prep: bf16 conversions + pads + m1w transpose ----------------
__global__ __launch_bounds__(256) void k_prep(const float* __restrict__ Wv1,
    const float* __restrict__ Wv2, const float* __restrict__ ipw, const float* __restrict__ ow,
    const float* __restrict__ l1w, const float* __restrict__ l2w, const float* __restrict__ m1w,
    ushort* __restrict__ wv1b, ushort* __restrict__ wv2b, ushort* __restrict__ ipwb,
    ushort* __restrict__ owb, ushort* __restrict__ l1wb, ushort* __restrict__ l2wb,
    float* __restrict__ m1wT) {
  int i = blockIdx.x * 256 + threadIdx.x;
  if (i < 746496) { int n = i / KPG, k = i % KPG;
    wv1b[i] = (n < 860 && k < 860) ? f2bf(Wv1[n * 860 + k]) : (ushort)0; return; }
  i -= 746496;
  if (i < 746496) { int n = i / KPG, k = i % KPG;
    wv2b[i] = (n < 860 && k < 860) ? f2bf(Wv2[n * 860 + k]) : (ushort)0; return; }
  i -= 746496;
  if (i < 153600) { ipwb[i] = f2bf(ipw[i]); return; }
  i -= 153600;
  if (i < 51200)  { owb[i] = f2bf(ow[i]); return; }
  i -= 51200;
  if (i < 40960)  { l1wb[i] = f2bf(l1w[i]); return; }
  i -= 40960;
  if (i < 40960)  { l2wb[i] = f2bf(l2w[i]); return; }
  i -= 40960;
  if (i < 38416)  { int n = i / 196, k = i % 196; m1wT[k * 196 + n] = m1w[i]; return; }
}

__global__ __launch_bounds__(256) void k_zero(float* __restrict__ p, int n) {
  int i = blockIdx.x * 256 + threadIdx.x;
  if (i < n) p[i] = 0.f;
}

// xb16[b,i, 4t+j] = bf16(relu(src[t,b,i]*R_u[4i+j])), stride KPG, zero-pad cols 860..863
__global__ __launch_bounds__(256) void k_xb16(const float* __restrict__ src,
    const float* __restrict__ R_u, ushort* __restrict__ xb16) {
  int idx = blockIdx.x * 256 + threadIdx.x;
  if (idx >= B_N * DINP * T_LEN) return;
  int t = idx % T_LEN;
  int i = (idx / T_LEN) % DINP;
  int b = idx / (T_LEN * DINP);
  float v = src[((size_t)t * B_N + b) * 72 + i];
  float4 r = ((const float4*)R_u)[i];
  ushort4 o;
  o.x = f2bf(fmaxf(v * r.x, 0.f)); o.y = f2bf(fmaxf(v * r.y, 0.f));
  o.z = f2bf(fmaxf(v * r.z, 0.f)); o.w = f2bf(fmaxf(v * r.w, 0.f));
  ushort* row = xb16 + (size_t)(b * DINP + i) * KPG;
  *(ushort4*)(row + 4 * t) = o;
  if (t == 0) { ushort4 z = {0, 0, 0, 0}; *(ushort4*)(row + 860) = z; }
}

// s1_16[b,n] = bf16( (1/36) sum_i V1[b*36+i, n] ), stride KPG, zero-pad
__global__ __launch_bounds__(256) void k_red_s1(const float* __restrict__ V1, ushort* __restrict__ s1) {
  int idx = blockIdx.x * 256 + threadIdx.x;
  if (idx >= B_N * KPG) return;
  int b = idx / KPG, n = idx % KPG;
  float s = 0.f;
  if (n < 860) {
    #pragma unroll 4
    for (int i = 0; i < DINP; i++) s += V1[((size_t)b * DINP + i) * 860 + n];
    s *= (1.0f / 36.0f);
  }
  s1[idx] = (n < 860) ? f2bf(s) : (ushort)0;
}

// x[t,b,*] (fp32 + bf16) from relu(v2acc + bv2) and inline positional encoding
__global__ __launch_bounds__(256) void k_buildx(const float* __restrict__ v2acc,
    const float* __restrict__ bv2, const float* __restrict__ times,
    float* __restrict__ x, ushort* __restrict__ x16) {
  int idx = blockIdx.x * 256 + threadIdx.x;
  if (idx >= T_LEN * B_N * 40) return;
  int c = idx % 40;
  int r = idx / 40;            // r = t*B + b
  int t = r / B_N, b = r % B_N;
  float4 f;
  if (c < 36) {
    float4 a = *(const float4*)&v2acc[(size_t)b * KPG + 4 * t];
    float4 bb = *(const float4*)&bv2[4 * t];
    f.x = fmaxf(a.x + bb.x, 0.f); f.y = fmaxf(a.y + bb.y, 0.f);
    f.z = fmaxf(a.z + bb.z, 0.f); f.w = fmaxf(a.w + bb.w, 0.f);
  } else {
    float tm = times[r];
    int j0 = (c - 36) * 4;         // 0,4,8,12
    bool is_sin = j0 < 8;
    int kb = j0 & 7;               // 0 or 4
    float o[4];
    #pragma unroll
    for (int qq = 0; qq < 4; qq++) {
      float ts = expf((float)(kb + qq) * 0.76723400f);  // 215^(k/7)
      float sc = tm / ts;
      o[qq] = is_sin ? sinf(sc) : cosf(sc);
    }
    f.x = o[0]; f.y = o[1]; f.z = o[2]; f.w = o[3];
  }
  ((float4*)(x + (size_t)r * D_TR))[c] = f;
  ushort4 h = {f2bf(f.x), f2bf(f.y), f2bf(f.z), f2bf(f.w)};
  *(ushort4*)(x16 + (size_t)r * D_TR + 4 * c) = h;
}

// ---------------- bf16 MFMA GEMM: C = act(A[M,KP] @ W[N,KP]^T + bias) ----------------
template <int RELU, int SPLIT, int WMODE>
__global__ __launch_bounds__(256) void gemm_bf16(const ushort* __restrict__ A,
    const ushort* __restrict__ W, const float* __restrict__ bias, void* __restrict__ Cv,
    int KP, int ldc, int ncols, int kts) {
  __shared__ ushort As[128 * 32];
  __shared__ ushort Ws[32 * 32];
  const int tid = threadIdx.x;
  const int wave = tid >> 6, lane = tid & 63;
  const int lr = lane & 15, hi = lane >> 4;
  const int m0 = blockIdx.y * 128, n0 = blockIdx.x * 32;
  const int kt0 = blockIdx.z * kts;

  f32x4 acc00 = {0.f, 0.f, 0.f, 0.f}, acc01 = acc00, acc10 = acc00, acc11 = acc00;

  const int ar0 = tid >> 2, as0 = tid & 3;
  const size_t abase0 = (size_t)(m0 + ar0) * KP;
  const size_t abase1 = (size_t)(m0 + ar0 + 64) * KP;
  const int awb0 = ar0 * 64 + ((as0 * 16) ^ ((ar0 & 3) << 4));
  const int awb1 = (ar0 + 64) * 64 + ((as0 * 16) ^ (((ar0 + 64) & 3) << 4));
  const size_t bbase = (size_t)(n0 + ar0) * KP;
  const int bwb = ar0 * 64 + ((as0 * 16) ^ ((ar0 & 3) << 4));

  const int arow0 = wave * 32 + lr, arow1 = arow0 + 16;
  const int arb0 = arow0 * 64 + ((hi * 16) ^ ((arow0 & 3) << 4));
  const int arb1 = arow1 * 64 + ((hi * 16) ^ ((arow1 & 3) << 4));
  const int brb0 = lr * 64 + ((hi * 16) ^ ((lr & 3) << 4));
  const int brb1 = (lr + 16) * 64 + ((hi * 16) ^ (((lr + 16) & 3) << 4));

  for (int kt = 0; kt < kts; ++kt) {
    const int k0 = (kt0 + kt) * 32;
    uint4 va0 = *(const uint4*)(A + abase0 + k0 + as0 * 8);
    uint4 va1 = *(const uint4*)(A + abase1 + k0 + as0 * 8);
    uint4 vb;
    if (tid < 128) vb = *(const uint4*)(W + bbase + k0 + as0 * 8);
    if (kt) __syncthreads();
    *(uint4*)((char*)As + awb0) = va0;
    *(uint4*)((char*)As + awb1) = va1;
    if (tid < 128) *(uint4*)((char*)Ws + bwb) = vb;
    __syncthreads();
    short8v a0 = *(const short8v*)((const char*)As + arb0);
    short8v a1 = *(const short8v*)((const char*)As + arb1);
    short8v b0 = *(const short8v*)((const char*)Ws + brb0);
    short8v b1 = *(const short8v*)((const char*)Ws + brb1);
    acc00 = __builtin_amdgcn_mfma_f32_16x16x32_bf16(a0, b0, acc00, 0, 0, 0);
    acc01 = __builtin_amdgcn_mfma_f32_16x16x32_bf16(a0, b1, acc01, 0, 0, 0);
    acc10 = __builtin_amdgcn_mfma_f32_16x16x32_bf16(a1, b0, acc10, 0, 0, 0);
    acc11 = __builtin_amdgcn_mfma_f32_16x16x32_bf16(a1, b1, acc11, 0, 0, 0);
  }

  const int gcol0 = n0 + lr, gcol1 = n0 + 16 + lr;
  const int grow0 = m0 + wave * 32 + hi * 4;

  #pragma unroll
  for (int f = 0; f < 4; f++) {
    f32x4 v = (f == 0) ? acc00 : (f == 1) ? acc01 : (f == 2) ? acc10 : acc11;
    int col = (f & 1) ? gcol1 : gcol0;
    int row = grow0 + ((f >> 1) ? 16 : 0);
    if (col < ncols) {
      if (SPLIT) {
        #pragma unroll
        for (int r = 0; r < 4; r++)
          atomicAdd((float*)Cv + (size_t)(row + r) * ldc + col, v[r]);
      } else {
        float bb = bias ? bias[col] : 0.f;
        #pragma unroll
        for (int r = 0; r < 4; r++) {
          float xv = v[r] + bb;
          if (RELU) xv = fmaxf(xv, 0.f);
          if (WMODE == 0) ((float*)Cv)[(size_t)(row + r) * ldc + col] = xv;
          else            ((ushort*)Cv)[(size_t)(row + r) * ldc + col] = f2bf(xv);
        }
      }
    }
  }
}

// ---------------- attention v2: defer-max, 4-way dot split, float4 LDS broadcasts ----------------
__global__ __launch_bounds__(256) void k_attn(const float* __restrict__ qkv,
    const int* __restrict__ lengths, ushort* __restrict__ o16) {
  __shared__ float4 kl[AKV * 10];
  __shared__ float4 vl[AKV * 10];
  const int b = blockIdx.x >> 2, h = blockIdx.x & 3;
  int L = lengths[b];
  if (L > T_LEN) L = T_LEN;
  const int tq = threadIdx.x;
  const float SC = 0.15811388300841898f;  // 1/sqrt(40)
  float4 q[10], acc[10];
  float m = -1e30f, l = 0.f;
  if (tq < T_LEN) {
    const float4* qp = (const float4*)(qkv + ((size_t)tq * B_N + b) * 480 + h * HD);
    #pragma unroll
    for (int i = 0; i < 10; i++) {
      float4 t = qp[i];
      q[i].x = t.x * SC; q[i].y = t.y * SC; q[i].z = t.z * SC; q[i].w = t.w * SC;
      acc[i].x = 0.f; acc[i].y = 0.f; acc[i].z = 0.f; acc[i].w = 0.f;
    }
  }
  const int sr = threadIdx.x >> 1, sh = threadIdx.x & 1;
  for (int c0 = 0; c0 < L; c0 += AKV) {
    const int cn = min(AKV, L - c0);
    __syncthreads();
    if (sr < cn) {
      const float4* kp = (const float4*)(qkv + ((size_t)(c0 + sr) * B_N + b) * 480 + 160 + h * HD) + sh * 5;
      #pragma unroll
      for (int i = 0; i < 5; i++) {
        kl[sr * 10 + sh * 5 + i] = kp[i];
        vl[sr * 10 + sh * 5 + i] = kp[i + 40];   // V is +160 floats = +40 float4
      }
    }
    __syncthreads();
    if (tq < T_LEN) {
      for (int tk = 0; tk < cn; ++tk) {
        const float4* kp = &kl[tk * 10];
        float sa = 0.f, sb = 0.f, sc2 = 0.f, sd = 0.f;
        #pragma unroll
        for (int i = 0; i < 10; i++) {
          float4 kv = kp[i];
          sa  = fmaf(q[i].x, kv.x, sa);
          sb  = fmaf(q[i].y, kv.y, sb);
          sc2 = fmaf(q[i].z, kv.z, sc2);
          sd  = fmaf(q[i].w, kv.w, sd);
        }
        float s = (sa + sb) + (sc2 + sd);
        const float4* vp = &vl[tk * 10];
        if (__builtin_expect(s - m > 8.0f, 0)) {
          float f = __expf(m - s);
          m = s;
          l = fmaf(l, f, 1.f);
          #pragma unroll
          for (int i = 0; i < 10; i++) {
            float4 vv = vp[i];
            acc[i].x = fmaf(acc[i].x, f, vv.x);
            acc[i].y = fmaf(acc[i].y, f, vv.y);
            acc[i].z = fmaf(acc[i].z, f, vv.z);
            acc[i].w = fmaf(acc[i].w, f, vv.w);
          }
        } else {
          float p = __expf(s - m);
          l += p;
          #pragma unroll
          for (int i = 0; i < 10; i++) {
            float4 vv = vp[i];
            acc[i].x = fmaf(p, vv.x, acc[i].x);
            acc[i].y = fmaf(p, vv.y, acc[i].y);
            acc[i].z = fmaf(p, vv.z, acc[i].z);
            acc[i].w = fmaf(p, vv.w, acc[i].w);
          }
        }
      }
    }
  }
  if (tq < T_LEN) {
    float inv = 1.0f / l;
    ushort* op = o16 + ((size_t)tq * B_N + b) * D_TR + h * HD;
    #pragma unroll
    for (int i = 0; i < 10; i++) {
      ushort4 hv;
      hv.x = f2bf(acc[i].x * inv); hv.y = f2bf(acc[i].y * inv);
      hv.z = f2bf(acc[i].z * inv); hv.w = f2bf(acc[i].w * inv);
      *(ushort4*)(op + i * 4) = hv;
    }
  }
}

// ---------------- fused residual + LayerNorm (writes fp32 x and bf16 x16) ----------------
__global__ __launch_bounds__(256) void k_lnres(float* __restrict__ x,
    const float* __restrict__ delta, const float* __restrict__ gam,
    const float* __restrict__ bet, ushort* __restrict__ x16) {
  int wid = (blockIdx.x * 256 + threadIdx.x) >> 6;
  int lane = threadIdx.x & 63;
  if (wid >= T_LEN * B_N) return;
  float* xr = x + (size_t)wid * D_TR;
  ushort* hr = x16 + (size_t)wid * D_TR;
  const float* dr = delta + (size_t)wid * D_TR;
  float a0 = xr[lane] + dr[lane];
  float a1 = xr[lane + 64] + dr[lane + 64];
  float a2 = (lane < 32) ? (xr[lane + 128] + dr[lane + 128]) : 0.f;
  float s = a0 + a1 + a2;
  #pragma unroll
  for (int off = 32; off; off >>= 1) s += __shfl_xor(s, off, 64);
  float mu = s * (1.0f / 160.0f);
  float d0 = a0 - mu, d1 = a1 - mu, d2 = (lane < 32) ? (a2 - mu) : 0.f;
  float sq = d0 * d0 + d1 * d1 + d2 * d2;
  #pragma unroll
  for (int off = 32; off; off >>= 1) sq += __shfl_xor(sq, off, 64);
  float rstd = rsqrtf(sq * (1.0f / 160.0f) + 1e-5f);
  float o0 = d0 * rstd * gam[lane] + bet[lane];
  float o1 = d1 * rstd * gam[lane + 64] + bet[lane + 64];
  xr[lane] = o0;      hr[lane] = f2bf(o0);
  xr[lane + 64] = o1; hr[lane + 64] = f2bf(o1);
  if (lane < 32) {
    float o2 = d2 * rstd * gam[lane + 128] + bet[lane + 128];
    xr[lane + 128] = o2; hr[lane + 128] = f2bf(o2);
  }
}

// ---------------- fused head: masked mean + emb + mlp1 + mlp2 + distance ----------------
__global__ __launch_bounds__(256) void k_head(const float* __restrict__ x,
    const int* __restrict__ lengths, const float* __restrict__ stat,
    const float* __restrict__ emb_w, const float* __restrict__ emb_b,
    const float* __restrict__ m1wT, const float* __restrict__ m1b,
    const float* __restrict__ m2w, const float* __restrict__ m2b,
    float* __restrict__ out) {
  __shared__ float feat[196];
  __shared__ float m1o[196];
  __shared__ float r0[4], r1[4];
  const int b = blockIdx.x, tid = threadIdx.x;
  int L = lengths[b];
  if (L > T_LEN) L = T_LEN;
  if (tid < D_TR) {
    float s = 0.f;
    for (int t = 0; t < L; t++) s += x[((size_t)t * B_N + b) * D_TR + tid];
    feat[tid] = s / (float)(L + 1);
  } else if (tid < D_FIN) {
    int i = tid - D_TR;
    float s = emb_b[i];
    #pragma unroll
    for (int k = 0; k < 9; k++) s = fmaf(stat[b * 9 + k], emb_w[i * 9 + k], s);
    feat[tid] = s;
  }
  __syncthreads();
  if (tid < D_FIN) {
    float s = m1b[tid];
    for (int k = 0; k < D_FIN; k++) s = fmaf(feat[k], m1wT[k * D_FIN + tid], s);
    m1o[tid] = fmaxf(s, 0.f);
  }
  __syncthreads();
  float p0 = 0.f, p1 = 0.f;
  if (tid < D_FIN) {
    p0 = m1o[tid] * m2w[tid];
    p1 = m1o[tid] * m2w[D_FIN + tid];
  }
  #pragma unroll
  for (int off = 32; off; off >>= 1) {
    p0 += __shfl_xor(p0, off, 64);
    p1 += __shfl_xor(p1, off, 64);
  }
  int w = tid >> 6;
  if ((tid & 63) == 0) { r0[w] = p0; r1[w] = p1; }
  __syncthreads();
  if (tid == 0) out[2 * b]     = r0[0] + r0[1] + r0[2] + r0[3] + m2b[0];
  if (tid == 1) out[2 * b + 1] = r1[0] + r1[1] + r1[2] + r1[3] + m2b[1];
  if (b == 0 && tid == 2) out[256] = 0.f;  // distance == 0 exactly
}

// ---------------- launch ----------------
extern "C" void kernel_launch(void* const* d_in, const int* in_sizes, int n_in,
                              void* d_out, int out_size, void* d_ws, size_t ws_size,
                              hipStream_t stream) {
  const float* src   = (const float*)d_in[0];
  const float* stat  = (const float*)d_in[1];
  const float* times = (const float*)d_in[2];
  const int*   lens  = (const int*)d_in[3];
  const float* R_u   = (const float*)d_in[4];
  const float* emb_w = (const float*)d_in[5];
  const float* emb_b = (const float*)d_in[6];
  const float* Wv1   = (const float*)d_in[7];
  const float* bv1   = (const float*)d_in[8];
  const float* Wv2   = (const float*)d_in[9];
  const float* bv2   = (const float*)d_in[10];
  const float* ipw   = (const float*)d_in[11];
  const float* ipb   = (const float*)d_in[12];
  const float* ow    = (const float*)d_in[13];
  const float* ob    = (const float*)d_in[14];
  const float* l1w   = (const float*)d_in[15];
  const float* l1b   = (const float*)d_in[16];
  const float* l2w   = (const float*)d_in[17];
  const float* l2b   = (const float*)d_in[18];
  const float* ln1s  = (const float*)d_in[19];
  const float* ln1bb = (const float*)d_in[20];
  const float* ln2s  = (const float*)d_in[21];
  const float* ln2bb = (const float*)d_in[22];
  const float* m1w   = (const float*)d_in[23];
  const float* m1b   = (const float*)d_in[24];
  const float* m2w   = (const float*)d_in[25];
  const float* m2b   = (const float*)d_in[26];
  float* out = (float*)d_out;

  // ---- workspace layout (bytes) ----
  char* p = (char*)d_ws;
  float*  x      = (float*)p;   p += 17612800;  // 27520 x 160 fp32
  ushort* x16    = (ushort*)p;  p += 8806400;   // 27520 x 160 bf16
  float*  v2acc  = (float*)p;   p += 442368;    // 128 x 864 fp32
  ushort* s1b    = (ushort*)p;  p += 221184;    // 128 x 864 bf16
  ushort* obuf16 = (ushort*)p;  p += 8806400;   // 27520 x 160 bf16
  ushort* wv1b   = (ushort*)p;  p += 1492992;   // 864 x 864 bf16
  ushort* wv2b   = (ushort*)p;  p += 1492992;
  ushort* ipwb   = (ushort*)p;  p += 307200;    // 2 x 480 x 160
  ushort* owb    = (ushort*)p;  p += 102400;    // 2 x 160 x 160
  ushort* l1wb   = (ushort*)p;  p += 81920;     // 2 x 128 x 160
  ushort* l2wb   = (ushort*)p;  p += 81920;     // 2 x 160 x 128
  float*  m1wT   = (float*)p;   p += 153664;    // 196 x 196 fp32 transposed
  char*   R2     = p;                           // shared big region (~52.9 MB)
  ushort* xb16   = (ushort*)R2;                 // phase A: 4608 x 864 bf16
  float*  V1     = (float*)(R2 + 7962624);      // phase A: 4608 x 860 fp32
  float*  qkvb   = (float*)R2;                  // phase B: 27520 x 480 fp32
  float*  t1     = (float*)R2;                  // post-attn: 27520 x 160 fp32
  ushort* ffb16  = (ushort*)(R2 + 17612800);    // 27520 x 128 bf16

  k_prep<<<7103, 256, 0, stream>>>(Wv1, Wv2, ipw, ow, l1w, l2w, m1w,
                                   wv1b, wv2b, ipwb, owb, l1wb, l2wb, m1wT);
  k_xb16<<<3870, 256, 0, stream>>>(src, R_u, xb16);

  // V1 = relu(xb @ Wv1^T + bv1)
  gemm_bf16<1, 0, 0><<<dim3(27, 36, 1), 256, 0, stream>>>(xb16, wv1b, bv1, V1, KPG, 860, 860, 27);
  k_red_s1<<<432, 256, 0, stream>>>(V1, s1b);
  k_zero<<<432, 256, 0, stream>>>(v2acc, 110592);
  gemm_bf16<0, 1, 0><<<dim3(27, 1, 3), 256, 0, stream>>>(s1b, wv2b, nullptr, v2acc, KPG, KPG, KPG, 9);
  k_buildx<<<4300, 256, 0, stream>>>(v2acc, bv2, times, x, x16);

  for (int l = 0; l < 2; l++) {
    gemm_bf16<0, 0, 0><<<dim3(15, 215, 1), 256, 0, stream>>>(
        x16, ipwb + (size_t)l * 76800, ipb + l * 480, qkvb, 160, 480, 480, 5);
    k_attn<<<512, 256, 0, stream>>>(qkvb, lens, obuf16);
    gemm_bf16<0, 0, 0><<<dim3(5, 215, 1), 256, 0, stream>>>(
        obuf16, owb + (size_t)l * 25600, ob + l * 160, t1, 160, 160, 160, 5);
    k_lnres<<<6880, 256, 0, stream>>>(x, t1, ln1s + l * 160, ln1bb + l * 160, x16);
    gemm_bf16<1, 0, 1><<<dim3(4, 215, 1), 256, 0, stream>>>(
        x16, l1wb + (size_t)l * 20480, l1b + l * 128, ffb16, 160, 128, 128, 5);
    gemm_bf16<0, 0, 0><<<dim3(5, 215, 1), 256, 0, stream>>>(
        ffb16, l2wb + (size_t)l * 20480, l2b + l * 160, t1, 128, 160, 160, 4);
    k_lnres<<<6880, 256, 0, stream>>>(x, t1, ln2s + l * 160, ln2bb + l * 160, x16);
  }

  k_head<<<128, 256, 0, stream>>>(x, lens, stat, emb_w, emb_b, m1wT, m1b, m2w, m2b, out);
}

// Round 4
// 391.216 us; speedup vs baseline: 4.5184x; 1.2733x over previous
//
#include <hip/hip_runtime.h>
#include <math.h>

#define T_LEN 215
#define B_N   128
#define DINP  36
#define D_TR  160
#define HD    40
#define D_FIN 196
#define KPG   864   // 860 padded to mult of 32
#define ALD   232   // S/P and Vt row stride in elems (bf16); 464 B

typedef __attribute__((ext_vector_type(8))) short short8v;
typedef __attribute__((ext_vector_type(4))) float f32x4;

__device__ __forceinline__ ushort f2bf(float x) {
  union { float f; unsigned u; } c; c.f = x;
  unsigned r = c.u + 0x7fffu + ((c.u >> 16) & 1u);
  return (ushort)(r >> 16);
}
__device__ __forceinline__ float bf2f(ushort h) {
  union { unsigned u; float f; } c; c.u = ((unsigned)h) << 16;
  return c.f;
}

// ---------------- fused weight prep: bf16 conversions + pads + m1w transpose ----------------
__global__ __launch_bounds__(256) void k_prep(const float* __restrict__ Wv1,
    const float* __restrict__ Wv2, const float* __restrict__ ipw, const float* __restrict__ ow,
    const float* __restrict__ l1w, const float* __restrict__ l2w, const float* __restrict__ m1w,
    ushort* __restrict__ wv1b, ushort* __restrict__ wv2b, ushort* __restrict__ ipwb,
    ushort* __restrict__ owb, ushort* __restrict__ l1wb, ushort* __restrict__ l2wb,
    float* __restrict__ m1wT) {
  int i = blockIdx.x * 256 + threadIdx.x;
  if (i < 746496) { int n = i / KPG, k = i % KPG;
    wv1b[i] = (n < 860 && k < 860) ? f2bf(Wv1[n * 860 + k]) : (ushort)0; return; }
  i -= 746496;
  if (i < 746496) { int n = i / KPG, k = i % KPG;
    wv2b[i] = (n < 860 && k < 860) ? f2bf(Wv2[n * 860 + k]) : (ushort)0; return; }
  i -= 746496;
  if (i < 153600) { ipwb[i] = f2bf(ipw[i]); return; }
  i -= 153600;
  if (i < 51200)  { owb[i] = f2bf(ow[i]); return; }
  i -= 51200;
  if (i < 40960)  { l1wb[i] = f2bf(l1w[i]); return; }
  i -= 40960;
  if (i < 40960)  { l2wb[i] = f2bf(l2w[i]); return; }
  i -= 40960;
  if (i < 38416)  { int n = i / 196, k = i % 196; m1wT[k * 196 + n] = m1w[i]; return; }
}

__global__ __launch_bounds__(256) void k_zero(float* __restrict__ p, int n) {
  int i = blockIdx.x * 256 + threadIdx.x;
  if (i < n) p[i] = 0.f;
}

// xb16[b,i, 4t+j] = bf16(relu(src[t,b,i]*R_u[4i+j])), stride KPG, zero-pad cols 860..863
__global__ __launch_bounds__(256) void k_xb16(const float* __restrict__ src,
    const float* __restrict__ R_u, ushort* __restrict__ xb16) {
  int idx = blockIdx.x * 256 + threadIdx.x;
  if (idx >= B_N * DINP * T_LEN) return;
  int t = idx % T_LEN;
  int i = (idx / T_LEN) % DINP;
  int b = idx / (T_LEN * DINP);
  float v = src[((size_t)t * B_N + b) * 72 + i];
  float4 r = ((const float4*)R_u)[i];
  ushort4 o;
  o.x = f2bf(fmaxf(v * r.x, 0.f)); o.y = f2bf(fmaxf(v * r.y, 0.f));
  o.z = f2bf(fmaxf(v * r.z, 0.f)); o.w = f2bf(fmaxf(v * r.w, 0.f));
  ushort* row = xb16 + (size_t)(b * DINP + i) * KPG;
  *(ushort4*)(row + 4 * t) = o;
  if (t == 0) { ushort4 z = {0, 0, 0, 0}; *(ushort4*)(row + 860) = z; }
}

// s1_16[b,n] = bf16( (1/36) sum_i V1[b*36+i, n] ), stride KPG, zero-pad
__global__ __launch_bounds__(256) void k_red_s1(const float* __restrict__ V1, ushort* __restrict__ s1) {
  int idx = blockIdx.x * 256 + threadIdx.x;
  if (idx >= B_N * KPG) return;
  int b = idx / KPG, n = idx % KPG;
  float s = 0.f;
  if (n < 860) {
    #pragma unroll 4
    for (int i = 0; i < DINP; i++) s += V1[((size_t)b * DINP + i) * 860 + n];
    s *= (1.0f / 36.0f);
  }
  s1[idx] = (n < 860) ? f2bf(s) : (ushort)0;
}

// x[t,b,*] (fp32 + bf16) from relu(v2acc + bv2) and inline positional encoding
__global__ __launch_bounds__(256) void k_buildx(const float* __restrict__ v2acc,
    const float* __restrict__ bv2, const float* __restrict__ times,
    float* __restrict__ x, ushort* __restrict__ x16) {
  int idx = blockIdx.x * 256 + threadIdx.x;
  if (idx >= T_LEN * B_N * 40) return;
  int c = idx % 40;
  int r = idx / 40;            // r = t*B + b
  int t = r / B_N, b = r % B_N;
  float4 f;
  if (c < 36) {
    float4 a = *(const float4*)&v2acc[(size_t)b * KPG + 4 * t];
    float4 bb = *(const float4*)&bv2[4 * t];
    f.x = fmaxf(a.x + bb.x, 0.f); f.y = fmaxf(a.y + bb.y, 0.f);
    f.z = fmaxf(a.z + bb.z, 0.f); f.w = fmaxf(a.w + bb.w, 0.f);
  } else {
    float tm = times[r];
    int j0 = (c - 36) * 4;         // 0,4,8,12
    bool is_sin = j0 < 8;
    int kb = j0 & 7;               // 0 or 4
    float o[4];
    #pragma unroll
    for (int qq = 0; qq < 4; qq++) {
      float ts = expf((float)(kb + qq) * 0.76723400f);  // 215^(k/7)
      float sc = tm / ts;
      o[qq] = is_sin ? sinf(sc) : cosf(sc);
    }
    f.x = o[0]; f.y = o[1]; f.z = o[2]; f.w = o[3];
  }
  ((float4*)(x + (size_t)r * D_TR))[c] = f;
  ushort4 h = {f2bf(f.x), f2bf(f.y), f2bf(f.z), f2bf(f.w)};
  *(ushort4*)(x16 + (size_t)r * D_TR + 4 * c) = h;
}

// ---------------- bf16 MFMA GEMM: C = act(A[M,KP] @ W[N,KP]^T + bias) ----------------
template <int RELU, int SPLIT, int WMODE>
__global__ __launch_bounds__(256) void gemm_bf16(const ushort* __restrict__ A,
    const ushort* __restrict__ W, const float* __restrict__ bias, void* __restrict__ Cv,
    int KP, int ldc, int ncols, int kts) {
  __shared__ ushort As[128 * 32];
  __shared__ ushort Ws[32 * 32];
  const int tid = threadIdx.x;
  const int wave = tid >> 6, lane = tid & 63;
  const int lr = lane & 15, hi = lane >> 4;
  const int m0 = blockIdx.y * 128, n0 = blockIdx.x * 32;
  const int kt0 = blockIdx.z * kts;

  f32x4 acc00 = {0.f, 0.f, 0.f, 0.f}, acc01 = acc00, acc10 = acc00, acc11 = acc00;

  const int ar0 = tid >> 2, as0 = tid & 3;
  const size_t abase0 = (size_t)(m0 + ar0) * KP;
  const size_t abase1 = (size_t)(m0 + ar0 + 64) * KP;
  const int awb0 = ar0 * 64 + ((as0 * 16) ^ ((ar0 & 3) << 4));
  const int awb1 = (ar0 + 64) * 64 + ((as0 * 16) ^ (((ar0 + 64) & 3) << 4));
  const size_t bbase = (size_t)(n0 + ar0) * KP;
  const int bwb = ar0 * 64 + ((as0 * 16) ^ ((ar0 & 3) << 4));

  const int arow0 = wave * 32 + lr, arow1 = arow0 + 16;
  const int arb0 = arow0 * 64 + ((hi * 16) ^ ((arow0 & 3) << 4));
  const int arb1 = arow1 * 64 + ((hi * 16) ^ ((arow1 & 3) << 4));
  const int brb0 = lr * 64 + ((hi * 16) ^ ((lr & 3) << 4));
  const int brb1 = (lr + 16) * 64 + ((hi * 16) ^ (((lr + 16) & 3) << 4));

  for (int kt = 0; kt < kts; ++kt) {
    const int k0 = (kt0 + kt) * 32;
    uint4 va0 = *(const uint4*)(A + abase0 + k0 + as0 * 8);
    uint4 va1 = *(const uint4*)(A + abase1 + k0 + as0 * 8);
    uint4 vb;
    if (tid < 128) vb = *(const uint4*)(W + bbase + k0 + as0 * 8);
    if (kt) __syncthreads();
    *(uint4*)((char*)As + awb0) = va0;
    *(uint4*)((char*)As + awb1) = va1;
    if (tid < 128) *(uint4*)((char*)Ws + bwb) = vb;
    __syncthreads();
    short8v a0 = *(const short8v*)((const char*)As + arb0);
    short8v a1 = *(const short8v*)((const char*)As + arb1);
    short8v b0 = *(const short8v*)((const char*)Ws + brb0);
    short8v b1 = *(const short8v*)((const char*)Ws + brb1);
    acc00 = __builtin_amdgcn_mfma_f32_16x16x32_bf16(a0, b0, acc00, 0, 0, 0);
    acc01 = __builtin_amdgcn_mfma_f32_16x16x32_bf16(a0, b1, acc01, 0, 0, 0);
    acc10 = __builtin_amdgcn_mfma_f32_16x16x32_bf16(a1, b0, acc10, 0, 0, 0);
    acc11 = __builtin_amdgcn_mfma_f32_16x16x32_bf16(a1, b1, acc11, 0, 0, 0);
  }

  const int gcol0 = n0 + lr, gcol1 = n0 + 16 + lr;
  const int grow0 = m0 + wave * 32 + hi * 4;

  #pragma unroll
  for (int f = 0; f < 4; f++) {
    f32x4 v = (f == 0) ? acc00 : (f == 1) ? acc01 : (f == 2) ? acc10 : acc11;
    int col = (f & 1) ? gcol1 : gcol0;
    int row = grow0 + ((f >> 1) ? 16 : 0);
    if (col < ncols) {
      if (SPLIT) {
        #pragma unroll
        for (int r = 0; r < 4; r++)
          atomicAdd((float*)Cv + (size_t)(row + r) * ldc + col, v[r]);
      } else {
        float bb = bias ? bias[col] : 0.f;
        #pragma unroll
        for (int r = 0; r < 4; r++) {
          float xv = v[r] + bb;
          if (RELU) xv = fmaxf(xv, 0.f);
          if (WMODE == 0) ((float*)Cv)[(size_t)(row + r) * ldc + col] = xv;
          else            ((ushort*)Cv)[(size_t)(row + r) * ldc + col] = f2bf(xv);
        }
      }
    }
  }
}

// ---------------- MFMA flash attention: block = (b*4+h, qtile of 128), 8 waves ----------------
// qkv is bf16 [t][b][480] (q|k|v). S,P bf16 in LDS; 1/sqrt(40) folded into softmax exp.
__global__ __launch_bounds__(512) void k_attn2(const ushort* __restrict__ qkv,
    const int* __restrict__ lengths, ushort* __restrict__ o16) {
  __shared__ ushort Qs[128 * 64];     // swizzled rows of 128B          16 KB
  __shared__ ushort Ks[224 * 64];     // swizzled rows of 128B          28.7 KB
  __shared__ ushort Vt[48 * ALD];     // [d][key]                       22.3 KB
  __shared__ ushort SP[128 * ALD];    // S then P (in-place)            59.4 KB
  __shared__ float lsum[128];
  const int bh = blockIdx.x;
  const int b = bh >> 2, h = bh & 3;
  const int q0 = blockIdx.y * 128;
  int L = lengths[b]; if (L > T_LEN) L = T_LEN;
  const int nkt = (L + 31) >> 5;      // 32-key tiles (1..7)
  const int tid = threadIdx.x;
  const int wv = tid >> 6, lane = tid & 63, lr = lane & 15, hi = lane >> 4;
  const float SC = 0.15811388300841898f;  // 1/sqrt(40)

  // phase 0: zero Vt (padded keys / d must be 0, stale LDS may be NaN)
  for (int i = tid; i < 48 * ALD / 8; i += 512) ((uint4*)Vt)[i] = (uint4){0, 0, 0, 0};
  __syncthreads();

  // phase 1: stage K (rows < nkt*32), Q (128 rows), fill Vt[d][key]
  for (int i = tid; i < nkt * 256; i += 512) {       // nkt*32 rows * 8 granules
    int row = i >> 3, g = i & 7;
    uint4 v = {0, 0, 0, 0};
    if (g < 5 && row < T_LEN)
      v = *(const uint4*)(qkv + ((size_t)row * B_N + b) * 480 + 160 + h * 40 + g * 8);
    *(uint4*)((char*)Ks + row * 128 + ((g * 16) ^ ((row & 7) << 4))) = v;
  }
  for (int i = tid; i < 128 * 8; i += 512) {
    int row = i >> 3, g = i & 7;
    int t = q0 + row;
    uint4 v = {0, 0, 0, 0};
    if (g < 5 && t < T_LEN)
      v = *(const uint4*)(qkv + ((size_t)t * B_N + b) * 480 + h * 40 + g * 8);
    *(uint4*)((char*)Qs + row * 128 + ((g * 16) ^ ((row & 7) << 4))) = v;
  }
  for (int i = tid; i < L * 40; i += 512) {
    int key = i / 40, d = i - key * 40;
    Vt[d * ALD + key] = qkv[((size_t)key * B_N + b) * 480 + 320 + h * 40 + d];
  }
  __syncthreads();

  // phase 2: S = Q @ K^T  (per wave: 16 q rows, nkt*2 key tiles of 16)
  {
    const int qrow = wv * 16 + lr;
    short8v qa0 = *(const short8v*)((char*)Qs + qrow * 128 + ((hi * 16) ^ ((qrow & 7) << 4)));
    short8v qa1 = *(const short8v*)((char*)Qs + qrow * 128 + (((64 + hi * 16)) ^ ((qrow & 7) << 4)));
    const int nk16 = nkt * 2;
    for (int kt = 0; kt < nk16; ++kt) {
      int krow = kt * 16 + lr;
      short8v kb0 = *(const short8v*)((char*)Ks + krow * 128 + ((hi * 16) ^ ((krow & 7) << 4)));
      short8v kb1 = *(const short8v*)((char*)Ks + krow * 128 + (((64 + hi * 16)) ^ ((krow & 7) << 4)));
      f32x4 c = {0.f, 0.f, 0.f, 0.f};
      c = __builtin_amdgcn_mfma_f32_16x16x32_bf16(qa0, kb0, c, 0, 0, 0);
      c = __builtin_amdgcn_mfma_f32_16x16x32_bf16(qa1, kb1, c, 0, 0, 0);
      #pragma unroll
      for (int r = 0; r < 4; r++)
        SP[(wv * 16 + hi * 4 + r) * ALD + kt * 16 + lr] = f2bf(c[r]);
    }
  }
  __syncthreads();

  // phase 3: masked softmax in-place on SP (4 threads per row)
  {
    const int row = tid >> 2, c4 = tid & 3;
    const int ncol4 = nkt * 8;
    ushort* sr = SP + row * ALD;
    float m = -1e30f;
    for (int j = c4; j < ncol4; j += 4) {
      ushort4 sv = *(const ushort4*)(sr + j * 4);
      int col = j * 4;
      float s0 = (col < L)     ? bf2f(sv.x) : -1e30f;
      float s1 = (col + 1 < L) ? bf2f(sv.y) : -1e30f;
      float s2 = (col + 2 < L) ? bf2f(sv.z) : -1e30f;
      float s3 = (col + 3 < L) ? bf2f(sv.w) : -1e30f;
      m = fmaxf(m, fmaxf(fmaxf(s0, s1), fmaxf(s2, s3)));
    }
    m = fmaxf(m, __shfl_xor(m, 1, 64));
    m = fmaxf(m, __shfl_xor(m, 2, 64));
    float sum = 0.f;
    for (int j = c4; j < ncol4; j += 4) {
      ushort4 sv = *(const ushort4*)(sr + j * 4);
      int col = j * 4;
      float p0 = (col < L)     ? __expf(SC * (bf2f(sv.x) - m)) : 0.f;
      float p1 = (col + 1 < L) ? __expf(SC * (bf2f(sv.y) - m)) : 0.f;
      float p2 = (col + 2 < L) ? __expf(SC * (bf2f(sv.z) - m)) : 0.f;
      float p3 = (col + 3 < L) ? __expf(SC * (bf2f(sv.w) - m)) : 0.f;
      sum += (p0 + p1) + (p2 + p3);
      ushort4 pv = {f2bf(p0), f2bf(p1), f2bf(p2), f2bf(p3)};
      *(ushort4*)(sr + j * 4) = pv;
    }
    sum += __shfl_xor(sum, 1, 64);
    sum += __shfl_xor(sum, 2, 64);
    if (c4 == 0) lsum[row] = sum;
  }
  __syncthreads();

  // phase 4: O = P @ Vt^T (per wave: 16 q rows x 48 d cols), scale 1/sum, store
  {
    f32x4 o0 = {0.f, 0.f, 0.f, 0.f}, o1 = o0, o2 = o0;
    for (int kt = 0; kt < nkt; ++kt) {
      short8v pa = *(const short8v*)((char*)SP + (wv * 16 + lr) * 464 + kt * 64 + hi * 16);
      short8v v0 = *(const short8v*)((char*)Vt + lr * 464 + kt * 64 + hi * 16);
      short8v v1 = *(const short8v*)((char*)Vt + (16 + lr) * 464 + kt * 64 + hi * 16);
      short8v v2 = *(const short8v*)((char*)Vt + (32 + lr) * 464 + kt * 64 + hi * 16);
      o0 = __builtin_amdgcn_mfma_f32_16x16x32_bf16(pa, v0, o0, 0, 0, 0);
      o1 = __builtin_amdgcn_mfma_f32_16x16x32_bf16(pa, v1, o1, 0, 0, 0);
      o2 = __builtin_amdgcn_mfma_f32_16x16x32_bf16(pa, v2, o2, 0, 0, 0);
    }
    #pragma unroll
    for (int r = 0; r < 4; r++) {
      int qr = wv * 16 + hi * 4 + r;
      int t = q0 + qr;
      if (t < T_LEN) {
        float inv = 1.0f / lsum[qr];
        ushort* op = o16 + ((size_t)t * B_N + b) * D_TR + h * 40;
        op[lr] = f2bf(o0[r] * inv);
        op[16 + lr] = f2bf(o1[r] * inv);
        if (lr < 8) op[32 + lr] = f2bf(o2[r] * inv);
      }
    }
  }
}

// ---------------- fused residual + LayerNorm (writes fp32 x and bf16 x16) ----------------
__global__ __launch_bounds__(256) void k_lnres(float* __restrict__ x,
    const float* __restrict__ delta, const float* __restrict__ gam,
    const float* __restrict__ bet, ushort* __restrict__ x16) {
  int wid = (blockIdx.x * 256 + threadIdx.x) >> 6;
  int lane = threadIdx.x & 63;
  if (wid >= T_LEN * B_N) return;
  float* xr = x + (size_t)wid * D_TR;
  ushort* hr = x16 + (size_t)wid * D_TR;
  const float* dr = delta + (size_t)wid * D_TR;
  float a0 = xr[lane] + dr[lane];
  float a1 = xr[lane + 64] + dr[lane + 64];
  float a2 = (lane < 32) ? (xr[lane + 128] + dr[lane + 128]) : 0.f;
  float s = a0 + a1 + a2;
  #pragma unroll
  for (int off = 32; off; off >>= 1) s += __shfl_xor(s, off, 64);
  float mu = s * (1.0f / 160.0f);
  float d0 = a0 - mu, d1 = a1 - mu, d2 = (lane < 32) ? (a2 - mu) : 0.f;
  float sq = d0 * d0 + d1 * d1 + d2 * d2;
  #pragma unroll
  for (int off = 32; off; off >>= 1) sq += __shfl_xor(sq, off, 64);
  float rstd = rsqrtf(sq * (1.0f / 160.0f) + 1e-5f);
  float o0 = d0 * rstd * gam[lane] + bet[lane];
  float o1 = d1 * rstd * gam[lane + 64] + bet[lane + 64];
  xr[lane] = o0;      hr[lane] = f2bf(o0);
  xr[lane + 64] = o1; hr[lane + 64] = f2bf(o1);
  if (lane < 32) {
    float o2 = d2 * rstd * gam[lane + 128] + bet[lane + 128];
    xr[lane + 128] = o2; hr[lane + 128] = f2bf(o2);
  }
}

// ---------------- fused head: masked mean + emb + mlp1 + mlp2 + distance ----------------
__global__ __launch_bounds__(256) void k_head(const float* __restrict__ x,
    const int* __restrict__ lengths, const float* __restrict__ stat,
    const float* __restrict__ emb_w, const float* __restrict__ emb_b,
    const float* __restrict__ m1wT, const float* __restrict__ m1b,
    const float* __restrict__ m2w, const float* __restrict__ m2b,
    float* __restrict__ out) {
  __shared__ float feat[196];
  __shared__ float m1o[196];
  __shared__ float r0[4], r1[4];
  const int b = blockIdx.x, tid = threadIdx.x;
  int L = lengths[b];
  if (L > T_LEN) L = T_LEN;
  if (tid < D_TR) {
    float s = 0.f;
    for (int t = 0; t < L; t++) s += x[((size_t)t * B_N + b) * D_TR + tid];
    feat[tid] = s / (float)(L + 1);
  } else if (tid < D_FIN) {
    int i = tid - D_TR;
    float s = emb_b[i];
    #pragma unroll
    for (int k = 0; k < 9; k++) s = fmaf(stat[b * 9 + k], emb_w[i * 9 + k], s);
    feat[tid] = s;
  }
  __syncthreads();
  if (tid < D_FIN) {
    float s = m1b[tid];
    for (int k = 0; k < D_FIN; k++) s = fmaf(feat[k], m1wT[k * D_FIN + tid], s);
    m1o[tid] = fmaxf(s, 0.f);
  }
  __syncthreads();
  float p0 = 0.f, p1 = 0.f;
  if (tid < D_FIN) {
    p0 = m1o[tid] * m2w[tid];
    p1 = m1o[tid] * m2w[D_FIN + tid];
  }
  #pragma unroll
  for (int off = 32; off; off >>= 1) {
    p0 += __shfl_xor(p0, off, 64);
    p1 += __shfl_xor(p1, off, 64);
  }
  int w = tid >> 6;
  if ((tid & 63) == 0) { r0[w] = p0; r1[w] = p1; }
  __syncthreads();
  if (tid == 0) out[2 * b]     = r0[0] + r0[1] + r0[2] + r0[3] + m2b[0];
  if (tid == 1) out[2 * b + 1] = r1[0] + r1[1] + r1[2] + r1[3] + m2b[1];
  if (b == 0 && tid == 2) out[256] = 0.f;  // distance == 0 exactly
}

// ---------------- launch ----------------
extern "C" void kernel_launch(void* const* d_in, const int* in_sizes, int n_in,
                              void* d_out, int out_size, void* d_ws, size_t ws_size,
                              hipStream_t stream) {
  const float* src   = (const float*)d_in[0];
  const float* stat  = (const float*)d_in[1];
  const float* times = (const float*)d_in[2];
  const int*   lens  = (const int*)d_in[3];
  const float* R_u   = (const float*)d_in[4];
  const float* emb_w = (const float*)d_in[5];
  const float* emb_b = (const float*)d_in[6];
  const float* Wv1   = (const float*)d_in[7];
  const float* bv1   = (const float*)d_in[8];
  const float* Wv2   = (const float*)d_in[9];
  const float* bv2   = (const float*)d_in[10];
  const float* ipw   = (const float*)d_in[11];
  const float* ipb   = (const float*)d_in[12];
  const float* ow    = (const float*)d_in[13];
  const float* ob    = (const float*)d_in[14];
  const float* l1w   = (const float*)d_in[15];
  const float* l1b   = (const float*)d_in[16];
  const float* l2w   = (const float*)d_in[17];
  const float* l2b   = (const float*)d_in[18];
  const float* ln1s  = (const float*)d_in[19];
  const float* ln1bb = (const float*)d_in[20];
  const float* ln2s  = (const float*)d_in[21];
  const float* ln2bb = (const float*)d_in[22];
  const float* m1w   = (const float*)d_in[23];
  const float* m1b   = (const float*)d_in[24];
  const float* m2w   = (const float*)d_in[25];
  const float* m2b   = (const float*)d_in[26];
  float* out = (float*)d_out;

  // ---- workspace layout (bytes) ----
  char* p = (char*)d_ws;
  float*  x      = (float*)p;   p += 17612800;  // 27520 x 160 fp32
  ushort* x16    = (ushort*)p;  p += 8806400;   // 27520 x 160 bf16
  float*  v2acc  = (float*)p;   p += 442368;    // 128 x 864 fp32
  ushort* s1b    = (ushort*)p;  p += 221184;    // 128 x 864 bf16
  ushort* obuf16 = (ushort*)p;  p += 8806400;   // 27520 x 160 bf16
  ushort* wv1b   = (ushort*)p;  p += 1492992;   // 864 x 864 bf16
  ushort* wv2b   = (ushort*)p;  p += 1492992;
  ushort* ipwb   = (ushort*)p;  p += 307200;    // 2 x 480 x 160
  ushort* owb    = (ushort*)p;  p += 102400;    // 2 x 160 x 160
  ushort* l1wb   = (ushort*)p;  p += 81920;     // 2 x 128 x 160
  ushort* l2wb   = (ushort*)p;  p += 81920;     // 2 x 160 x 128
  float*  m1wT   = (float*)p;   p += 153664;    // 196 x 196 fp32 transposed
  char*   R2     = p;                           // shared big region
  ushort* xb16   = (ushort*)R2;                 // phase A: 4608 x 864 bf16
  float*  V1     = (float*)(R2 + 7962624);      // phase A: 4608 x 860 fp32
  ushort* qkv16  = (ushort*)R2;                 // phase B: 27520 x 480 bf16 (26.4 MB)
  float*  t1     = (float*)R2;                  // post-attn: 27520 x 160 fp32
  ushort* ffb16  = (ushort*)(R2 + 17612800);    // 27520 x 128 bf16

  k_prep<<<7103, 256, 0, stream>>>(Wv1, Wv2, ipw, ow, l1w, l2w, m1w,
                                   wv1b, wv2b, ipwb, owb, l1wb, l2wb, m1wT);
  k_xb16<<<3870, 256, 0, stream>>>(src, R_u, xb16);

  // V1 = relu(xb @ Wv1^T + bv1)
  gemm_bf16<1, 0, 0><<<dim3(27, 36, 1), 256, 0, stream>>>(xb16, wv1b, bv1, V1, KPG, 860, 860, 27);
  k_red_s1<<<432, 256, 0, stream>>>(V1, s1b);
  k_zero<<<432, 256, 0, stream>>>(v2acc, 110592);
  gemm_bf16<0, 1, 0><<<dim3(27, 1, 3), 256, 0, stream>>>(s1b, wv2b, nullptr, v2acc, KPG, KPG, KPG, 9);
  k_buildx<<<4300, 256, 0, stream>>>(v2acc, bv2, times, x, x16);

  for (int l = 0; l < 2; l++) {
    gemm_bf16<0, 0, 1><<<dim3(15, 215, 1), 256, 0, stream>>>(
        x16, ipwb + (size_t)l * 76800, ipb + l * 480, qkv16, 160, 480, 480, 5);
    k_attn2<<<dim3(512, 2), 512, 0, stream>>>(qkv16, lens, obuf16);
    gemm_bf16<0, 0, 0><<<dim3(5, 215, 1), 256, 0, stream>>>(
        obuf16, owb + (size_t)l * 25600, ob + l * 160, t1, 160, 160, 160, 5);
    k_lnres<<<6880, 256, 0, stream>>>(x, t1, ln1s + l * 160, ln1bb + l * 160, x16);
    gemm_bf16<1, 0, 1><<<dim3(4, 215, 1), 256, 0, stream>>>(
        x16, l1wb + (size_t)l * 20480, l1b + l * 128, ffb16, 160, 128, 128, 5);
    gemm_bf16<0, 0, 0><<<dim3(5, 215, 1), 256, 0, stream>>>(
        ffb16, l2wb + (size_t)l * 20480, l2b + l * 160, t1, 128, 160, 160, 4);
    k_lnres<<<6880, 256, 0, stream>>>(x, t1, ln2s + l * 160, ln2bb + l * 160, x16);
  }

  k_head<<<128, 256, 0, stream>>>(x, lens, stat, emb_w, emb_b, m1wT, m1b, m2w, m2b, out);
}

// Round 5
// 331.964 us; speedup vs baseline: 5.3249x; 1.1785x over previous
//
#include <hip/hip_runtime.h>
#include <math.h>

#define T_LEN 215
#define B_N   128
#define DINP  36
#define D_TR  160
#define HD    40
#define D_FIN 196
#define KPG   864   // 860 padded to mult of 32
#define ALD   232   // S/P and Vt row stride in elems (bf16); 464 B

typedef __attribute__((ext_vector_type(8))) short short8v;
typedef __attribute__((ext_vector_type(4))) float f32x4;

__device__ __forceinline__ ushort f2bf(float x) {
  union { float f; unsigned u; } c; c.f = x;
  unsigned r = c.u + 0x7fffu + ((c.u >> 16) & 1u);
  return (ushort)(r >> 16);
}
__device__ __forceinline__ float bf2f(ushort h) {
  union { unsigned u; float f; } c; c.u = ((unsigned)h) << 16;
  return c.f;
}

// ---------------- fused weight prep: bf16 conversions + pads + m1w transpose + zeros ----------------
__global__ __launch_bounds__(256) void k_prep(const float* __restrict__ Wv1,
    const float* __restrict__ Wv2, const float* __restrict__ ipw, const float* __restrict__ ow,
    const float* __restrict__ l1w, const float* __restrict__ l2w,
    ushort* __restrict__ wv1b, ushort* __restrict__ wv2b, ushort* __restrict__ ipwb,
    ushort* __restrict__ owb, ushort* __restrict__ l1wb, ushort* __restrict__ l2wb,
    float* __restrict__ v2acc, float* __restrict__ featacc) {
  int i = blockIdx.x * 256 + threadIdx.x;
  if (i < 746496) { int n = i / KPG, k = i % KPG;
    wv1b[i] = (n < 860 && k < 860) ? f2bf(Wv1[n * 860 + k]) : (ushort)0; return; }
  i -= 746496;
  if (i < 746496) { int n = i / KPG, k = i % KPG;
    wv2b[i] = (n < 860 && k < 860) ? f2bf(Wv2[n * 860 + k]) : (ushort)0; return; }
  i -= 746496;
  if (i < 153600) { ipwb[i] = f2bf(ipw[i]); return; }
  i -= 153600;
  if (i < 51200)  { owb[i] = f2bf(ow[i]); return; }
  i -= 51200;
  if (i < 40960)  { l1wb[i] = f2bf(l1w[i]); return; }
  i -= 40960;
  if (i < 40960)  { l2wb[i] = f2bf(l2w[i]); return; }
  i -= 40960;
  if (i < 110592) { v2acc[i] = 0.f; return; }
  i -= 110592;
  if (i < 25088)  { featacc[i] = 0.f; return; }
}

// xb16[b,i, 4t+j] = bf16(relu(src[t,b,i]*R_u[4i+j])), stride KPG, zero-pad cols 860..863
__global__ __launch_bounds__(256) void k_xb16(const float* __restrict__ src,
    const float* __restrict__ R_u, ushort* __restrict__ xb16) {
  int idx = blockIdx.x * 256 + threadIdx.x;
  if (idx >= B_N * DINP * T_LEN) return;
  int t = idx % T_LEN;
  int i = (idx / T_LEN) % DINP;
  int b = idx / (T_LEN * DINP);
  float v = src[((size_t)t * B_N + b) * 72 + i];
  float4 r = ((const float4*)R_u)[i];
  ushort4 o;
  o.x = f2bf(fmaxf(v * r.x, 0.f)); o.y = f2bf(fmaxf(v * r.y, 0.f));
  o.z = f2bf(fmaxf(v * r.z, 0.f)); o.w = f2bf(fmaxf(v * r.w, 0.f));
  ushort* row = xb16 + (size_t)(b * DINP + i) * KPG;
  *(ushort4*)(row + 4 * t) = o;
  if (t == 0) { ushort4 z = {0, 0, 0, 0}; *(ushort4*)(row + 860) = z; }
}

// s1_16[b,n] = bf16( (1/36) sum_i V1[b*36+i, n] ), stride KPG, zero-pad
__global__ __launch_bounds__(256) void k_red_s1(const float* __restrict__ V1, ushort* __restrict__ s1) {
  int idx = blockIdx.x * 256 + threadIdx.x;
  if (idx >= B_N * KPG) return;
  int b = idx / KPG, n = idx % KPG;
  float s = 0.f;
  if (n < 860) {
    #pragma unroll 4
    for (int i = 0; i < DINP; i++) s += V1[((size_t)b * DINP + i) * 860 + n];
    s *= (1.0f / 36.0f);
  }
  s1[idx] = (n < 860) ? f2bf(s) : (ushort)0;
}

// x[t,b,*] (fp32 + bf16) from relu(v2acc + bv2) and inline positional encoding
__global__ __launch_bounds__(256) void k_buildx(const float* __restrict__ v2acc,
    const float* __restrict__ bv2, const float* __restrict__ times,
    float* __restrict__ x, ushort* __restrict__ x16) {
  int idx = blockIdx.x * 256 + threadIdx.x;
  if (idx >= T_LEN * B_N * 40) return;
  int c = idx % 40;
  int r = idx / 40;            // r = t*B + b
  int t = r / B_N, b = r % B_N;
  float4 f;
  if (c < 36) {
    float4 a = *(const float4*)&v2acc[(size_t)b * KPG + 4 * t];
    float4 bb = *(const float4*)&bv2[4 * t];
    f.x = fmaxf(a.x + bb.x, 0.f); f.y = fmaxf(a.y + bb.y, 0.f);
    f.z = fmaxf(a.z + bb.z, 0.f); f.w = fmaxf(a.w + bb.w, 0.f);
  } else {
    float tm = times[r];
    int j0 = (c - 36) * 4;         // 0,4,8,12
    bool is_sin = j0 < 8;
    int kb = j0 & 7;               // 0 or 4
    float o[4];
    #pragma unroll
    for (int qq = 0; qq < 4; qq++) {
      float ts = expf((float)(kb + qq) * 0.76723400f);  // 215^(k/7)
      float sc = tm / ts;
      o[qq] = is_sin ? sinf(sc) : cosf(sc);
    }
    f.x = o[0]; f.y = o[1]; f.z = o[2]; f.w = o[3];
  }
  ((float4*)(x + (size_t)r * D_TR))[c] = f;
  ushort4 h = {f2bf(f.x), f2bf(f.y), f2bf(f.z), f2bf(f.w)};
  *(ushort4*)(x16 + (size_t)r * D_TR + 4 * c) = h;
}

// ---------------- bf16 MFMA GEMM: C = act(A[M,KP] @ W[N,KP]^T + bias) ----------------
// BM=128, BN=64, BK=32, 256 threads (4 waves). M%128==0; store guard via ncols.
template <int RELU, int SPLIT, int WMODE>
__global__ __launch_bounds__(256) void gemm_bf16(const ushort* __restrict__ A,
    const ushort* __restrict__ W, const float* __restrict__ bias, void* __restrict__ Cv,
    int KP, int ldc, int ncols, int kts) {
  __shared__ ushort As[128 * 32];
  __shared__ ushort Ws[64 * 32];
  const int tid = threadIdx.x;
  const int wave = tid >> 6, lane = tid & 63;
  const int lr = lane & 15, hi = lane >> 4;
  const int m0 = blockIdx.y * 128, n0 = blockIdx.x * 64;
  const int kt0 = blockIdx.z * kts;

  f32x4 acc[2][4];
  #pragma unroll
  for (int i = 0; i < 2; i++)
    #pragma unroll
    for (int j = 0; j < 4; j++) acc[i][j] = (f32x4){0.f, 0.f, 0.f, 0.f};

  // staging: A = 512 granules of 16B (2/thread), W = 256 granules (1/thread)
  const int ar = tid >> 2, g = tid & 3;
  const size_t abase0 = (size_t)(m0 + ar) * KP;
  const size_t abase1 = (size_t)(m0 + ar + 64) * KP;
  const size_t bbase  = (size_t)(n0 + ar) * KP;
  const int awb0 = ar * 64 + ((g * 16) ^ ((ar & 3) << 4));
  const int awb1 = awb0 + 64 * 64;
  const int bwb  = ar * 64 + ((g * 16) ^ ((ar & 3) << 4));

  // fragment read offsets (bytes)
  const int arow0 = wave * 32 + lr;
  const int arb0 = arow0 * 64 + ((hi * 16) ^ ((arow0 & 3) << 4));
  const int arb1 = (arow0 + 16) * 64 + ((hi * 16) ^ (((arow0 + 16) & 3) << 4));
  int brb[4];
  #pragma unroll
  for (int j = 0; j < 4; j++)
    brb[j] = (j * 16 + lr) * 64 + ((hi * 16) ^ ((lr & 3) << 4));

  for (int kt = 0; kt < kts; ++kt) {
    const int k0 = (kt0 + kt) * 32;
    uint4 va0 = *(const uint4*)(A + abase0 + k0 + g * 8);
    uint4 va1 = *(const uint4*)(A + abase1 + k0 + g * 8);
    uint4 vb  = *(const uint4*)(W + bbase  + k0 + g * 8);
    if (kt) __syncthreads();
    *(uint4*)((char*)As + awb0) = va0;
    *(uint4*)((char*)As + awb1) = va1;
    *(uint4*)((char*)Ws + bwb)  = vb;
    __syncthreads();
    short8v a0 = *(const short8v*)((const char*)As + arb0);
    short8v a1 = *(const short8v*)((const char*)As + arb1);
    short8v bfr[4];
    #pragma unroll
    for (int j = 0; j < 4; j++) bfr[j] = *(const short8v*)((const char*)Ws + brb[j]);
    #pragma unroll
    for (int j = 0; j < 4; j++) {
      acc[0][j] = __builtin_amdgcn_mfma_f32_16x16x32_bf16(a0, bfr[j], acc[0][j], 0, 0, 0);
      acc[1][j] = __builtin_amdgcn_mfma_f32_16x16x32_bf16(a1, bfr[j], acc[1][j], 0, 0, 0);
    }
  }

  #pragma unroll
  for (int i = 0; i < 2; i++) {
    #pragma unroll
    for (int j = 0; j < 4; j++) {
      int col = n0 + j * 16 + lr;
      int row = m0 + wave * 32 + i * 16 + hi * 4;
      if (col < ncols) {
        if (SPLIT) {
          #pragma unroll
          for (int r = 0; r < 4; r++)
            atomicAdd((float*)Cv + (size_t)(row + r) * ldc + col, acc[i][j][r]);
        } else {
          float bb = bias ? bias[col] : 0.f;
          #pragma unroll
          for (int r = 0; r < 4; r++) {
            float xv = acc[i][j][r] + bb;
            if (RELU) xv = fmaxf(xv, 0.f);
            if (WMODE == 0) ((float*)Cv)[(size_t)(row + r) * ldc + col] = xv;
            else            ((ushort*)Cv)[(size_t)(row + r) * ldc + col] = f2bf(xv);
          }
        }
      }
    }
  }
}

// ---------------- MFMA flash attention: block = (b*4+h, qtile of 128), 8 waves ----------------
__global__ __launch_bounds__(512) void k_attn2(const ushort* __restrict__ qkv,
    const int* __restrict__ lengths, ushort* __restrict__ o16) {
  __shared__ ushort Qs[128 * 64];
  __shared__ ushort Ks[224 * 64];
  __shared__ ushort Vt[48 * ALD];
  __shared__ ushort SP[128 * ALD];
  __shared__ float lsum[128];
  const int bh = blockIdx.x;
  const int b = bh >> 2, h = bh & 3;
  const int q0 = blockIdx.y * 128;
  int L = lengths[b]; if (L > T_LEN) L = T_LEN;
  const int nkt = (L + 31) >> 5;
  const int tid = threadIdx.x;
  const int wv = tid >> 6, lane = tid & 63, lr = lane & 15, hi = lane >> 4;
  const float SC = 0.15811388300841898f;  // 1/sqrt(40)

  for (int i = tid; i < 48 * ALD / 8; i += 512) ((uint4*)Vt)[i] = (uint4){0, 0, 0, 0};
  __syncthreads();

  for (int i = tid; i < nkt * 256; i += 512) {
    int row = i >> 3, g = i & 7;
    uint4 v = {0, 0, 0, 0};
    if (g < 5 && row < T_LEN)
      v = *(const uint4*)(qkv + ((size_t)row * B_N + b) * 480 + 160 + h * 40 + g * 8);
    *(uint4*)((char*)Ks + row * 128 + ((g * 16) ^ ((row & 7) << 4))) = v;
  }
  for (int i = tid; i < 128 * 8; i += 512) {
    int row = i >> 3, g = i & 7;
    int t = q0 + row;
    uint4 v = {0, 0, 0, 0};
    if (g < 5 && t < T_LEN)
      v = *(const uint4*)(qkv + ((size_t)t * B_N + b) * 480 + h * 40 + g * 8);
    *(uint4*)((char*)Qs + row * 128 + ((g * 16) ^ ((row & 7) << 4))) = v;
  }
  for (int i = tid; i < L * 40; i += 512) {
    int key = i / 40, d = i - key * 40;
    Vt[d * ALD + key] = qkv[((size_t)key * B_N + b) * 480 + 320 + h * 40 + d];
  }
  __syncthreads();

  {
    const int qrow = wv * 16 + lr;
    short8v qa0 = *(const short8v*)((char*)Qs + qrow * 128 + ((hi * 16) ^ ((qrow & 7) << 4)));
    short8v qa1 = *(const short8v*)((char*)Qs + qrow * 128 + (((64 + hi * 16)) ^ ((qrow & 7) << 4)));
    const int nk16 = nkt * 2;
    for (int kt = 0; kt < nk16; ++kt) {
      int krow = kt * 16 + lr;
      short8v kb0 = *(const short8v*)((char*)Ks + krow * 128 + ((hi * 16) ^ ((krow & 7) << 4)));
      short8v kb1 = *(const short8v*)((char*)Ks + krow * 128 + (((64 + hi * 16)) ^ ((krow & 7) << 4)));
      f32x4 c = {0.f, 0.f, 0.f, 0.f};
      c = __builtin_amdgcn_mfma_f32_16x16x32_bf16(qa0, kb0, c, 0, 0, 0);
      c = __builtin_amdgcn_mfma_f32_16x16x32_bf16(qa1, kb1, c, 0, 0, 0);
      #pragma unroll
      for (int r = 0; r < 4; r++)
        SP[(wv * 16 + hi * 4 + r) * ALD + kt * 16 + lr] = f2bf(c[r]);
    }
  }
  __syncthreads();

  {
    const int row = tid >> 2, c4 = tid & 3;
    const int ncol4 = nkt * 8;
    ushort* sr = SP + row * ALD;
    float m = -1e30f;
    for (int j = c4; j < ncol4; j += 4) {
      ushort4 sv = *(const ushort4*)(sr + j * 4);
      int col = j * 4;
      float s0 = (col < L)     ? bf2f(sv.x) : -1e30f;
      float s1 = (col + 1 < L) ? bf2f(sv.y) : -1e30f;
      float s2 = (col + 2 < L) ? bf2f(sv.z) : -1e30f;
      float s3 = (col + 3 < L) ? bf2f(sv.w) : -1e30f;
      m = fmaxf(m, fmaxf(fmaxf(s0, s1), fmaxf(s2, s3)));
    }
    m = fmaxf(m, __shfl_xor(m, 1, 64));
    m = fmaxf(m, __shfl_xor(m, 2, 64));
    float sum = 0.f;
    for (int j = c4; j < ncol4; j += 4) {
      ushort4 sv = *(const ushort4*)(sr + j * 4);
      int col = j * 4;
      float p0 = (col < L)     ? __expf(SC * (bf2f(sv.x) - m)) : 0.f;
      float p1 = (col + 1 < L) ? __expf(SC * (bf2f(sv.y) - m)) : 0.f;
      float p2 = (col + 2 < L) ? __expf(SC * (bf2f(sv.z) - m)) : 0.f;
      float p3 = (col + 3 < L) ? __expf(SC * (bf2f(sv.w) - m)) : 0.f;
      sum += (p0 + p1) + (p2 + p3);
      ushort4 pv = {f2bf(p0), f2bf(p1), f2bf(p2), f2bf(p3)};
      *(ushort4*)(sr + j * 4) = pv;
    }
    sum += __shfl_xor(sum, 1, 64);
    sum += __shfl_xor(sum, 2, 64);
    if (c4 == 0) lsum[row] = sum;
  }
  __syncthreads();

  {
    f32x4 o0 = {0.f, 0.f, 0.f, 0.f}, o1 = o0, o2 = o0;
    for (int kt = 0; kt < nkt; ++kt) {
      short8v pa = *(const short8v*)((char*)SP + (wv * 16 + lr) * 464 + kt * 64 + hi * 16);
      short8v v0 = *(const short8v*)((char*)Vt + lr * 464 + kt * 64 + hi * 16);
      short8v v1 = *(const short8v*)((char*)Vt + (16 + lr) * 464 + kt * 64 + hi * 16);
      short8v v2 = *(const short8v*)((char*)Vt + (32 + lr) * 464 + kt * 64 + hi * 16);
      o0 = __builtin_amdgcn_mfma_f32_16x16x32_bf16(pa, v0, o0, 0, 0, 0);
      o1 = __builtin_amdgcn_mfma_f32_16x16x32_bf16(pa, v1, o1, 0, 0, 0);
      o2 = __builtin_amdgcn_mfma_f32_16x16x32_bf16(pa, v2, o2, 0, 0, 0);
    }
    #pragma unroll
    for (int r = 0; r < 4; r++) {
      int qr = wv * 16 + hi * 4 + r;
      int t = q0 + qr;
      if (t < T_LEN) {
        float inv = 1.0f / lsum[qr];
        ushort* op = o16 + ((size_t)t * B_N + b) * D_TR + h * 40;
        op[lr] = f2bf(o0[r] * inv);
        op[16 + lr] = f2bf(o1[r] * inv);
        if (lr < 8) op[32 + lr] = f2bf(o2[r] * inv);
      }
    }
  }
}

// ---------------- fused residual + LayerNorm (writes fp32 x and bf16 x16) ----------------
__global__ __launch_bounds__(256) void k_lnres(float* __restrict__ x,
    const float* __restrict__ delta, const float* __restrict__ gam,
    const float* __restrict__ bet, ushort* __restrict__ x16) {
  int wid = (blockIdx.x * 256 + threadIdx.x) >> 6;
  int lane = threadIdx.x & 63;
  if (wid >= T_LEN * B_N) return;
  float* xr = x + (size_t)wid * D_TR;
  ushort* hr = x16 + (size_t)wid * D_TR;
  const float* dr = delta + (size_t)wid * D_TR;
  float a0 = xr[lane] + dr[lane];
  float a1 = xr[lane + 64] + dr[lane + 64];
  float a2 = (lane < 32) ? (xr[lane + 128] + dr[lane + 128]) : 0.f;
  float s = a0 + a1 + a2;
  #pragma unroll
  for (int off = 32; off; off >>= 1) s += __shfl_xor(s, off, 64);
  float mu = s * (1.0f / 160.0f);
  float d0 = a0 - mu, d1 = a1 - mu, d2 = (lane < 32) ? (a2 - mu) : 0.f;
  float sq = d0 * d0 + d1 * d1 + d2 * d2;
  #pragma unroll
  for (int off = 32; off; off >>= 1) sq += __shfl_xor(sq, off, 64);
  float rstd = rsqrtf(sq * (1.0f / 160.0f) + 1e-5f);
  float o0 = d0 * rstd * gam[lane] + bet[lane];
  float o1 = d1 * rstd * gam[lane + 64] + bet[lane + 64];
  xr[lane] = o0;      hr[lane] = f2bf(o0);
  xr[lane + 64] = o1; hr[lane + 64] = f2bf(o1);
  if (lane < 32) {
    float o2 = d2 * rstd * gam[lane + 128] + bet[lane + 128];
    xr[lane + 128] = o2; hr[lane + 128] = f2bf(o2);
  }
}

// ---------------- head part 1: parallel masked sum over t (+ emb), atomics into featacc ----------------
__global__ __launch_bounds__(256) void k_agg(const float* __restrict__ x,
    const int* __restrict__ lengths, const float* __restrict__ stat,
    const float* __restrict__ emb_w, const float* __restrict__ emb_b,
    float* __restrict__ featacc) {
  const int cx = blockIdx.x, b = blockIdx.y;
  const int tid = threadIdx.x;
  int L = lengths[b]; if (L > T_LEN) L = T_LEN;
  const int c0 = cx * 27;
  if (tid < D_TR) {
    float s = 0.f;
    #pragma unroll
    for (int tl = 0; tl < 27; ++tl) {
      int t = c0 + tl;
      if (t < L) s += x[((size_t)t * B_N + b) * D_TR + tid];
    }
    atomicAdd(&featacc[b * D_FIN + tid], s);
  } else if (cx == 0 && tid < D_FIN) {
    int i = tid - D_TR;
    float s = emb_b[i];
    #pragma unroll
    for (int k = 0; k < 9; k++) s = fmaf(stat[b * 9 + k], emb_w[i * 9 + k], s);
    featacc[b * D_FIN + tid] = s;
  }
}

// ---------------- head part 2: m1o = relu(feat @ m1w^T + m1b), one wave per output ----------------
__global__ __launch_bounds__(256) void k_mlp1(const float* __restrict__ featacc,
    const int* __restrict__ lengths, const float* __restrict__ m1w,
    const float* __restrict__ m1b, float* __restrict__ m1o) {
  const int b = blockIdx.y;
  const int wv = threadIdx.x >> 6, lane = threadIdx.x & 63;
  const int n = blockIdx.x * 4 + wv;           // 49*4 = 196
  int L = lengths[b]; if (L > T_LEN) L = T_LEN;
  const float inv = 1.0f / (float)(L + 1);
  const float* wr = m1w + (size_t)n * D_FIN;
  const float* fr = featacc + (size_t)b * D_FIN;
  float s = 0.f;
  for (int k = lane; k < D_FIN; k += 64) {
    float f = fr[k] * (k < D_TR ? inv : 1.f);
    s = fmaf(f, wr[k], s);
  }
  #pragma unroll
  for (int off = 32; off; off >>= 1) s += __shfl_xor(s, off, 64);
  if (lane == 0) m1o[(size_t)b * D_FIN + n] = fmaxf(s + m1b[n], 0.f);
}

// ---------------- head part 3: logits + distance ----------------
__global__ __launch_bounds__(128) void k_logits(const float* __restrict__ m1o,
    const float* __restrict__ m2w, const float* __restrict__ m2b, float* __restrict__ out) {
  const int b = blockIdx.x;
  const int c = threadIdx.x >> 6, lane = threadIdx.x & 63;
  const float* mr = m1o + (size_t)b * D_FIN;
  const float* wr = m2w + c * D_FIN;
  float s = 0.f;
  for (int k = lane; k < D_FIN; k += 64) s = fmaf(mr[k], wr[k], s);
  #pragma unroll
  for (int off = 32; off; off >>= 1) s += __shfl_xor(s, off, 64);
  if (lane == 0) out[2 * b + c] = s + m2b[c];
  if (b == 0 && threadIdx.x == 127) out[256] = 0.f;  // distance == 0 exactly
}

// ---------------- launch ----------------
extern "C" void kernel_launch(void* const* d_in, const int* in_sizes, int n_in,
                              void* d_out, int out_size, void* d_ws, size_t ws_size,
                              hipStream_t stream) {
  const float* src   = (const float*)d_in[0];
  const float* stat  = (const float*)d_in[1];
  const float* times = (const float*)d_in[2];
  const int*   lens  = (const int*)d_in[3];
  const float* R_u   = (const float*)d_in[4];
  const float* emb_w = (const float*)d_in[5];
  const float* emb_b = (const float*)d_in[6];
  const float* Wv1   = (const float*)d_in[7];
  const float* bv1   = (const float*)d_in[8];
  const float* Wv2   = (const float*)d_in[9];
  const float* bv2   = (const float*)d_in[10];
  const float* ipw   = (const float*)d_in[11];
  const float* ipb   = (const float*)d_in[12];
  const float* ow    = (const float*)d_in[13];
  const float* ob    = (const float*)d_in[14];
  const float* l1w   = (const float*)d_in[15];
  const float* l1b   = (const float*)d_in[16];
  const float* l2w   = (const float*)d_in[17];
  const float* l2b   = (const float*)d_in[18];
  const float* ln1s  = (const float*)d_in[19];
  const float* ln1bb = (const float*)d_in[20];
  const float* ln2s  = (const float*)d_in[21];
  const float* ln2bb = (const float*)d_in[22];
  const float* m1w   = (const float*)d_in[23];
  const float* m1b   = (const float*)d_in[24];
  const float* m2w   = (const float*)d_in[25];
  const float* m2b   = (const float*)d_in[26];
  float* out = (float*)d_out;

  // ---- workspace layout (bytes) ----
  char* p = (char*)d_ws;
  float*  x      = (float*)p;   p += 17612800;  // 27520 x 160 fp32
  ushort* x16    = (ushort*)p;  p += 8806400;   // 27520 x 160 bf16
  float*  v2acc  = (float*)p;   p += 442368;    // 128 x 864 fp32
  ushort* s1b    = (ushort*)p;  p += 221184;    // 128 x 864 bf16
  ushort* obuf16 = (ushort*)p;  p += 8806400;   // 27520 x 160 bf16
  ushort* wv1b   = (ushort*)p;  p += 1492992;   // 864 x 864 bf16
  ushort* wv2b   = (ushort*)p;  p += 1492992;
  ushort* ipwb   = (ushort*)p;  p += 307200;    // 2 x 480 x 160
  ushort* owb    = (ushort*)p;  p += 102400;    // 2 x 160 x 160
  ushort* l1wb   = (ushort*)p;  p += 81920;     // 2 x 128 x 160
  ushort* l2wb   = (ushort*)p;  p += 81920;     // 2 x 160 x 128
  float*  featacc= (float*)p;   p += 100352;    // 128 x 196 fp32
  float*  m1o    = (float*)p;   p += 100352;    // 128 x 196 fp32
  char*   R2     = p;                           // shared big region
  ushort* xb16   = (ushort*)R2;                 // phase A: 4608 x 864 bf16
  float*  V1     = (float*)(R2 + 7962624);      // phase A: 4608 x 860 fp32
  ushort* qkv16  = (ushort*)R2;                 // phase B: 27520 x 480 bf16
  float*  t1     = (float*)R2;                  // post-attn: 27520 x 160 fp32
  ushort* ffb16  = (ushort*)(R2 + 17612800);    // 27520 x 128 bf16

  k_prep<<<7633, 256, 0, stream>>>(Wv1, Wv2, ipw, ow, l1w, l2w,
                                   wv1b, wv2b, ipwb, owb, l1wb, l2wb, v2acc, featacc);
  k_xb16<<<3870, 256, 0, stream>>>(src, R_u, xb16);

  // V1 = relu(xb @ Wv1^T + bv1)
  gemm_bf16<1, 0, 0><<<dim3(14, 36, 1), 256, 0, stream>>>(xb16, wv1b, bv1, V1, KPG, 860, 860, 27);
  k_red_s1<<<432, 256, 0, stream>>>(V1, s1b);
  gemm_bf16<0, 1, 0><<<dim3(14, 1, 3), 256, 0, stream>>>(s1b, wv2b, nullptr, v2acc, KPG, KPG, KPG, 9);
  k_buildx<<<4300, 256, 0, stream>>>(v2acc, bv2, times, x, x16);

  for (int l = 0; l < 2; l++) {
    gemm_bf16<0, 0, 1><<<dim3(8, 215, 1), 256, 0, stream>>>(
        x16, ipwb + (size_t)l * 76800, ipb + l * 480, qkv16, 160, 480, 480, 5);
    k_attn2<<<dim3(512, 2), 512, 0, stream>>>(qkv16, lens, obuf16);
    gemm_bf16<0, 0, 0><<<dim3(3, 215, 1), 256, 0, stream>>>(
        obuf16, owb + (size_t)l * 25600, ob + l * 160, t1, 160, 160, 160, 5);
    k_lnres<<<6880, 256, 0, stream>>>(x, t1, ln1s + l * 160, ln1bb + l * 160, x16);
    gemm_bf16<1, 0, 1><<<dim3(2, 215, 1), 256, 0, stream>>>(
        x16, l1wb + (size_t)l * 20480, l1b + l * 128, ffb16, 160, 128, 128, 5);
    gemm_bf16<0, 0, 0><<<dim3(3, 215, 1), 256, 0, stream>>>(
        ffb16, l2wb + (size_t)l * 20480, l2b + l * 160, t1, 128, 160, 160, 4);
    k_lnres<<<6880, 256, 0, stream>>>(x, t1, ln2s + l * 160, ln2bb + l * 160, x16);
  }

  k_agg<<<dim3(8, 128), 256, 0, stream>>>(x, lens, stat, emb_w, emb_b, featacc);
  k_mlp1<<<dim3(49, 128), 256, 0, stream>>>(featacc, lens, m1w, m1b, m1o);
  k_logits<<<128, 128, 0, stream>>>(m1o, m2w, m2b, out);
}

// Round 6
// 298.102 us; speedup vs baseline: 5.9297x; 1.1136x over previous
//
#include <hip/hip_runtime.h>
#include <math.h>

#define T_LEN 215
#define B_N   128
#define DINP  36
#define D_TR  160
#define HD    40
#define D_FIN 196
#define KPG   864   // 860 padded to mult of 32
#define VLD   224   // Vt col count (>= 7*32)

typedef __attribute__((ext_vector_type(8))) short short8v;
typedef __attribute__((ext_vector_type(4))) float f32x4;

__device__ __forceinline__ ushort f2bf(float x) {
  union { float f; unsigned u; } c; c.f = x;
  unsigned r = c.u + 0x7fffu + ((c.u >> 16) & 1u);
  return (ushort)(r >> 16);
}
__device__ __forceinline__ float bf2f(ushort h) {
  union { unsigned u; float f; } c; c.u = ((unsigned)h) << 16;
  return c.f;
}

// ---------------- fused weight prep: bf16 conversions + pads + zeros ----------------
__global__ __launch_bounds__(256) void k_prep(const float* __restrict__ Wv1,
    const float* __restrict__ Wv2, const float* __restrict__ ipw, const float* __restrict__ ow,
    const float* __restrict__ l1w, const float* __restrict__ l2w,
    ushort* __restrict__ wv1b, ushort* __restrict__ wv2b, ushort* __restrict__ ipwb,
    ushort* __restrict__ owb, ushort* __restrict__ l1wb, ushort* __restrict__ l2wb,
    float* __restrict__ v2acc, float* __restrict__ featacc) {
  int i = blockIdx.x * 256 + threadIdx.x;
  if (i < 746496) { int n = i / KPG, k = i % KPG;
    wv1b[i] = (n < 860 && k < 860) ? f2bf(Wv1[n * 860 + k]) : (ushort)0; return; }
  i -= 746496;
  if (i < 746496) { int n = i / KPG, k = i % KPG;
    wv2b[i] = (n < 860 && k < 860) ? f2bf(Wv2[n * 860 + k]) : (ushort)0; return; }
  i -= 746496;
  if (i < 153600) { ipwb[i] = f2bf(ipw[i]); return; }
  i -= 153600;
  if (i < 51200)  { owb[i] = f2bf(ow[i]); return; }
  i -= 51200;
  if (i < 40960)  { l1wb[i] = f2bf(l1w[i]); return; }
  i -= 40960;
  if (i < 40960)  { l2wb[i] = f2bf(l2w[i]); return; }
  i -= 40960;
  if (i < 110592) { v2acc[i] = 0.f; return; }
  i -= 110592;
  if (i < 25088)  { featacc[i] = 0.f; return; }
}

// xb16[b,i, 4t+j] = bf16(relu(src[t,b,i]*R_u[4i+j])), stride KPG, zero-pad cols 860..863
__global__ __launch_bounds__(256) void k_xb16(const float* __restrict__ src,
    const float* __restrict__ R_u, ushort* __restrict__ xb16) {
  int idx = blockIdx.x * 256 + threadIdx.x;
  if (idx >= B_N * DINP * T_LEN) return;
  int t = idx % T_LEN;
  int i = (idx / T_LEN) % DINP;
  int b = idx / (T_LEN * DINP);
  float v = src[((size_t)t * B_N + b) * 72 + i];
  float4 r = ((const float4*)R_u)[i];
  ushort4 o;
  o.x = f2bf(fmaxf(v * r.x, 0.f)); o.y = f2bf(fmaxf(v * r.y, 0.f));
  o.z = f2bf(fmaxf(v * r.z, 0.f)); o.w = f2bf(fmaxf(v * r.w, 0.f));
  ushort* row = xb16 + (size_t)(b * DINP + i) * KPG;
  *(ushort4*)(row + 4 * t) = o;
  if (t == 0) { ushort4 z = {0, 0, 0, 0}; *(ushort4*)(row + 860) = z; }
}

// s1_16[b,n] = bf16( (1/36) sum_i V1[b*36+i, n] ), stride KPG, zero-pad
__global__ __launch_bounds__(256) void k_red_s1(const float* __restrict__ V1, ushort* __restrict__ s1) {
  int idx = blockIdx.x * 256 + threadIdx.x;
  if (idx >= B_N * KPG) return;
  int b = idx / KPG, n = idx % KPG;
  float s = 0.f;
  if (n < 860) {
    #pragma unroll 4
    for (int i = 0; i < DINP; i++) s += V1[((size_t)b * DINP + i) * 860 + n];
    s *= (1.0f / 36.0f);
  }
  s1[idx] = (n < 860) ? f2bf(s) : (ushort)0;
}

// x[t,b,*] (fp32 + bf16) from relu(v2acc + bv2) and inline positional encoding
__global__ __launch_bounds__(256) void k_buildx(const float* __restrict__ v2acc,
    const float* __restrict__ bv2, const float* __restrict__ times,
    float* __restrict__ x, ushort* __restrict__ x16) {
  int idx = blockIdx.x * 256 + threadIdx.x;
  if (idx >= T_LEN * B_N * 40) return;
  int c = idx % 40;
  int r = idx / 40;            // r = t*B + b
  int t = r / B_N, b = r % B_N;
  float4 f;
  if (c < 36) {
    float4 a = *(const float4*)&v2acc[(size_t)b * KPG + 4 * t];
    float4 bb = *(const float4*)&bv2[4 * t];
    f.x = fmaxf(a.x + bb.x, 0.f); f.y = fmaxf(a.y + bb.y, 0.f);
    f.z = fmaxf(a.z + bb.z, 0.f); f.w = fmaxf(a.w + bb.w, 0.f);
  } else {
    float tm = times[r];
    int j0 = (c - 36) * 4;         // 0,4,8,12
    bool is_sin = j0 < 8;
    int kb = j0 & 7;               // 0 or 4
    float o[4];
    #pragma unroll
    for (int qq = 0; qq < 4; qq++) {
      float ts = expf((float)(kb + qq) * 0.76723400f);  // 215^(k/7)
      float sc = tm / ts;
      o[qq] = is_sin ? sinf(sc) : cosf(sc);
    }
    f.x = o[0]; f.y = o[1]; f.z = o[2]; f.w = o[3];
  }
  ((float4*)(x + (size_t)r * D_TR))[c] = f;
  ushort4 h = {f2bf(f.x), f2bf(f.y), f2bf(f.z), f2bf(f.w)};
  *(ushort4*)(x16 + (size_t)r * D_TR + 4 * c) = h;
}

// ---------------- bf16 MFMA GEMM: C = act(A[M,KP] @ W[N,KP]^T + bias) ----------------
// BM=128, BN=64, BK=32, 256 threads (4 waves). M%128==0; store guard via ncols.
template <int RELU, int SPLIT, int WMODE>
__global__ __launch_bounds__(256) void gemm_bf16(const ushort* __restrict__ A,
    const ushort* __restrict__ W, const float* __restrict__ bias, void* __restrict__ Cv,
    int KP, int ldc, int ncols, int kts) {
  __shared__ ushort As[128 * 32];
  __shared__ ushort Ws[64 * 32];
  const int tid = threadIdx.x;
  const int wave = tid >> 6, lane = tid & 63;
  const int lr = lane & 15, hi = lane >> 4;
  const int m0 = blockIdx.y * 128, n0 = blockIdx.x * 64;
  const int kt0 = blockIdx.z * kts;

  f32x4 acc[2][4];
  #pragma unroll
  for (int i = 0; i < 2; i++)
    #pragma unroll
    for (int j = 0; j < 4; j++) acc[i][j] = (f32x4){0.f, 0.f, 0.f, 0.f};

  const int ar = tid >> 2, g = tid & 3;
  const size_t abase0 = (size_t)(m0 + ar) * KP;
  const size_t abase1 = (size_t)(m0 + ar + 64) * KP;
  const size_t bbase  = (size_t)(n0 + ar) * KP;
  const int awb0 = ar * 64 + ((g * 16) ^ ((ar & 3) << 4));
  const int awb1 = awb0 + 64 * 64;
  const int bwb  = ar * 64 + ((g * 16) ^ ((ar & 3) << 4));

  const int arow0 = wave * 32 + lr;
  const int arb0 = arow0 * 64 + ((hi * 16) ^ ((arow0 & 3) << 4));
  const int arb1 = (arow0 + 16) * 64 + ((hi * 16) ^ (((arow0 + 16) & 3) << 4));
  int brb[4];
  #pragma unroll
  for (int j = 0; j < 4; j++)
    brb[j] = (j * 16 + lr) * 64 + ((hi * 16) ^ ((lr & 3) << 4));

  for (int kt = 0; kt < kts; ++kt) {
    const int k0 = (kt0 + kt) * 32;
    uint4 va0 = *(const uint4*)(A + abase0 + k0 + g * 8);
    uint4 va1 = *(const uint4*)(A + abase1 + k0 + g * 8);
    uint4 vb  = *(const uint4*)(W + bbase  + k0 + g * 8);
    if (kt) __syncthreads();
    *(uint4*)((char*)As + awb0) = va0;
    *(uint4*)((char*)As + awb1) = va1;
    *(uint4*)((char*)Ws + bwb)  = vb;
    __syncthreads();
    short8v a0 = *(const short8v*)((const char*)As + arb0);
    short8v a1 = *(const short8v*)((const char*)As + arb1);
    short8v bfr[4];
    #pragma unroll
    for (int j = 0; j < 4; j++) bfr[j] = *(const short8v*)((const char*)Ws + brb[j]);
    #pragma unroll
    for (int j = 0; j < 4; j++) {
      acc[0][j] = __builtin_amdgcn_mfma_f32_16x16x32_bf16(a0, bfr[j], acc[0][j], 0, 0, 0);
      acc[1][j] = __builtin_amdgcn_mfma_f32_16x16x32_bf16(a1, bfr[j], acc[1][j], 0, 0, 0);
    }
  }

  #pragma unroll
  for (int i = 0; i < 2; i++) {
    #pragma unroll
    for (int j = 0; j < 4; j++) {
      int col = n0 + j * 16 + lr;
      int row = m0 + wave * 32 + i * 16 + hi * 4;
      if (col < ncols) {
        if (SPLIT) {
          #pragma unroll
          for (int r = 0; r < 4; r++)
            atomicAdd((float*)Cv + (size_t)(row + r) * ldc + col, acc[i][j][r]);
        } else {
          float bb = bias ? bias[col] : 0.f;
          #pragma unroll
          for (int r = 0; r < 4; r++) {
            float xv = acc[i][j][r] + bb;
            if (RELU) xv = fmaxf(xv, 0.f);
            if (WMODE == 0) ((float*)Cv)[(size_t)(row + r) * ldc + col] = xv;
            else            ((ushort*)Cv)[(size_t)(row + r) * ldc + col] = f2bf(xv);
          }
        }
      }
    }
  }
}

// ---------------- Vt precompute: vt[bh][d<48][k<224] = V^T (bf16), zero-padded ----------------
__global__ __launch_bounds__(256) void k_vt(const ushort* __restrict__ qkv,
    ushort* __restrict__ vt) {
  int idx = blockIdx.x * 256 + threadIdx.x;
  if (idx >= 512 * VLD) return;
  int k = idx % VLD, bh = idx / VLD;
  int b = bh >> 2, h = bh & 3;
  ushort* dst = vt + (size_t)bh * 48 * VLD + k;
  if (k < T_LEN) {
    const ushort* sp = qkv + ((size_t)k * B_N + b) * 480 + 320 + h * 40;
    #pragma unroll
    for (int d = 0; d < 40; d++) dst[d * VLD] = sp[d];
  } else {
    #pragma unroll
    for (int d = 0; d < 40; d++) dst[d * VLD] = 0;
  }
  #pragma unroll
  for (int d = 40; d < 48; d++) dst[d * VLD] = 0;
}

// ---------------- barrier-free 1-wave flash attention ----------------
// block = (b*4+h, q-tile of 16). Q/K fragments direct from global, Vt from global,
// S + softmax fully in registers, P through a 7.4KB LDS tile for the C->A transpose.
__global__ __launch_bounds__(64) void k_attn3(const ushort* __restrict__ qkv,
    const ushort* __restrict__ vt, const int* __restrict__ lengths,
    ushort* __restrict__ o16) {
  __shared__ ushort SP[16 * 232];
  const int bh = blockIdx.x;
  const int b = bh >> 2, h = bh & 3;
  int L = lengths[b]; if (L > T_LEN) L = T_LEN;
  const int q0 = blockIdx.y << 4;
  if (q0 >= L) return;                     // rows >= L are never consumed downstream
  const int lane = threadIdx.x;
  const int lr = lane & 15, hi = lane >> 4;
  const int nk16 = (L + 15) >> 4;          // 16-key tiles (<=14)
  const int nkt  = (L + 31) >> 5;          // 32-key tiles (<=7)
  const float SC = 0.15811388300841898f;   // 1/sqrt(40)

  // Q fragments (lane: q-row = lr, k = hi*8..+7 / 32+hi*8)
  uint4 qa0u = {0, 0, 0, 0}, qa1u = {0, 0, 0, 0};
  {
    int q = q0 + lr;
    if (q < T_LEN) {
      const ushort* qp = qkv + ((size_t)q * B_N + b) * 480 + h * 40;
      qa0u = *(const uint4*)(qp + hi * 8);
      if (hi == 0) qa1u = *(const uint4*)(qp + 32);
    }
  }
  short8v qa0 = *(short8v*)&qa0u;
  short8v qa1 = *(short8v*)&qa1u;

  // S = Q@K^T in registers: c[kt] holds rows hi*4+r, key col kt*16+lr
  f32x4 c[14];
  #pragma unroll
  for (int kt = 0; kt < 14; ++kt) {
    c[kt] = (f32x4){0.f, 0.f, 0.f, 0.f};
    if (kt < nk16) {
      int krow = kt * 16 + lr;
      uint4 kb0u = {0, 0, 0, 0}, kb1u = {0, 0, 0, 0};
      if (krow < L) {
        const ushort* kp = qkv + ((size_t)krow * B_N + b) * 480 + 160 + h * 40;
        kb0u = *(const uint4*)(kp + hi * 8);
        if (hi == 0) kb1u = *(const uint4*)(kp + 32);
      }
      c[kt] = __builtin_amdgcn_mfma_f32_16x16x32_bf16(qa0, *(short8v*)&kb0u, c[kt], 0, 0, 0);
      c[kt] = __builtin_amdgcn_mfma_f32_16x16x32_bf16(qa1, *(short8v*)&kb1u, c[kt], 0, 0, 0);
    }
  }

  // in-register masked softmax (reduce over kt regs + 16-lane lr group)
  float mx[4] = {-1e30f, -1e30f, -1e30f, -1e30f};
  #pragma unroll
  for (int kt = 0; kt < 14; ++kt) {
    if (kt < nk16) {
      bool valid = (kt * 16 + lr) < L;
      #pragma unroll
      for (int r = 0; r < 4; r++) {
        float v = valid ? c[kt][r] : -1e30f;
        mx[r] = fmaxf(mx[r], v);
      }
    }
  }
  #pragma unroll
  for (int r = 0; r < 4; r++) {
    mx[r] = fmaxf(mx[r], __shfl_xor(mx[r], 1, 64));
    mx[r] = fmaxf(mx[r], __shfl_xor(mx[r], 2, 64));
    mx[r] = fmaxf(mx[r], __shfl_xor(mx[r], 4, 64));
    mx[r] = fmaxf(mx[r], __shfl_xor(mx[r], 8, 64));
  }
  float sum[4] = {0.f, 0.f, 0.f, 0.f};
  #pragma unroll
  for (int kt = 0; kt < 14; ++kt) {
    if (kt < nk16) {
      bool valid = (kt * 16 + lr) < L;
      #pragma unroll
      for (int r = 0; r < 4; r++) {
        float p = valid ? __expf(SC * (c[kt][r] - mx[r])) : 0.f;
        sum[r] += p;
        c[kt][r] = p;
      }
    }
  }
  #pragma unroll
  for (int r = 0; r < 4; r++) {
    sum[r] += __shfl_xor(sum[r], 1, 64);
    sum[r] += __shfl_xor(sum[r], 2, 64);
    sum[r] += __shfl_xor(sum[r], 4, 64);
    sum[r] += __shfl_xor(sum[r], 8, 64);
  }

  // write P (bf16) to LDS; cols [nk16*16, nkt*32) get zeros (c[kt]=0 there)
  const int nk16w = nkt * 2;
  #pragma unroll
  for (int kt = 0; kt < 14; ++kt) {
    if (kt < nk16w) {
      #pragma unroll
      for (int r = 0; r < 4; r++)
        SP[(hi * 4 + r) * 232 + kt * 16 + lr] = f2bf(c[kt][r]);
    }
  }
  __syncthreads();   // single-wave: compiles to a waitcnt, no real barrier cost

  // O = P @ Vt: A rows = q (lr), B rows = d from global vt
  f32x4 o0 = {0.f, 0.f, 0.f, 0.f}, o1 = o0, o2 = o0;
  const ushort* vbase = vt + (size_t)bh * 48 * VLD;
  #pragma unroll
  for (int kt = 0; kt < 7; ++kt) {
    if (kt < nkt) {
      short8v pa = *(const short8v*)((const char*)SP + lr * 464 + kt * 64 + hi * 16);
      const ushort* vb = vbase + kt * 32 + hi * 8;
      short8v v0 = *(const short8v*)(vb + (size_t)lr * VLD);
      short8v v1 = *(const short8v*)(vb + (size_t)(16 + lr) * VLD);
      short8v v2 = *(const short8v*)(vb + (size_t)(32 + lr) * VLD);
      o0 = __builtin_amdgcn_mfma_f32_16x16x32_bf16(pa, v0, o0, 0, 0, 0);
      o1 = __builtin_amdgcn_mfma_f32_16x16x32_bf16(pa, v1, o1, 0, 0, 0);
      o2 = __builtin_amdgcn_mfma_f32_16x16x32_bf16(pa, v2, o2, 0, 0, 0);
    }
  }

  #pragma unroll
  for (int r = 0; r < 4; r++) {
    int t = q0 + hi * 4 + r;
    if (t < T_LEN) {
      float inv = 1.0f / sum[r];
      ushort* op = o16 + ((size_t)t * B_N + b) * D_TR + h * 40;
      op[lr]      = f2bf(o0[r] * inv);
      op[16 + lr] = f2bf(o1[r] * inv);
      if (lr < 8) op[32 + lr] = f2bf(o2[r] * inv);
    }
  }
}

// ---------------- fused residual + LayerNorm (writes fp32 x and bf16 x16) ----------------
__global__ __launch_bounds__(256) void k_lnres(float* __restrict__ x,
    const float* __restrict__ delta, const float* __restrict__ gam,
    const float* __restrict__ bet, ushort* __restrict__ x16) {
  int wid = (blockIdx.x * 256 + threadIdx.x) >> 6;
  int lane = threadIdx.x & 63;
  if (wid >= T_LEN * B_N) return;
  float* xr = x + (size_t)wid * D_TR;
  ushort* hr = x16 + (size_t)wid * D_TR;
  const float* dr = delta + (size_t)wid * D_TR;
  float a0 = xr[lane] + dr[lane];
  float a1 = xr[lane + 64] + dr[lane + 64];
  float a2 = (lane < 32) ? (xr[lane + 128] + dr[lane + 128]) : 0.f;
  float s = a0 + a1 + a2;
  #pragma unroll
  for (int off = 32; off; off >>= 1) s += __shfl_xor(s, off, 64);
  float mu = s * (1.0f / 160.0f);
  float d0 = a0 - mu, d1 = a1 - mu, d2 = (lane < 32) ? (a2 - mu) : 0.f;
  float sq = d0 * d0 + d1 * d1 + d2 * d2;
  #pragma unroll
  for (int off = 32; off; off >>= 1) sq += __shfl_xor(sq, off, 64);
  float rstd = rsqrtf(sq * (1.0f / 160.0f) + 1e-5f);
  float o0 = d0 * rstd * gam[lane] + bet[lane];
  float o1 = d1 * rstd * gam[lane + 64] + bet[lane + 64];
  xr[lane] = o0;      hr[lane] = f2bf(o0);
  xr[lane + 64] = o1; hr[lane + 64] = f2bf(o1);
  if (lane < 32) {
    float o2 = d2 * rstd * gam[lane + 128] + bet[lane + 128];
    xr[lane + 128] = o2; hr[lane + 128] = f2bf(o2);
  }
}

// ---------------- head: parallel masked sum (+emb) -> mlp1 -> logits ----------------
__global__ __launch_bounds__(256) void k_agg(const float* __restrict__ x,
    const int* __restrict__ lengths, const float* __restrict__ stat,
    const float* __restrict__ emb_w, const float* __restrict__ emb_b,
    float* __restrict__ featacc) {
  const int cx = blockIdx.x, b = blockIdx.y;
  const int tid = threadIdx.x;
  int L = lengths[b]; if (L > T_LEN) L = T_LEN;
  const int c0 = cx * 27;
  if (tid < D_TR) {
    float s = 0.f;
    #pragma unroll
    for (int tl = 0; tl < 27; ++tl) {
      int t = c0 + tl;
      if (t < L) s += x[((size_t)t * B_N + b) * D_TR + tid];
    }
    atomicAdd(&featacc[b * D_FIN + tid], s);
  } else if (cx == 0 && tid < D_FIN) {
    int i = tid - D_TR;
    float s = emb_b[i];
    #pragma unroll
    for (int k = 0; k < 9; k++) s = fmaf(stat[b * 9 + k], emb_w[i * 9 + k], s);
    featacc[b * D_FIN + tid] = s;
  }
}

__global__ __launch_bounds__(256) void k_mlp1(const float* __restrict__ featacc,
    const int* __restrict__ lengths, const float* __restrict__ m1w,
    const float* __restrict__ m1b, float* __restrict__ m1o) {
  const int b = blockIdx.y;
  const int wv = threadIdx.x >> 6, lane = threadIdx.x & 63;
  const int n = blockIdx.x * 4 + wv;
  int L = lengths[b]; if (L > T_LEN) L = T_LEN;
  const float inv = 1.0f / (float)(L + 1);
  const float* wr = m1w + (size_t)n * D_FIN;
  const float* fr = featacc + (size_t)b * D_FIN;
  float s = 0.f;
  for (int k = lane; k < D_FIN; k += 64) {
    float f = fr[k] * (k < D_TR ? inv : 1.f);
    s = fmaf(f, wr[k], s);
  }
  #pragma unroll
  for (int off = 32; off; off >>= 1) s += __shfl_xor(s, off, 64);
  if (lane == 0) m1o[(size_t)b * D_FIN + n] = fmaxf(s + m1b[n], 0.f);
}

__global__ __launch_bounds__(128) void k_logits(const float* __restrict__ m1o,
    const float* __restrict__ m2w, const float* __restrict__ m2b, float* __restrict__ out) {
  const int b = blockIdx.x;
  const int c = threadIdx.x >> 6, lane = threadIdx.x & 63;
  const float* mr = m1o + (size_t)b * D_FIN;
  const float* wr = m2w + c * D_FIN;
  float s = 0.f;
  for (int k = lane; k < D_FIN; k += 64) s = fmaf(mr[k], wr[k], s);
  #pragma unroll
  for (int off = 32; off; off >>= 1) s += __shfl_xor(s, off, 64);
  if (lane == 0) out[2 * b + c] = s + m2b[c];
  if (b == 0 && threadIdx.x == 127) out[256] = 0.f;  // distance == 0 exactly
}

// ---------------- launch ----------------
extern "C" void kernel_launch(void* const* d_in, const int* in_sizes, int n_in,
                              void* d_out, int out_size, void* d_ws, size_t ws_size,
                              hipStream_t stream) {
  const float* src   = (const float*)d_in[0];
  const float* stat  = (const float*)d_in[1];
  const float* times = (const float*)d_in[2];
  const int*   lens  = (const int*)d_in[3];
  const float* R_u   = (const float*)d_in[4];
  const float* emb_w = (const float*)d_in[5];
  const float* emb_b = (const float*)d_in[6];
  const float* Wv1   = (const float*)d_in[7];
  const float* bv1   = (const float*)d_in[8];
  const float* Wv2   = (const float*)d_in[9];
  const float* bv2   = (const float*)d_in[10];
  const float* ipw   = (const float*)d_in[11];
  const float* ipb   = (const float*)d_in[12];
  const float* ow    = (const float*)d_in[13];
  const float* ob    = (const float*)d_in[14];
  const float* l1w   = (const float*)d_in[15];
  const float* l1b   = (const float*)d_in[16];
  const float* l2w   = (const float*)d_in[17];
  const float* l2b   = (const float*)d_in[18];
  const float* ln1s  = (const float*)d_in[19];
  const float* ln1bb = (const float*)d_in[20];
  const float* ln2s  = (const float*)d_in[21];
  const float* ln2bb = (const float*)d_in[22];
  const float* m1w   = (const float*)d_in[23];
  const float* m1b   = (const float*)d_in[24];
  const float* m2w   = (const float*)d_in[25];
  const float* m2b   = (const float*)d_in[26];
  float* out = (float*)d_out;

  // ---- workspace layout (bytes) ----
  char* p = (char*)d_ws;
  float*  x      = (float*)p;   p += 17612800;  // 27520 x 160 fp32
  ushort* x16    = (ushort*)p;  p += 8806400;   // 27520 x 160 bf16
  float*  v2acc  = (float*)p;   p += 442368;    // 128 x 864 fp32
  ushort* s1b    = (ushort*)p;  p += 221184;    // 128 x 864 bf16
  ushort* obuf16 = (ushort*)p;  p += 8806400;   // 27520 x 160 bf16
  ushort* wv1b   = (ushort*)p;  p += 1492992;   // 864 x 864 bf16
  ushort* wv2b   = (ushort*)p;  p += 1492992;
  ushort* ipwb   = (ushort*)p;  p += 307200;    // 2 x 480 x 160
  ushort* owb    = (ushort*)p;  p += 102400;    // 2 x 160 x 160
  ushort* l1wb   = (ushort*)p;  p += 81920;     // 2 x 128 x 160
  ushort* l2wb   = (ushort*)p;  p += 81920;     // 2 x 160 x 128
  float*  featacc= (float*)p;   p += 100352;    // 128 x 196 fp32
  float*  m1o    = (float*)p;   p += 100352;    // 128 x 196 fp32
  char*   R2     = p;                           // shared big region
  ushort* xb16   = (ushort*)R2;                 // phase A: 4608 x 864 bf16
  float*  V1     = (float*)(R2 + 7962624);      // phase A: 4608 x 860 fp32
  ushort* qkv16  = (ushort*)R2;                 // phase B: 27520 x 480 bf16 (26.42 MB)
  float*  t1     = (float*)R2;                  // post-attn: 27520 x 160 fp32
  ushort* ffb16  = (ushort*)(R2 + 17612800);    // 27520 x 128 bf16
  ushort* vt     = (ushort*)(R2 + 26419200);    // 512 x 48 x 224 bf16 (11 MB)

  k_prep<<<7633, 256, 0, stream>>>(Wv1, Wv2, ipw, ow, l1w, l2w,
                                   wv1b, wv2b, ipwb, owb, l1wb, l2wb, v2acc, featacc);
  k_xb16<<<3870, 256, 0, stream>>>(src, R_u, xb16);

  // V1 = relu(xb @ Wv1^T + bv1)
  gemm_bf16<1, 0, 0><<<dim3(14, 36, 1), 256, 0, stream>>>(xb16, wv1b, bv1, V1, KPG, 860, 860, 27);
  k_red_s1<<<432, 256, 0, stream>>>(V1, s1b);
  gemm_bf16<0, 1, 0><<<dim3(14, 1, 3), 256, 0, stream>>>(s1b, wv2b, nullptr, v2acc, KPG, KPG, KPG, 9);
  k_buildx<<<4300, 256, 0, stream>>>(v2acc, bv2, times, x, x16);

  for (int l = 0; l < 2; l++) {
    gemm_bf16<0, 0, 1><<<dim3(8, 215, 1), 256, 0, stream>>>(
        x16, ipwb + (size_t)l * 76800, ipb + l * 480, qkv16, 160, 480, 480, 5);
    k_vt<<<448, 256, 0, stream>>>(qkv16, vt);
    k_attn3<<<dim3(512, 14), 64, 0, stream>>>(qkv16, vt, lens, obuf16);
    gemm_bf16<0, 0, 0><<<dim3(3, 215, 1), 256, 0, stream>>>(
        obuf16, owb + (size_t)l * 25600, ob + l * 160, t1, 160, 160, 160, 5);
    k_lnres<<<6880, 256, 0, stream>>>(x, t1, ln1s + l * 160, ln1bb + l * 160, x16);
    gemm_bf16<1, 0, 1><<<dim3(2, 215, 1), 256, 0, stream>>>(
        x16, l1wb + (size_t)l * 20480, l1b + l * 128, ffb16, 160, 128, 128, 5);
    gemm_bf16<0, 0, 0><<<dim3(3, 215, 1), 256, 0, stream>>>(
        ffb16, l2wb + (size_t)l * 20480, l2b + l * 160, t1, 128, 160, 160, 4);
    k_lnres<<<6880, 256, 0, stream>>>(x, t1, ln2s + l * 160, ln2bb + l * 160, x16);
  }

  k_agg<<<dim3(8, 128), 256, 0, stream>>>(x, lens, stat, emb_w, emb_b, featacc);
  k_mlp1<<<dim3(49, 128), 256, 0, stream>>>(featacc, lens, m1w, m1b, m1o);
  k_logits<<<128, 128, 0, stream>>>(m1o, m2w, m2b, out);
}

// Round 7
// 266.681 us; speedup vs baseline: 6.6284x; 1.1178x over previous
//
#include <hip/hip_runtime.h>
#include <math.h>

#define T_LEN 215
#define B_N   128
#define DINP  36
#define D_TR  160
#define HD    40
#define D_FIN 196
#define KPG   864   // 860 padded to mult of 32

typedef __attribute__((ext_vector_type(8))) short short8v;
typedef __attribute__((ext_vector_type(4))) float f32x4;

__device__ __forceinline__ ushort f2bf(float x) {
  union { float f; unsigned u; } c; c.f = x;
  unsigned r = c.u + 0x7fffu + ((c.u >> 16) & 1u);
  return (ushort)(r >> 16);
}
__device__ __forceinline__ float bf2f(ushort h) {
  union { unsigned u; float f; } c; c.u = ((unsigned)h) << 16;
  return c.f;
}

// ---------------- fused weight prep: bf16 conversions + pads + zeros ----------------
__global__ __launch_bounds__(256) void k_prep(const float* __restrict__ Wv1,
    const float* __restrict__ Wv2, const float* __restrict__ ipw, const float* __restrict__ ow,
    const float* __restrict__ l1w, const float* __restrict__ l2w,
    ushort* __restrict__ wv1b, ushort* __restrict__ wv2b, ushort* __restrict__ ipwb,
    ushort* __restrict__ owb, ushort* __restrict__ l1wb, ushort* __restrict__ l2wb,
    float* __restrict__ v2acc, float* __restrict__ featacc) {
  int i = blockIdx.x * 256 + threadIdx.x;
  if (i < 746496) { int n = i / KPG, k = i % KPG;
    wv1b[i] = (n < 860 && k < 860) ? f2bf(Wv1[n * 860 + k]) : (ushort)0; return; }
  i -= 746496;
  if (i < 746496) { int n = i / KPG, k = i % KPG;
    wv2b[i] = (n < 860 && k < 860) ? f2bf(Wv2[n * 860 + k]) : (ushort)0; return; }
  i -= 746496;
  if (i < 153600) { ipwb[i] = f2bf(ipw[i]); return; }
  i -= 153600;
  if (i < 51200)  { owb[i] = f2bf(ow[i]); return; }
  i -= 51200;
  if (i < 40960)  { l1wb[i] = f2bf(l1w[i]); return; }
  i -= 40960;
  if (i < 40960)  { l2wb[i] = f2bf(l2w[i]); return; }
  i -= 40960;
  if (i < 110592) { v2acc[i] = 0.f; return; }
  i -= 110592;
  if (i < 25088)  { featacc[i] = 0.f; return; }
}

// ---------------- coalesced xb16 via LDS transpose: block per b ----------------
__global__ __launch_bounds__(256) void k_xb16(const float* __restrict__ src,
    const float* __restrict__ R_u, ushort* __restrict__ xb16) {
  __shared__ float Ss[T_LEN * DINP];
  const int b = blockIdx.x, tid = threadIdx.x;
  for (int i = tid; i < T_LEN * DINP; i += 256) {
    int t = i / DINP, j = i - t * DINP;
    Ss[i] = src[((size_t)t * B_N + b) * 72 + j];
  }
  __syncthreads();
  for (int i = tid; i < DINP * T_LEN; i += 256) {
    int ii = i / T_LEN, t = i - ii * T_LEN;
    float v = Ss[t * DINP + ii];
    float4 r = ((const float4*)R_u)[ii];
    ushort4 o;
    o.x = f2bf(fmaxf(v * r.x, 0.f)); o.y = f2bf(fmaxf(v * r.y, 0.f));
    o.z = f2bf(fmaxf(v * r.z, 0.f)); o.w = f2bf(fmaxf(v * r.w, 0.f));
    ushort* row = xb16 + (size_t)(b * DINP + ii) * KPG;
    *(ushort4*)(row + 4 * t) = o;
    if (t == 0) { ushort4 z = {0, 0, 0, 0}; *(ushort4*)(row + 860) = z; }
  }
}

// s1_16[b,n] = bf16( (1/36) sum_i V1b[b*36+i, n] ), stride KPG, zero-pad
__global__ __launch_bounds__(256) void k_red_s1(const ushort* __restrict__ V1b, ushort* __restrict__ s1) {
  int idx = blockIdx.x * 256 + threadIdx.x;
  if (idx >= B_N * KPG) return;
  int b = idx / KPG, n = idx % KPG;
  float s = 0.f;
  if (n < 860) {
    #pragma unroll 4
    for (int i = 0; i < DINP; i++) s += bf2f(V1b[((size_t)b * DINP + i) * 860 + n]);
    s *= (1.0f / 36.0f);
  }
  s1[idx] = (n < 860) ? f2bf(s) : (ushort)0;
}

// x[t,b,*] (fp32 + bf16) from relu(v2acc + bv2) and inline positional encoding
__global__ __launch_bounds__(256) void k_buildx(const float* __restrict__ v2acc,
    const float* __restrict__ bv2, const float* __restrict__ times,
    float* __restrict__ x, ushort* __restrict__ x16) {
  int idx = blockIdx.x * 256 + threadIdx.x;
  if (idx >= T_LEN * B_N * 40) return;
  int c = idx % 40;
  int r = idx / 40;            // r = t*B + b
  int t = r / B_N, b = r % B_N;
  float4 f;
  if (c < 36) {
    float4 a = *(const float4*)&v2acc[(size_t)b * KPG + 4 * t];
    float4 bb = *(const float4*)&bv2[4 * t];
    f.x = fmaxf(a.x + bb.x, 0.f); f.y = fmaxf(a.y + bb.y, 0.f);
    f.z = fmaxf(a.z + bb.z, 0.f); f.w = fmaxf(a.w + bb.w, 0.f);
  } else {
    float tm = times[r];
    int j0 = (c - 36) * 4;
    bool is_sin = j0 < 8;
    int kb = j0 & 7;
    float o[4];
    #pragma unroll
    for (int qq = 0; qq < 4; qq++) {
      float ts = expf((float)(kb + qq) * 0.76723400f);  // 215^(k/7)
      float sc = tm / ts;
      o[qq] = is_sin ? sinf(sc) : cosf(sc);
    }
    f.x = o[0]; f.y = o[1]; f.z = o[2]; f.w = o[3];
  }
  ((float4*)(x + (size_t)r * D_TR))[c] = f;
  ushort4 h = {f2bf(f.x), f2bf(f.y), f2bf(f.z), f2bf(f.w)};
  *(ushort4*)(x16 + (size_t)r * D_TR + 4 * c) = h;
}

// ---------------- bf16 MFMA GEMM: C = act(A[M,KP] @ W[N,KP]^T + bias) ----------------
// BM=128, BN=64, BK=32, 256 threads (4 waves). M%128==0; store guard via ncols.
template <int RELU, int SPLIT, int WMODE>
__global__ __launch_bounds__(256) void gemm_bf16(const ushort* __restrict__ A,
    const ushort* __restrict__ W, const float* __restrict__ bias, void* __restrict__ Cv,
    int KP, int ldc, int ncols, int kts) {
  __shared__ ushort As[128 * 32];
  __shared__ ushort Ws[64 * 32];
  const int tid = threadIdx.x;
  const int wave = tid >> 6, lane = tid & 63;
  const int lr = lane & 15, hi = lane >> 4;
  const int m0 = blockIdx.y * 128, n0 = blockIdx.x * 64;
  const int kt0 = blockIdx.z * kts;

  f32x4 acc[2][4];
  #pragma unroll
  for (int i = 0; i < 2; i++)
    #pragma unroll
    for (int j = 0; j < 4; j++) acc[i][j] = (f32x4){0.f, 0.f, 0.f, 0.f};

  const int ar = tid >> 2, g = tid & 3;
  const size_t abase0 = (size_t)(m0 + ar) * KP;
  const size_t abase1 = (size_t)(m0 + ar + 64) * KP;
  const size_t bbase  = (size_t)(n0 + ar) * KP;
  const int awb0 = ar * 64 + ((g * 16) ^ ((ar & 3) << 4));
  const int awb1 = awb0 + 64 * 64;
  const int bwb  = ar * 64 + ((g * 16) ^ ((ar & 3) << 4));

  const int arow0 = wave * 32 + lr;
  const int arb0 = arow0 * 64 + ((hi * 16) ^ ((arow0 & 3) << 4));
  const int arb1 = (arow0 + 16) * 64 + ((hi * 16) ^ (((arow0 + 16) & 3) << 4));
  int brb[4];
  #pragma unroll
  for (int j = 0; j < 4; j++)
    brb[j] = (j * 16 + lr) * 64 + ((hi * 16) ^ ((lr & 3) << 4));

  for (int kt = 0; kt < kts; ++kt) {
    const int k0 = (kt0 + kt) * 32;
    uint4 va0 = *(const uint4*)(A + abase0 + k0 + g * 8);
    uint4 va1 = *(const uint4*)(A + abase1 + k0 + g * 8);
    uint4 vb  = *(const uint4*)(W + bbase  + k0 + g * 8);
    if (kt) __syncthreads();
    *(uint4*)((char*)As + awb0) = va0;
    *(uint4*)((char*)As + awb1) = va1;
    *(uint4*)((char*)Ws + bwb)  = vb;
    __syncthreads();
    short8v a0 = *(const short8v*)((const char*)As + arb0);
    short8v a1 = *(const short8v*)((const char*)As + arb1);
    short8v bfr[4];
    #pragma unroll
    for (int j = 0; j < 4; j++) bfr[j] = *(const short8v*)((const char*)Ws + brb[j]);
    #pragma unroll
    for (int j = 0; j < 4; j++) {
      acc[0][j] = __builtin_amdgcn_mfma_f32_16x16x32_bf16(a0, bfr[j], acc[0][j], 0, 0, 0);
      acc[1][j] = __builtin_amdgcn_mfma_f32_16x16x32_bf16(a1, bfr[j], acc[1][j], 0, 0, 0);
    }
  }

  #pragma unroll
  for (int i = 0; i < 2; i++) {
    #pragma unroll
    for (int j = 0; j < 4; j++) {
      int col = n0 + j * 16 + lr;
      int row = m0 + wave * 32 + i * 16 + hi * 4;
      if (col < ncols) {
        if (SPLIT) {
          #pragma unroll
          for (int r = 0; r < 4; r++)
            atomicAdd((float*)Cv + (size_t)(row + r) * ldc + col, acc[i][j][r]);
        } else {
          float bb = bias ? bias[col] : 0.f;
          #pragma unroll
          for (int r = 0; r < 4; r++) {
            float xv = acc[i][j][r] + bb;
            if (RELU) xv = fmaxf(xv, 0.f);
            if (WMODE == 0) ((float*)Cv)[(size_t)(row + r) * ldc + col] = xv;
            else            ((ushort*)Cv)[(size_t)(row + r) * ldc + col] = f2bf(xv);
          }
        }
      }
    }
  }
}

// ---------------- fused GEMM(N=160) + bias + residual + LayerNorm ----------------
// BM=64, BN=160 (full row), 256 threads (4 waves). A bf16 [27520,KP], W [160,KP].
__global__ __launch_bounds__(256) void gemm_ln(const ushort* __restrict__ A,
    const ushort* __restrict__ W, const float* __restrict__ bias,
    const float* __restrict__ gam, const float* __restrict__ bet,
    float* __restrict__ x, ushort* __restrict__ x16, int KP, int kts) {
  __shared__ ushort As[64 * 32];
  __shared__ ushort Ws[160 * 32];
  const int tid = threadIdx.x;
  const int wave = tid >> 6, lane = tid & 63;
  const int lr = lane & 15, hi = lane >> 4;
  const int m0 = blockIdx.x * 64;

  f32x4 acc[10];
  #pragma unroll
  for (int j = 0; j < 10; j++) acc[j] = (f32x4){0.f, 0.f, 0.f, 0.f};

  const int ar = tid >> 2, g = tid & 3;             // A: 256 granules, 1/thread
  const size_t abase = (size_t)(m0 + ar) * KP;
  const int awb = ar * 64 + ((g * 16) ^ ((ar & 3) << 4));
  // W: 640 granules: tid, tid+256, tid+512 (tid<128)
  const int wr0 = tid >> 2,        ws0 = tid & 3;
  const int wr1 = (tid + 256) >> 2, ws1 = (tid + 256) & 3;
  const int wr2 = (tid + 512) >> 2, ws2 = (tid + 512) & 3;
  const int wwb0 = wr0 * 64 + ((ws0 * 16) ^ ((wr0 & 3) << 4));
  const int wwb1 = wr1 * 64 + ((ws1 * 16) ^ ((wr1 & 3) << 4));
  const int wwb2 = wr2 * 64 + ((ws2 * 16) ^ ((wr2 & 3) << 4));

  const int arow = wave * 16 + lr;
  const int arb = arow * 64 + ((hi * 16) ^ ((arow & 3) << 4));
  int brb[10];
  #pragma unroll
  for (int j = 0; j < 10; j++)
    brb[j] = (j * 16 + lr) * 64 + ((hi * 16) ^ ((lr & 3) << 4));

  for (int kt = 0; kt < kts; ++kt) {
    const int k0 = kt * 32;
    uint4 va = *(const uint4*)(A + abase + k0 + g * 8);
    uint4 w0 = *(const uint4*)(W + (size_t)wr0 * KP + k0 + ws0 * 8);
    uint4 w1 = *(const uint4*)(W + (size_t)wr1 * KP + k0 + ws1 * 8);
    uint4 w2;
    if (tid < 128) w2 = *(const uint4*)(W + (size_t)wr2 * KP + k0 + ws2 * 8);
    if (kt) __syncthreads();
    *(uint4*)((char*)As + awb) = va;
    *(uint4*)((char*)Ws + wwb0) = w0;
    *(uint4*)((char*)Ws + wwb1) = w1;
    if (tid < 128) *(uint4*)((char*)Ws + wwb2) = w2;
    __syncthreads();
    short8v a0 = *(const short8v*)((const char*)As + arb);
    #pragma unroll
    for (int j = 0; j < 10; j++) {
      short8v bf = *(const short8v*)((const char*)Ws + brb[j]);
      acc[j] = __builtin_amdgcn_mfma_f32_16x16x32_bf16(a0, bf, acc[j], 0, 0, 0);
    }
  }

  // epilogue: v = acc + bias + x_old; LN over the 160 cols of each row.
  const int rb = m0 + wave * 16 + hi * 4;
  float s[4] = {0.f, 0.f, 0.f, 0.f};
  #pragma unroll
  for (int j = 0; j < 10; j++) {
    const int col = j * 16 + lr;
    const float bb = bias[col];
    #pragma unroll
    for (int r = 0; r < 4; r++) {
      float v = acc[j][r] + bb + x[(size_t)(rb + r) * D_TR + col];
      acc[j][r] = v;
      s[r] += v;
    }
  }
  #pragma unroll
  for (int r = 0; r < 4; r++) {
    s[r] += __shfl_xor(s[r], 1, 64);
    s[r] += __shfl_xor(s[r], 2, 64);
    s[r] += __shfl_xor(s[r], 4, 64);
    s[r] += __shfl_xor(s[r], 8, 64);
  }
  float mu[4], q2[4] = {0.f, 0.f, 0.f, 0.f};
  #pragma unroll
  for (int r = 0; r < 4; r++) mu[r] = s[r] * (1.0f / 160.0f);
  #pragma unroll
  for (int j = 0; j < 10; j++)
    #pragma unroll
    for (int r = 0; r < 4; r++) {
      float d = acc[j][r] - mu[r];
      q2[r] += d * d;
    }
  #pragma unroll
  for (int r = 0; r < 4; r++) {
    q2[r] += __shfl_xor(q2[r], 1, 64);
    q2[r] += __shfl_xor(q2[r], 2, 64);
    q2[r] += __shfl_xor(q2[r], 4, 64);
    q2[r] += __shfl_xor(q2[r], 8, 64);
  }
  float rstd[4];
  #pragma unroll
  for (int r = 0; r < 4; r++) rstd[r] = rsqrtf(q2[r] * (1.0f / 160.0f) + 1e-5f);
  #pragma unroll
  for (int j = 0; j < 10; j++) {
    const int col = j * 16 + lr;
    const float gc = gam[col], bc = bet[col];
    #pragma unroll
    for (int r = 0; r < 4; r++) {
      float o = (acc[j][r] - mu[r]) * rstd[r] * gc + bc;
      x[(size_t)(rb + r) * D_TR + col] = o;
      x16[(size_t)(rb + r) * D_TR + col] = f2bf(o);
    }
  }
}

// ---------------- fragment packer: Qf/Kf [bh][14][80][8], Vf [bh][7][3][64][8] ----------------
__global__ __launch_bounds__(256) void k_frag(const ushort* __restrict__ qkv,
    const int* __restrict__ lengths, ushort* __restrict__ Qf,
    ushort* __restrict__ Kf, ushort* __restrict__ Vf) {
  __shared__ ushort Vs[T_LEN * 40];
  const int bh = blockIdx.x, b = bh >> 2, h = bh & 3, tid = threadIdx.x;
  int L = lengths[b]; if (L > T_LEN) L = T_LEN;
  const int nt = (L + 15) >> 4, nvt = (L + 31) >> 5;

  // stage V rows into LDS (coalesced 80B rows)
  for (int i = tid; i < T_LEN * 5; i += 256) {
    int t = i / 5, g = i - t * 5;
    *(uint4*)&Vs[t * 40 + g * 8] =
        *(const uint4*)(qkv + ((size_t)t * B_N + b) * 480 + 320 + h * 40 + g * 8);
  }

  // Q/K fragments (tile-major; 160 tasks/tile: 80 Q + 80 K)
  for (int i = tid; i < nt * 160; i += 256) {
    int tile = i / 160, e = i - tile * 160;
    int isK = e >= 80; if (isK) e -= 80;
    int t, d0;
    if (e < 64) { t = tile * 16 + (e & 15); d0 = (e >> 4) * 8; }
    else        { t = tile * 16 + (e - 64); d0 = 32; }
    uint4 v = {0, 0, 0, 0};
    if (t < T_LEN)
      v = *(const uint4*)(qkv + ((size_t)t * B_N + b) * 480 + (isK ? 160 : 0) + h * 40 + d0);
    ushort* dst = (isK ? Kf : Qf) + (((size_t)bh * 14 + tile) * 80 + e) * 8;
    *(uint4*)dst = v;
  }
  __syncthreads();

  // V fragments (transpose from LDS): lane l of (kt,ds): d=ds*16+lr, k=kt*32+hi*8+e
  for (int i = tid; i < nvt * 192; i += 256) {
    int kt = i / 192, e = i - kt * 192;
    int l = e & 63, ds = e >> 6;
    int lr = l & 15, hi2 = l >> 4;
    int d = ds * 16 + lr, k0 = kt * 32 + hi2 * 8;
    ushort tmp[8];
    #pragma unroll
    for (int e2 = 0; e2 < 8; e2++) {
      int k = k0 + e2;
      tmp[e2] = (d < 40 && k < T_LEN) ? Vs[k * 40 + d] : (ushort)0;
    }
    *(uint4*)(Vf + (((size_t)bh * 7 + kt) * 192 + e) * 8) = *(uint4*)tmp;
  }
}

// ---------------- barrier-free 1-wave flash attention (fragment-packed inputs) ----------------
__global__ __launch_bounds__(64) void k_attn3(const ushort* __restrict__ Qf,
    const ushort* __restrict__ Kf, const ushort* __restrict__ Vf,
    const int* __restrict__ lengths, ushort* __restrict__ o16) {
  __shared__ ushort SP[16 * 232];
  const int bh = blockIdx.x;
  const int b = bh >> 2, h = bh & 3;
  int L = lengths[b]; if (L > T_LEN) L = T_LEN;
  const int q0 = blockIdx.y << 4;
  if (q0 >= L) return;
  const int lane = threadIdx.x;
  const int lr = lane & 15, hi = lane >> 4;
  const int nk16 = (L + 15) >> 4;
  const int nkt  = (L + 31) >> 5;
  const float SC = 0.15811388300841898f;  // 1/sqrt(40)

  const ushort* qb = Qf + ((size_t)bh * 14 + (q0 >> 4)) * 640;
  uint4 qa0u = *(const uint4*)(qb + lane * 8);
  uint4 qa1u = {0, 0, 0, 0};
  if (hi == 0) qa1u = *(const uint4*)(qb + (64 + lr) * 8);
  short8v qa0 = *(short8v*)&qa0u;
  short8v qa1 = *(short8v*)&qa1u;

  f32x4 c[14];
  #pragma unroll
  for (int kt = 0; kt < 14; ++kt) {
    c[kt] = (f32x4){0.f, 0.f, 0.f, 0.f};
    if (kt < nk16) {
      const ushort* kb = Kf + ((size_t)bh * 14 + kt) * 640;
      uint4 kb0u = *(const uint4*)(kb + lane * 8);
      uint4 kb1u = {0, 0, 0, 0};
      if (hi == 0) kb1u = *(const uint4*)(kb + (64 + lr) * 8);
      c[kt] = __builtin_amdgcn_mfma_f32_16x16x32_bf16(qa0, *(short8v*)&kb0u, c[kt], 0, 0, 0);
      c[kt] = __builtin_amdgcn_mfma_f32_16x16x32_bf16(qa1, *(short8v*)&kb1u, c[kt], 0, 0, 0);
    }
  }

  float mx[4] = {-1e30f, -1e30f, -1e30f, -1e30f};
  #pragma unroll
  for (int kt = 0; kt < 14; ++kt) {
    if (kt < nk16) {
      bool valid = (kt * 16 + lr) < L;
      #pragma unroll
      for (int r = 0; r < 4; r++) {
        float v = valid ? c[kt][r] : -1e30f;
        mx[r] = fmaxf(mx[r], v);
      }
    }
  }
  #pragma unroll
  for (int r = 0; r < 4; r++) {
    mx[r] = fmaxf(mx[r], __shfl_xor(mx[r], 1, 64));
    mx[r] = fmaxf(mx[r], __shfl_xor(mx[r], 2, 64));
    mx[r] = fmaxf(mx[r], __shfl_xor(mx[r], 4, 64));
    mx[r] = fmaxf(mx[r], __shfl_xor(mx[r], 8, 64));
  }
  float sum[4] = {0.f, 0.f, 0.f, 0.f};
  #pragma unroll
  for (int kt = 0; kt < 14; ++kt) {
    if (kt < nk16) {
      bool valid = (kt * 16 + lr) < L;
      #pragma unroll
      for (int r = 0; r < 4; r++) {
        float p = valid ? __expf(SC * (c[kt][r] - mx[r])) : 0.f;
        sum[r] += p;
        c[kt][r] = p;
      }
    }
  }
  #pragma unroll
  for (int r = 0; r < 4; r++) {
    sum[r] += __shfl_xor(sum[r], 1, 64);
    sum[r] += __shfl_xor(sum[r], 2, 64);
    sum[r] += __shfl_xor(sum[r], 4, 64);
    sum[r] += __shfl_xor(sum[r], 8, 64);
  }

  const int nk16w = nkt * 2;
  #pragma unroll
  for (int kt = 0; kt < 14; ++kt) {
    if (kt < nk16w) {
      #pragma unroll
      for (int r = 0; r < 4; r++)
        SP[(hi * 4 + r) * 232 + kt * 16 + lr] = f2bf(c[kt][r]);
    }
  }
  __syncthreads();

  f32x4 o0 = {0.f, 0.f, 0.f, 0.f}, o1 = o0, o2 = o0;
  #pragma unroll
  for (int kt = 0; kt < 7; ++kt) {
    if (kt < nkt) {
      short8v pa = *(const short8v*)((const char*)SP + lr * 464 + kt * 64 + hi * 16);
      const ushort* vb = Vf + ((size_t)bh * 7 + kt) * 1536;
      short8v v0 = *(const short8v*)(vb + lane * 8);
      short8v v1 = *(const short8v*)(vb + 512 + lane * 8);
      short8v v2 = *(const short8v*)(vb + 1024 + lane * 8);
      o0 = __builtin_amdgcn_mfma_f32_16x16x32_bf16(pa, v0, o0, 0, 0, 0);
      o1 = __builtin_amdgcn_mfma_f32_16x16x32_bf16(pa, v1, o1, 0, 0, 0);
      o2 = __builtin_amdgcn_mfma_f32_16x16x32_bf16(pa, v2, o2, 0, 0, 0);
    }
  }

  #pragma unroll
  for (int r = 0; r < 4; r++) {
    int t = q0 + hi * 4 + r;
    if (t < T_LEN) {
      float inv = 1.0f / sum[r];
      ushort* op = o16 + ((size_t)t * B_N + b) * D_TR + h * 40;
      op[lr]      = f2bf(o0[r] * inv);
      op[16 + lr] = f2bf(o1[r] * inv);
      if (lr < 8) op[32 + lr] = f2bf(o2[r] * inv);
    }
  }
}

// ---------------- head: parallel masked sum (+emb) -> mlp1 -> logits ----------------
__global__ __launch_bounds__(256) void k_agg(const float* __restrict__ x,
    const int* __restrict__ lengths, const float* __restrict__ stat,
    const float* __restrict__ emb_w, const float* __restrict__ emb_b,
    float* __restrict__ featacc) {
  const int cx = blockIdx.x, b = blockIdx.y;
  const int tid = threadIdx.x;
  int L = lengths[b]; if (L > T_LEN) L = T_LEN;
  const int c0 = cx * 27;
  if (tid < D_TR) {
    float s = 0.f;
    #pragma unroll
    for (int tl = 0; tl < 27; ++tl) {
      int t = c0 + tl;
      if (t < L) s += x[((size_t)t * B_N + b) * D_TR + tid];
    }
    atomicAdd(&featacc[b * D_FIN + tid], s);
  } else if (cx == 0 && tid < D_FIN) {
    int i = tid - D_TR;
    float s = emb_b[i];
    #pragma unroll
    for (int k = 0; k < 9; k++) s = fmaf(stat[b * 9 + k], emb_w[i * 9 + k], s);
    featacc[b * D_FIN + tid] = s;
  }
}

__global__ __launch_bounds__(256) void k_mlp1(const float* __restrict__ featacc,
    const int* __restrict__ lengths, const float* __restrict__ m1w,
    const float* __restrict__ m1b, float* __restrict__ m1o) {
  const int b = blockIdx.y;
  const int wv = threadIdx.x >> 6, lane = threadIdx.x & 63;
  const int n = blockIdx.x * 4 + wv;
  int L = lengths[b]; if (L > T_LEN) L = T_LEN;
  const float inv = 1.0f / (float)(L + 1);
  const float* wr = m1w + (size_t)n * D_FIN;
  const float* fr = featacc + (size_t)b * D_FIN;
  float s = 0.f;
  for (int k = lane; k < D_FIN; k += 64) {
    float f = fr[k] * (k < D_TR ? inv : 1.f);
    s = fmaf(f, wr[k], s);
  }
  #pragma unroll
  for (int off = 32; off; off >>= 1) s += __shfl_xor(s, off, 64);
  if (lane == 0) m1o[(size_t)b * D_FIN + n] = fmaxf(s + m1b[n], 0.f);
}

__global__ __launch_bounds__(128) void k_logits(const float* __restrict__ m1o,
    const float* __restrict__ m2w, const float* __restrict__ m2b, float* __restrict__ out) {
  const int b = blockIdx.x;
  const int c = threadIdx.x >> 6, lane = threadIdx.x & 63;
  const float* mr = m1o + (size_t)b * D_FIN;
  const float* wr = m2w + c * D_FIN;
  float s = 0.f;
  for (int k = lane; k < D_FIN; k += 64) s = fmaf(mr[k], wr[k], s);
  #pragma unroll
  for (int off = 32; off; off >>= 1) s += __shfl_xor(s, off, 64);
  if (lane == 0) out[2 * b + c] = s + m2b[c];
  if (b == 0 && threadIdx.x == 127) out[256] = 0.f;  // distance == 0 exactly
}

// ---------------- launch ----------------
extern "C" void kernel_launch(void* const* d_in, const int* in_sizes, int n_in,
                              void* d_out, int out_size, void* d_ws, size_t ws_size,
                              hipStream_t stream) {
  const float* src   = (const float*)d_in[0];
  const float* stat  = (const float*)d_in[1];
  const float* times = (const float*)d_in[2];
  const int*   lens  = (const int*)d_in[3];
  const float* R_u   = (const float*)d_in[4];
  const float* emb_w = (const float*)d_in[5];
  const float* emb_b = (const float*)d_in[6];
  const float* Wv1   = (const float*)d_in[7];
  const float* bv1   = (const float*)d_in[8];
  const float* Wv2   = (const float*)d_in[9];
  const float* bv2   = (const float*)d_in[10];
  const float* ipw   = (const float*)d_in[11];
  const float* ipb   = (const float*)d_in[12];
  const float* ow    = (const float*)d_in[13];
  const float* ob    = (const float*)d_in[14];
  const float* l1w   = (const float*)d_in[15];
  const float* l1b   = (const float*)d_in[16];
  const float* l2w   = (const float*)d_in[17];
  const float* l2b   = (const float*)d_in[18];
  const float* ln1s  = (const float*)d_in[19];
  const float* ln1bb = (const float*)d_in[20];
  const float* ln2s  = (const float*)d_in[21];
  const float* ln2bb = (const float*)d_in[22];
  const float* m1w   = (const float*)d_in[23];
  const float* m1b   = (const float*)d_in[24];
  const float* m2w   = (const float*)d_in[25];
  const float* m2b   = (const float*)d_in[26];
  float* out = (float*)d_out;

  // ---- workspace layout (bytes), total ~95.4 MB ----
  char* p = (char*)d_ws;
  float*  x      = (float*)p;   p += 17612800;  // 27520 x 160 fp32
  ushort* x16    = (ushort*)p;  p += 8806400;   // 27520 x 160 bf16
  float*  v2acc  = (float*)p;   p += 442368;    // 128 x 864 fp32
  ushort* s1b    = (ushort*)p;  p += 221184;    // 128 x 864 bf16
  ushort* obuf16 = (ushort*)p;  p += 8806400;   // 27520 x 160 bf16
  ushort* wv1b   = (ushort*)p;  p += 1492992;   // 864 x 864 bf16
  ushort* wv2b   = (ushort*)p;  p += 1492992;
  ushort* ipwb   = (ushort*)p;  p += 307200;    // 2 x 480 x 160
  ushort* owb    = (ushort*)p;  p += 102400;    // 2 x 160 x 160
  ushort* l1wb   = (ushort*)p;  p += 81920;     // 2 x 128 x 160
  ushort* l2wb   = (ushort*)p;  p += 81920;     // 2 x 160 x 128
  float*  featacc= (float*)p;   p += 100352;    // 128 x 196 fp32
  float*  m1o    = (float*)p;   p += 100352;    // 128 x 196 fp32
  char*   R2     = p;
  ushort* xb16   = (ushort*)R2;                  // phase A: 4608 x 864 bf16 (7.96 MB)
  ushort* V1b    = (ushort*)(R2 + 7962624);      // phase A: 4608 x 860 bf16 (7.93 MB)
  ushort* qkv16  = (ushort*)R2;                  // phase B: 27520 x 480 bf16 (26.42 MB)
  ushort* ffb16  = (ushort*)R2;                  // aliases qkv16 (dead after k_frag)
  ushort* Qf     = (ushort*)(R2 + 26419200);     // 512 x 14 x 80 x 8 (9.18 MB)
  ushort* Kf     = (ushort*)(R2 + 35594240);     // 9.18 MB
  ushort* Vf     = (ushort*)(R2 + 44769280);     // 512 x 7 x 192 x 8 (11.01 MB)

  k_prep<<<7482, 256, 0, stream>>>(Wv1, Wv2, ipw, ow, l1w, l2w,
                                   wv1b, wv2b, ipwb, owb, l1wb, l2wb, v2acc, featacc);
  k_xb16<<<128, 256, 0, stream>>>(src, R_u, xb16);

  // V1b = bf16(relu(xb @ Wv1^T + bv1))
  gemm_bf16<1, 0, 1><<<dim3(14, 36, 1), 256, 0, stream>>>(xb16, wv1b, bv1, V1b, KPG, 860, 860, 27);
  k_red_s1<<<432, 256, 0, stream>>>(V1b, s1b);
  gemm_bf16<0, 1, 0><<<dim3(14, 1, 3), 256, 0, stream>>>(s1b, wv2b, nullptr, v2acc, KPG, KPG, KPG, 9);
  k_buildx<<<4300, 256, 0, stream>>>(v2acc, bv2, times, x, x16);

  for (int l = 0; l < 2; l++) {
    gemm_bf16<0, 0, 1><<<dim3(8, 215, 1), 256, 0, stream>>>(
        x16, ipwb + (size_t)l * 76800, ipb + l * 480, qkv16, 160, 480, 480, 5);
    k_frag<<<512, 256, 0, stream>>>(qkv16, lens, Qf, Kf, Vf);
    k_attn3<<<dim3(512, 14), 64, 0, stream>>>(Qf, Kf, Vf, lens, obuf16);
    gemm_ln<<<430, 256, 0, stream>>>(obuf16, owb + (size_t)l * 25600, ob + l * 160,
                                     ln1s + l * 160, ln1bb + l * 160, x, x16, 160, 5);
    gemm_bf16<1, 0, 1><<<dim3(2, 215, 1), 256, 0, stream>>>(
        x16, l1wb + (size_t)l * 20480, l1b + l * 128, ffb16, 160, 128, 128, 5);
    gemm_ln<<<430, 256, 0, stream>>>(ffb16, l2wb + (size_t)l * 20480, l2b + l * 160,
                                     ln2s + l * 160, ln2bb + l * 160, x, x16, 128, 4);
  }

  k_agg<<<dim3(8, 128), 256, 0, stream>>>(x, lens, stat, emb_w, emb_b, featacc);
  k_mlp1<<<dim3(49, 128), 256, 0, stream>>>(featacc, lens, m1w, m1b, m1o);
  k_logits<<<128, 128, 0, stream>>>(m1o, m2w, m2b, out);
}

// Round 8
// 254.114 us; speedup vs baseline: 6.9562x; 1.0495x over previous
//
#include <hip/hip_runtime.h>
#include <math.h>

#define T_LEN 215
#define TP    224   // padded T (14 * 16)
#define B_N   128
#define DINP  36
#define D_TR  160
#define HD    40
#define D_FIN 196
#define KPG   864   // 860 padded to mult of 32
#define MROW  28672 // 128 * 224 b-major rows

typedef __attribute__((ext_vector_type(8))) short short8v;
typedef __attribute__((ext_vector_type(4))) float f32x4;

__device__ __forceinline__ ushort f2bf(float x) {
  union { float f; unsigned u; } c; c.f = x;
  unsigned r = c.u + 0x7fffu + ((c.u >> 16) & 1u);
  return (ushort)(r >> 16);
}
__device__ __forceinline__ float bf2f(ushort h) {
  union { unsigned u; float f; } c; c.u = ((unsigned)h) << 16;
  return c.f;
}

// ---------------- fused weight prep: bf16 conversions + pads + zeros + obuf pad ----------------
__global__ __launch_bounds__(256) void k_prep(const float* __restrict__ Wv1,
    const float* __restrict__ Wv2, const float* __restrict__ ipw, const float* __restrict__ ow,
    const float* __restrict__ l1w, const float* __restrict__ l2w,
    ushort* __restrict__ wv1b, ushort* __restrict__ wv2b, ushort* __restrict__ ipwb,
    ushort* __restrict__ owb, ushort* __restrict__ l1wb, ushort* __restrict__ l2wb,
    float* __restrict__ v2acc, float* __restrict__ featacc, ushort* __restrict__ obuf16) {
  int i = blockIdx.x * 256 + threadIdx.x;
  if (i < 746496) { int n = i / KPG, k = i % KPG;
    wv1b[i] = (n < 860 && k < 860) ? f2bf(Wv1[n * 860 + k]) : (ushort)0; return; }
  i -= 746496;
  if (i < 746496) { int n = i / KPG, k = i % KPG;
    wv2b[i] = (n < 860 && k < 860) ? f2bf(Wv2[n * 860 + k]) : (ushort)0; return; }
  i -= 746496;
  if (i < 153600) { ipwb[i] = f2bf(ipw[i]); return; }
  i -= 153600;
  if (i < 51200)  { owb[i] = f2bf(ow[i]); return; }
  i -= 51200;
  if (i < 40960)  { l1wb[i] = f2bf(l1w[i]); return; }
  i -= 40960;
  if (i < 40960)  { l2wb[i] = f2bf(l2w[i]); return; }
  i -= 40960;
  if (i < 110592) { v2acc[i] = 0.f; return; }
  i -= 110592;
  if (i < 25088)  { featacc[i] = 0.f; return; }
  i -= 25088;
  if (i < 184320) {  // zero obuf16 pad rows t in [215,224) so LN chain stays finite
    int b = i / 1440, rem = i % 1440;
    int t = 215 + rem / 160, cc = rem % 160;
    obuf16[((size_t)b * TP + t) * D_TR + cc] = 0; return;
  }
}

// ---------------- coalesced xb16 via LDS transpose: block per b ----------------
__global__ __launch_bounds__(256) void k_xb16(const float* __restrict__ src,
    const float* __restrict__ R_u, ushort* __restrict__ xb16) {
  __shared__ float Ss[T_LEN * DINP];
  const int b = blockIdx.x, tid = threadIdx.x;
  for (int i = tid; i < T_LEN * DINP; i += 256) {
    int t = i / DINP, j = i - t * DINP;
    Ss[i] = src[((size_t)t * B_N + b) * 72 + j];
  }
  __syncthreads();
  for (int i = tid; i < DINP * T_LEN; i += 256) {
    int ii = i / T_LEN, t = i - ii * T_LEN;
    float v = Ss[t * DINP + ii];
    float4 r = ((const float4*)R_u)[ii];
    ushort4 o;
    o.x = f2bf(fmaxf(v * r.x, 0.f)); o.y = f2bf(fmaxf(v * r.y, 0.f));
    o.z = f2bf(fmaxf(v * r.z, 0.f)); o.w = f2bf(fmaxf(v * r.w, 0.f));
    ushort* row = xb16 + (size_t)(b * DINP + ii) * KPG;
    *(ushort4*)(row + 4 * t) = o;
    if (t == 0) { ushort4 z = {0, 0, 0, 0}; *(ushort4*)(row + 860) = z; }
  }
}

// s1_16[b,n] = bf16( (1/36) sum_i V1b[b*36+i, n] ), stride KPG, zero-pad
__global__ __launch_bounds__(256) void k_red_s1(const ushort* __restrict__ V1b, ushort* __restrict__ s1) {
  int idx = blockIdx.x * 256 + threadIdx.x;
  if (idx >= B_N * KPG) return;
  int b = idx / KPG, n = idx % KPG;
  float s = 0.f;
  if (n < 860) {
    #pragma unroll 4
    for (int i = 0; i < DINP; i++) s += bf2f(V1b[((size_t)b * DINP + i) * 860 + n]);
    s *= (1.0f / 36.0f);
  }
  s1[idx] = (n < 860) ? f2bf(s) : (ushort)0;
}

// x[b,t,*] (fp32 + bf16, b-major) from relu(v2acc + bv2) and inline pe; pad rows zeroed
__global__ __launch_bounds__(256) void k_buildx(const float* __restrict__ v2acc,
    const float* __restrict__ bv2, const float* __restrict__ times,
    float* __restrict__ x, ushort* __restrict__ x16) {
  int idx = blockIdx.x * 256 + threadIdx.x;
  if (idx >= B_N * TP * 40) return;
  int c = idx % 40;
  int r = idx / 40;            // r = b*224 + t
  int t = r % TP, b = r / TP;
  float4 f = {0.f, 0.f, 0.f, 0.f};
  if (t < T_LEN) {
    if (c < 36) {
      float4 a = *(const float4*)&v2acc[(size_t)b * KPG + 4 * t];
      float4 bb = *(const float4*)&bv2[4 * t];
      f.x = fmaxf(a.x + bb.x, 0.f); f.y = fmaxf(a.y + bb.y, 0.f);
      f.z = fmaxf(a.z + bb.z, 0.f); f.w = fmaxf(a.w + bb.w, 0.f);
    } else {
      float tm = times[t * B_N + b];
      int j0 = (c - 36) * 4;
      bool is_sin = j0 < 8;
      int kb = j0 & 7;
      float o[4];
      #pragma unroll
      for (int qq = 0; qq < 4; qq++) {
        float ts = expf((float)(kb + qq) * 0.76723400f);  // 215^(k/7)
        float sc = tm / ts;
        o[qq] = is_sin ? sinf(sc) : cosf(sc);
      }
      f.x = o[0]; f.y = o[1]; f.z = o[2]; f.w = o[3];
    }
  }
  ((float4*)(x + (size_t)r * D_TR))[c] = f;
  ushort4 h = {f2bf(f.x), f2bf(f.y), f2bf(f.z), f2bf(f.w)};
  *(ushort4*)(x16 + (size_t)r * D_TR + 4 * c) = h;
}

// ---------------- bf16 MFMA GEMM: C = act(A[M,KP] @ W[N,KP]^T + bias), BN templated ----------------
template <int RELU, int SPLIT, int WMODE, int BNT>
__global__ __launch_bounds__(256) void gemm_bf16(const ushort* __restrict__ A,
    const ushort* __restrict__ W, const float* __restrict__ bias, void* __restrict__ Cv,
    int KP, int ldc, int ncols, int kts) {
  __shared__ ushort As[128 * 32];
  __shared__ ushort Ws[BNT * 32];
  constexpr int NJ = BNT / 16;
  const int tid = threadIdx.x;
  const int wave = tid >> 6, lane = tid & 63;
  const int lr = lane & 15, hi = lane >> 4;
  const int m0 = blockIdx.y * 128, n0 = blockIdx.x * BNT;
  const int kt0 = blockIdx.z * kts;

  f32x4 acc[2][NJ];
  #pragma unroll
  for (int i = 0; i < 2; i++)
    #pragma unroll
    for (int j = 0; j < NJ; j++) acc[i][j] = (f32x4){0.f, 0.f, 0.f, 0.f};

  const int ar = tid >> 2, g = tid & 3;
  const size_t abase0 = (size_t)(m0 + ar) * KP;
  const size_t abase1 = (size_t)(m0 + ar + 64) * KP;
  const size_t bbase0 = (size_t)(n0 + ar) * KP;
  const size_t bbase1 = (size_t)(n0 + ar + 64) * KP;
  const int awb0 = ar * 64 + ((g * 16) ^ ((ar & 3) << 4));
  const int awb1 = awb0 + 64 * 64;

  const int arow0 = wave * 32 + lr;
  const int arb0 = arow0 * 64 + ((hi * 16) ^ ((arow0 & 3) << 4));
  const int arb1 = (arow0 + 16) * 64 + ((hi * 16) ^ (((arow0 + 16) & 3) << 4));
  int brb[NJ];
  #pragma unroll
  for (int j = 0; j < NJ; j++)
    brb[j] = (j * 16 + lr) * 64 + ((hi * 16) ^ ((lr & 3) << 4));

  for (int kt = 0; kt < kts; ++kt) {
    const int k0 = (kt0 + kt) * 32;
    uint4 va0 = *(const uint4*)(A + abase0 + k0 + g * 8);
    uint4 va1 = *(const uint4*)(A + abase1 + k0 + g * 8);
    uint4 vb0 = *(const uint4*)(W + bbase0 + k0 + g * 8);
    uint4 vb1;
    if constexpr (BNT == 128) vb1 = *(const uint4*)(W + bbase1 + k0 + g * 8);
    if (kt) __syncthreads();
    *(uint4*)((char*)As + awb0) = va0;
    *(uint4*)((char*)As + awb1) = va1;
    *(uint4*)((char*)Ws + awb0) = vb0;
    if constexpr (BNT == 128) *(uint4*)((char*)Ws + awb1) = vb1;
    __syncthreads();
    short8v a0 = *(const short8v*)((const char*)As + arb0);
    short8v a1 = *(const short8v*)((const char*)As + arb1);
    #pragma unroll
    for (int j = 0; j < NJ; j++) {
      short8v bf = *(const short8v*)((const char*)Ws + brb[j]);
      acc[0][j] = __builtin_amdgcn_mfma_f32_16x16x32_bf16(a0, bf, acc[0][j], 0, 0, 0);
      acc[1][j] = __builtin_amdgcn_mfma_f32_16x16x32_bf16(a1, bf, acc[1][j], 0, 0, 0);
    }
  }

  #pragma unroll
  for (int i = 0; i < 2; i++) {
    #pragma unroll
    for (int j = 0; j < NJ; j++) {
      int col = n0 + j * 16 + lr;
      int row = m0 + wave * 32 + i * 16 + hi * 4;
      if (col < ncols) {
        if (SPLIT) {
          #pragma unroll
          for (int r = 0; r < 4; r++)
            atomicAdd((float*)Cv + (size_t)(row + r) * ldc + col, acc[i][j][r]);
        } else {
          float bb = bias ? bias[col] : 0.f;
          #pragma unroll
          for (int r = 0; r < 4; r++) {
            float xv = acc[i][j][r] + bb;
            if (RELU) xv = fmaxf(xv, 0.f);
            if (WMODE == 0) ((float*)Cv)[(size_t)(row + r) * ldc + col] = xv;
            else            ((ushort*)Cv)[(size_t)(row + r) * ldc + col] = f2bf(xv);
          }
        }
      }
    }
  }
}

// ---------------- qkv GEMM (BN=128): writes Q,K to qkvB[b-major][480]; V transposed to Vt ----------------
__global__ __launch_bounds__(256) void gemm_qkv(const ushort* __restrict__ A,
    const ushort* __restrict__ W, const float* __restrict__ bias,
    ushort* __restrict__ qkvB, ushort* __restrict__ Vt, int kts) {
  __shared__ ushort As[128 * 32];
  __shared__ ushort Ws[128 * 32];
  const int KP = 160;
  const int tid = threadIdx.x;
  const int wave = tid >> 6, lane = tid & 63;
  const int lr = lane & 15, hi = lane >> 4;
  const int m0 = blockIdx.y * 128, n0 = blockIdx.x * 128;

  f32x4 acc[2][8];
  #pragma unroll
  for (int i = 0; i < 2; i++)
    #pragma unroll
    for (int j = 0; j < 8; j++) acc[i][j] = (f32x4){0.f, 0.f, 0.f, 0.f};

  const int ar = tid >> 2, g = tid & 3;
  const size_t abase0 = (size_t)(m0 + ar) * KP;
  const size_t abase1 = (size_t)(m0 + ar + 64) * KP;
  const size_t bbase0 = (size_t)(n0 + ar) * KP;
  const size_t bbase1 = (size_t)(n0 + ar + 64) * KP;
  const int awb0 = ar * 64 + ((g * 16) ^ ((ar & 3) << 4));
  const int awb1 = awb0 + 64 * 64;

  const int arow0 = wave * 32 + lr;
  const int arb0 = arow0 * 64 + ((hi * 16) ^ ((arow0 & 3) << 4));
  const int arb1 = (arow0 + 16) * 64 + ((hi * 16) ^ (((arow0 + 16) & 3) << 4));
  int brb[8];
  #pragma unroll
  for (int j = 0; j < 8; j++)
    brb[j] = (j * 16 + lr) * 64 + ((hi * 16) ^ ((lr & 3) << 4));

  for (int kt = 0; kt < kts; ++kt) {
    const int k0 = kt * 32;
    uint4 va0 = *(const uint4*)(A + abase0 + k0 + g * 8);
    uint4 va1 = *(const uint4*)(A + abase1 + k0 + g * 8);
    uint4 vb0 = *(const uint4*)(W + bbase0 + k0 + g * 8);
    uint4 vb1 = *(const uint4*)(W + bbase1 + k0 + g * 8);
    if (kt) __syncthreads();
    *(uint4*)((char*)As + awb0) = va0;
    *(uint4*)((char*)As + awb1) = va1;
    *(uint4*)((char*)Ws + awb0) = vb0;
    *(uint4*)((char*)Ws + awb1) = vb1;
    __syncthreads();
    short8v a0 = *(const short8v*)((const char*)As + arb0);
    short8v a1 = *(const short8v*)((const char*)As + arb1);
    #pragma unroll
    for (int j = 0; j < 8; j++) {
      short8v bf = *(const short8v*)((const char*)Ws + brb[j]);
      acc[0][j] = __builtin_amdgcn_mfma_f32_16x16x32_bf16(a0, bf, acc[0][j], 0, 0, 0);
      acc[1][j] = __builtin_amdgcn_mfma_f32_16x16x32_bf16(a1, bf, acc[1][j], 0, 0, 0);
    }
  }

  #pragma unroll
  for (int i = 0; i < 2; i++) {
    const int row = m0 + wave * 32 + i * 16 + hi * 4;   // = b*224 + t0 (4 consecutive t)
    const int b = row / TP, t0 = row - b * TP;
    #pragma unroll
    for (int j = 0; j < 8; j++) {
      int col = n0 + j * 16 + lr;
      if (col < 320) {               // Q or K: row-major scalar stores
        float bb = bias[col];
        #pragma unroll
        for (int r = 0; r < 4; r++)
          qkvB[(size_t)(row + r) * 480 + col] = f2bf(acc[i][j][r] + bb);
      } else if (col < 480) {        // V: transposed packed store (4 consecutive t = 8B)
        float bb = bias[col];
        int dg = col - 320;
        int hh = dg / 40, dd = dg - hh * 40;
        ushort4 pv;
        pv.x = f2bf(acc[i][j][0] + bb); pv.y = f2bf(acc[i][j][1] + bb);
        pv.z = f2bf(acc[i][j][2] + bb); pv.w = f2bf(acc[i][j][3] + bb);
        *(ushort4*)(Vt + (((size_t)(b * 4 + hh) * 48 + dd) * TP + t0)) = pv;
      }
    }
  }
}

// ---------------- fused GEMM(N=160) + bias + residual + LayerNorm (b-major) ----------------
__global__ __launch_bounds__(256) void gemm_ln(const ushort* __restrict__ A,
    const ushort* __restrict__ W, const float* __restrict__ bias,
    const float* __restrict__ gam, const float* __restrict__ bet,
    float* __restrict__ x, ushort* __restrict__ x16, int KP, int kts) {
  __shared__ ushort As[64 * 32];
  __shared__ ushort Ws[160 * 32];
  const int tid = threadIdx.x;
  const int wave = tid >> 6, lane = tid & 63;
  const int lr = lane & 15, hi = lane >> 4;
  const int m0 = blockIdx.x * 64;

  f32x4 acc[10];
  #pragma unroll
  for (int j = 0; j < 10; j++) acc[j] = (f32x4){0.f, 0.f, 0.f, 0.f};

  const int ar = tid >> 2, g = tid & 3;
  const size_t abase = (size_t)(m0 + ar) * KP;
  const int awb = ar * 64 + ((g * 16) ^ ((ar & 3) << 4));
  const int wr0 = tid >> 2,         ws0 = tid & 3;
  const int wr1 = (tid + 256) >> 2, ws1 = (tid + 256) & 3;
  const int wr2 = (tid + 512) >> 2, ws2 = (tid + 512) & 3;
  const int wwb0 = wr0 * 64 + ((ws0 * 16) ^ ((wr0 & 3) << 4));
  const int wwb1 = wr1 * 64 + ((ws1 * 16) ^ ((wr1 & 3) << 4));
  const int wwb2 = wr2 * 64 + ((ws2 * 16) ^ ((wr2 & 3) << 4));

  const int arow = wave * 16 + lr;
  const int arb = arow * 64 + ((hi * 16) ^ ((arow & 3) << 4));
  int brb[10];
  #pragma unroll
  for (int j = 0; j < 10; j++)
    brb[j] = (j * 16 + lr) * 64 + ((hi * 16) ^ ((lr & 3) << 4));

  for (int kt = 0; kt < kts; ++kt) {
    const int k0 = kt * 32;
    uint4 va = *(const uint4*)(A + abase + k0 + g * 8);
    uint4 w0 = *(const uint4*)(W + (size_t)wr0 * KP + k0 + ws0 * 8);
    uint4 w1 = *(const uint4*)(W + (size_t)wr1 * KP + k0 + ws1 * 8);
    uint4 w2;
    if (tid < 128) w2 = *(const uint4*)(W + (size_t)wr2 * KP + k0 + ws2 * 8);
    if (kt) __syncthreads();
    *(uint4*)((char*)As + awb) = va;
    *(uint4*)((char*)Ws + wwb0) = w0;
    *(uint4*)((char*)Ws + wwb1) = w1;
    if (tid < 128) *(uint4*)((char*)Ws + wwb2) = w2;
    __syncthreads();
    short8v a0 = *(const short8v*)((const char*)As + arb);
    #pragma unroll
    for (int j = 0; j < 10; j++) {
      short8v bf = *(const short8v*)((const char*)Ws + brb[j]);
      acc[j] = __builtin_amdgcn_mfma_f32_16x16x32_bf16(a0, bf, acc[j], 0, 0, 0);
    }
  }

  const int rb = m0 + wave * 16 + hi * 4;
  float s[4] = {0.f, 0.f, 0.f, 0.f};
  #pragma unroll
  for (int j = 0; j < 10; j++) {
    const int col = j * 16 + lr;
    const float bb = bias[col];
    #pragma unroll
    for (int r = 0; r < 4; r++) {
      float v = acc[j][r] + bb + x[(size_t)(rb + r) * D_TR + col];
      acc[j][r] = v;
      s[r] += v;
    }
  }
  #pragma unroll
  for (int r = 0; r < 4; r++) {
    s[r] += __shfl_xor(s[r], 1, 64);
    s[r] += __shfl_xor(s[r], 2, 64);
    s[r] += __shfl_xor(s[r], 4, 64);
    s[r] += __shfl_xor(s[r], 8, 64);
  }
  float mu[4], q2[4] = {0.f, 0.f, 0.f, 0.f};
  #pragma unroll
  for (int r = 0; r < 4; r++) mu[r] = s[r] * (1.0f / 160.0f);
  #pragma unroll
  for (int j = 0; j < 10; j++)
    #pragma unroll
    for (int r = 0; r < 4; r++) {
      float d = acc[j][r] - mu[r];
      q2[r] += d * d;
    }
  #pragma unroll
  for (int r = 0; r < 4; r++) {
    q2[r] += __shfl_xor(q2[r], 1, 64);
    q2[r] += __shfl_xor(q2[r], 2, 64);
    q2[r] += __shfl_xor(q2[r], 4, 64);
    q2[r] += __shfl_xor(q2[r], 8, 64);
  }
  float rstd[4];
  #pragma unroll
  for (int r = 0; r < 4; r++) rstd[r] = rsqrtf(q2[r] * (1.0f / 160.0f) + 1e-5f);
  #pragma unroll
  for (int j = 0; j < 10; j++) {
    const int col = j * 16 + lr;
    const float gc = gam[col], bc = bet[col];
    #pragma unroll
    for (int r = 0; r < 4; r++) {
      float o = (acc[j][r] - mu[r]) * rstd[r] * gc + bc;
      x[(size_t)(rb + r) * D_TR + col] = o;
      x16[(size_t)(rb + r) * D_TR + col] = f2bf(o);
    }
  }
}

// ---------------- barrier-free 1-wave flash attention (b-major qkv + Vt) ----------------
__global__ __launch_bounds__(64) void k_attn4(const ushort* __restrict__ qkvB,
    const ushort* __restrict__ Vt, const int* __restrict__ lengths,
    ushort* __restrict__ o16) {
  __shared__ ushort SP[16 * 232];
  const int bh = blockIdx.x;
  const int b = bh >> 2, h = bh & 3;
  int L = lengths[b]; if (L > T_LEN) L = T_LEN;
  const int q0 = blockIdx.y << 4;
  if (q0 >= L) return;
  const int lane = threadIdx.x;
  const int lr = lane & 15, hi = lane >> 4;
  const int nk16 = (L + 15) >> 4;
  const int nkt  = (L + 31) >> 5;
  const float SC = 0.15811388300841898f;  // 1/sqrt(40)

  const ushort* qrow = qkvB + ((size_t)b * TP + q0) * 480 + h * 40;
  uint4 qa0u = *(const uint4*)(qrow + lr * 480 + hi * 8);
  uint4 qa1u = {0, 0, 0, 0};
  if (hi == 0) qa1u = *(const uint4*)(qrow + lr * 480 + 32);
  short8v qa0 = *(short8v*)&qa0u;
  short8v qa1 = *(short8v*)&qa1u;

  f32x4 c[14];
  #pragma unroll
  for (int kt = 0; kt < 14; ++kt) {
    c[kt] = (f32x4){0.f, 0.f, 0.f, 0.f};
    if (kt < nk16) {
      const ushort* krow = qkvB + ((size_t)b * TP + kt * 16) * 480 + 160 + h * 40;
      uint4 kb0u = *(const uint4*)(krow + lr * 480 + hi * 8);
      uint4 kb1u = {0, 0, 0, 0};
      if (hi == 0) kb1u = *(const uint4*)(krow + lr * 480 + 32);
      c[kt] = __builtin_amdgcn_mfma_f32_16x16x32_bf16(qa0, *(short8v*)&kb0u, c[kt], 0, 0, 0);
      c[kt] = __builtin_amdgcn_mfma_f32_16x16x32_bf16(qa1, *(short8v*)&kb1u, c[kt], 0, 0, 0);
    }
  }

  float mx[4] = {-1e30f, -1e30f, -1e30f, -1e30f};
  #pragma unroll
  for (int kt = 0; kt < 14; ++kt) {
    if (kt < nk16) {
      bool valid = (kt * 16 + lr) < L;
      #pragma unroll
      for (int r = 0; r < 4; r++) {
        float v = valid ? c[kt][r] : -1e30f;
        mx[r] = fmaxf(mx[r], v);
      }
    }
  }
  #pragma unroll
  for (int r = 0; r < 4; r++) {
    mx[r] = fmaxf(mx[r], __shfl_xor(mx[r], 1, 64));
    mx[r] = fmaxf(mx[r], __shfl_xor(mx[r], 2, 64));
    mx[r] = fmaxf(mx[r], __shfl_xor(mx[r], 4, 64));
    mx[r] = fmaxf(mx[r], __shfl_xor(mx[r], 8, 64));
  }
  float sum[4] = {0.f, 0.f, 0.f, 0.f};
  #pragma unroll
  for (int kt = 0; kt < 14; ++kt) {
    if (kt < nk16) {
      bool valid = (kt * 16 + lr) < L;
      #pragma unroll
      for (int r = 0; r < 4; r++) {
        float p = valid ? __expf(SC * (c[kt][r] - mx[r])) : 0.f;
        sum[r] += p;
        c[kt][r] = p;
      }
    }
  }
  #pragma unroll
  for (int r = 0; r < 4; r++) {
    sum[r] += __shfl_xor(sum[r], 1, 64);
    sum[r] += __shfl_xor(sum[r], 2, 64);
    sum[r] += __shfl_xor(sum[r], 4, 64);
    sum[r] += __shfl_xor(sum[r], 8, 64);
  }

  const int nk16w = nkt * 2;
  #pragma unroll
  for (int kt = 0; kt < 14; ++kt) {
    if (kt < nk16w) {
      #pragma unroll
      for (int r = 0; r < 4; r++)
        SP[(hi * 4 + r) * 232 + kt * 16 + lr] = f2bf(c[kt][r]);
    }
  }
  __syncthreads();

  f32x4 o0 = {0.f, 0.f, 0.f, 0.f}, o1 = o0, o2 = o0;
  const ushort* vbase = Vt + (size_t)bh * 48 * TP;
  #pragma unroll
  for (int kt = 0; kt < 7; ++kt) {
    if (kt < nkt) {
      short8v pa = *(const short8v*)((const char*)SP + lr * 464 + kt * 64 + hi * 16);
      const ushort* vb = vbase + kt * 32 + hi * 8;
      short8v v0 = *(const short8v*)(vb + (size_t)lr * TP);
      short8v v1 = *(const short8v*)(vb + (size_t)(16 + lr) * TP);
      short8v v2 = *(const short8v*)(vb + (size_t)(32 + lr) * TP);
      o0 = __builtin_amdgcn_mfma_f32_16x16x32_bf16(pa, v0, o0, 0, 0, 0);
      o1 = __builtin_amdgcn_mfma_f32_16x16x32_bf16(pa, v1, o1, 0, 0, 0);
      o2 = __builtin_amdgcn_mfma_f32_16x16x32_bf16(pa, v2, o2, 0, 0, 0);
    }
  }

  #pragma unroll
  for (int r = 0; r < 4; r++) {
    int t = q0 + hi * 4 + r;
    if (t < T_LEN) {
      float inv = 1.0f / sum[r];
      ushort* op = o16 + ((size_t)b * TP + t) * D_TR + h * 40;
      op[lr]      = f2bf(o0[r] * inv);
      op[16 + lr] = f2bf(o1[r] * inv);
      if (lr < 8) op[32 + lr] = f2bf(o2[r] * inv);
    }
  }
}

// ---------------- head: parallel masked sum (+emb) -> mlp1 -> logits ----------------
__global__ __launch_bounds__(256) void k_agg(const float* __restrict__ x,
    const int* __restrict__ lengths, const float* __restrict__ stat,
    const float* __restrict__ emb_w, const float* __restrict__ emb_b,
    float* __restrict__ featacc) {
  const int cx = blockIdx.x, b = blockIdx.y;
  const int tid = threadIdx.x;
  int L = lengths[b]; if (L > T_LEN) L = T_LEN;
  const int c0 = cx * 27;
  if (tid < D_TR) {
    float s = 0.f;
    #pragma unroll
    for (int tl = 0; tl < 27; ++tl) {
      int t = c0 + tl;
      if (t < L) s += x[((size_t)b * TP + t) * D_TR + tid];
    }
    atomicAdd(&featacc[b * D_FIN + tid], s);
  } else if (cx == 0 && tid < D_FIN) {
    int i = tid - D_TR;
    float s = emb_b[i];
    #pragma unroll
    for (int k = 0; k < 9; k++) s = fmaf(stat[b * 9 + k], emb_w[i * 9 + k], s);
    featacc[b * D_FIN + tid] = s;
  }
}

__global__ __launch_bounds__(256) void k_mlp1(const float* __restrict__ featacc,
    const int* __restrict__ lengths, const float* __restrict__ m1w,
    const float* __restrict__ m1b, float* __restrict__ m1o) {
  const int b = blockIdx.y;
  const int wv = threadIdx.x >> 6, lane = threadIdx.x & 63;
  const int n = blockIdx.x * 4 + wv;
  int L = lengths[b]; if (L > T_LEN) L = T_LEN;
  const float inv = 1.0f / (float)(L + 1);
  const float* wr = m1w + (size_t)n * D_FIN;
  const float* fr = featacc + (size_t)b * D_FIN;
  float s = 0.f;
  for (int k = lane; k < D_FIN; k += 64) {
    float f = fr[k] * (k < D_TR ? inv : 1.f);
    s = fmaf(f, wr[k], s);
  }
  #pragma unroll
  for (int off = 32; off; off >>= 1) s += __shfl_xor(s, off, 64);
  if (lane == 0) m1o[(size_t)b * D_FIN + n] = fmaxf(s + m1b[n], 0.f);
}

__global__ __launch_bounds__(128) void k_logits(const float* __restrict__ m1o,
    const float* __restrict__ m2w, const float* __restrict__ m2b, float* __restrict__ out) {
  const int b = blockIdx.x;
  const int c = threadIdx.x >> 6, lane = threadIdx.x & 63;
  const float* mr = m1o + (size_t)b * D_FIN;
  const float* wr = m2w + c * D_FIN;
  float s = 0.f;
  for (int k = lane; k < D_FIN; k += 64) s = fmaf(mr[k], wr[k], s);
  #pragma unroll
  for (int off = 32; off; off >>= 1) s += __shfl_xor(s, off, 64);
  if (lane == 0) out[2 * b + c] = s + m2b[c];
  if (b == 0 && threadIdx.x == 127) out[256] = 0.f;  // distance == 0 exactly
}

// ---------------- launch ----------------
extern "C" void kernel_launch(void* const* d_in, const int* in_sizes, int n_in,
                              void* d_out, int out_size, void* d_ws, size_t ws_size,
                              hipStream_t stream) {
  const float* src   = (const float*)d_in[0];
  const float* stat  = (const float*)d_in[1];
  const float* times = (const float*)d_in[2];
  const int*   lens  = (const int*)d_in[3];
  const float* R_u   = (const float*)d_in[4];
  const float* emb_w = (const float*)d_in[5];
  const float* emb_b = (const float*)d_in[6];
  const float* Wv1   = (const float*)d_in[7];
  const float* bv1   = (const float*)d_in[8];
  const float* Wv2   = (const float*)d_in[9];
  const float* bv2   = (const float*)d_in[10];
  const float* ipw   = (const float*)d_in[11];
  const float* ipb   = (const float*)d_in[12];
  const float* ow    = (const float*)d_in[13];
  const float* ob    = (const float*)d_in[14];
  const float* l1w   = (const float*)d_in[15];
  const float* l1b   = (const float*)d_in[16];
  const float* l2w   = (const float*)d_in[17];
  const float* l2b   = (const float*)d_in[18];
  const float* ln1s  = (const float*)d_in[19];
  const float* ln1bb = (const float*)d_in[20];
  const float* ln2s  = (const float*)d_in[21];
  const float* ln2bb = (const float*)d_in[22];
  const float* m1w   = (const float*)d_in[23];
  const float* m1b   = (const float*)d_in[24];
  const float* m2w   = (const float*)d_in[25];
  const float* m2b   = (const float*)d_in[26];
  float* out = (float*)d_out;

  // ---- workspace layout (bytes) ----
  char* p = (char*)d_ws;
  float*  x      = (float*)p;   p += 18350080;  // 28672 x 160 fp32 (b-major)
  ushort* x16    = (ushort*)p;  p += 9175040;   // 28672 x 160 bf16
  float*  v2acc  = (float*)p;   p += 442368;    // 128 x 864 fp32
  ushort* s1b    = (ushort*)p;  p += 221184;    // 128 x 864 bf16
  ushort* obuf16 = (ushort*)p;  p += 9175040;   // 28672 x 160 bf16 (b-major)
  ushort* wv1b   = (ushort*)p;  p += 1492992;   // 864 x 864 bf16
  ushort* wv2b   = (ushort*)p;  p += 1492992;
  ushort* ipwb   = (ushort*)p;  p += 307200;    // 2 x 480 x 160
  ushort* owb    = (ushort*)p;  p += 102400;    // 2 x 160 x 160
  ushort* l1wb   = (ushort*)p;  p += 81920;     // 2 x 128 x 160
  ushort* l2wb   = (ushort*)p;  p += 81920;     // 2 x 160 x 128
  float*  featacc= (float*)p;   p += 100352;    // 128 x 196 fp32
  float*  m1o    = (float*)p;   p += 100352;    // 128 x 196 fp32
  char*   R2     = p;
  ushort* xb16   = (ushort*)R2;                  // phase A: 4608 x 864 bf16 (7.96 MB)
  ushort* V1b    = (ushort*)(R2 + 7962624);      // phase A: 4608 x 860 bf16 (7.93 MB)
  ushort* qkvB   = (ushort*)R2;                  // phase B: 128 x 224 x 480 bf16 (27.5 MB)
  ushort* ffb16  = (ushort*)R2;                  // aliases qkvB (dead after attention)
  ushort* Vt     = (ushort*)(R2 + 27525120);     // 512 x 48 x 224 bf16 (11 MB)

  k_prep<<<8202, 256, 0, stream>>>(Wv1, Wv2, ipw, ow, l1w, l2w,
                                   wv1b, wv2b, ipwb, owb, l1wb, l2wb, v2acc, featacc, obuf16);
  k_xb16<<<128, 256, 0, stream>>>(src, R_u, xb16);

  // V1b = bf16(relu(xb @ Wv1^T + bv1)), BN=128
  gemm_bf16<1, 0, 1, 128><<<dim3(7, 36, 1), 256, 0, stream>>>(
      xb16, wv1b, bv1, V1b, KPG, 860, 860, 27);
  k_red_s1<<<432, 256, 0, stream>>>(V1b, s1b);
  gemm_bf16<0, 1, 0, 64><<<dim3(14, 1, 9), 256, 0, stream>>>(
      s1b, wv2b, nullptr, v2acc, KPG, KPG, KPG, 3);
  k_buildx<<<4480, 256, 0, stream>>>(v2acc, bv2, times, x, x16);

  for (int l = 0; l < 2; l++) {
    gemm_qkv<<<dim3(4, 224, 1), 256, 0, stream>>>(
        x16, ipwb + (size_t)l * 76800, ipb + l * 480, qkvB, Vt, 5);
    k_attn4<<<dim3(512, 14), 64, 0, stream>>>(qkvB, Vt, lens, obuf16);
    gemm_ln<<<448, 256, 0, stream>>>(obuf16, owb + (size_t)l * 25600, ob + l * 160,
                                     ln1s + l * 160, ln1bb + l * 160, x, x16, 160, 5);
    gemm_bf16<1, 0, 1, 64><<<dim3(2, 224, 1), 256, 0, stream>>>(
        x16, l1wb + (size_t)l * 20480, l1b + l * 128, ffb16, 160, 128, 128, 5);
    gemm_ln<<<448, 256, 0, stream>>>(ffb16, l2wb + (size_t)l * 20480, l2b + l * 160,
                                     ln2s + l * 160, ln2bb + l * 160, x, x16, 128, 4);
  }

  k_agg<<<dim3(8, 128), 256, 0, stream>>>(x, lens, stat, emb_w, emb_b, featacc);
  k_mlp1<<<dim3(49, 128), 256, 0, stream>>>(featacc, lens, m1w, m1b, m1o);
  k_logits<<<128, 128, 0, stream>>>(m1o, m2w, m2b, out);
}

// Round 9
// 248.146 us; speedup vs baseline: 7.1235x; 1.0241x over previous
//
#include <hip/hip_runtime.h>
#include <math.h>

#define T_LEN 215
#define TP    224   // padded T (14 * 16)
#define B_N   128
#define DINP  36
#define D_TR  160
#define HD    40
#define D_FIN 196
#define KPG   864   // 860 padded to mult of 32

typedef __attribute__((ext_vector_type(8))) short short8v;
typedef __attribute__((ext_vector_type(4))) float f32x4;

__device__ __forceinline__ ushort f2bf(float x) {
  union { float f; unsigned u; } c; c.f = x;
  unsigned r = c.u + 0x7fffu + ((c.u >> 16) & 1u);
  return (ushort)(r >> 16);
}
__device__ __forceinline__ float bf2f(ushort h) {
  union { unsigned u; float f; } c; c.u = ((unsigned)h) << 16;
  return c.f;
}

// ---------------- mega-prep: weight converts + zeros + emb + xb16 ----------------
// flat blocks [0,8202): conversions/zeros/emb/obuf-pad; blocks [8202,8330): xb16 per b.
__global__ __launch_bounds__(256) void k_prep(const float* __restrict__ Wv1,
    const float* __restrict__ Wv2, const float* __restrict__ ipw, const float* __restrict__ ow,
    const float* __restrict__ l1w, const float* __restrict__ l2w,
    const float* __restrict__ src, const float* __restrict__ R_u,
    const float* __restrict__ stat, const float* __restrict__ emb_w, const float* __restrict__ emb_b,
    ushort* __restrict__ wv1b, ushort* __restrict__ wv2b, ushort* __restrict__ ipwb,
    ushort* __restrict__ owb, ushort* __restrict__ l1wb, ushort* __restrict__ l2wb,
    float* __restrict__ v2acc, float* __restrict__ featacc, ushort* __restrict__ obuf16,
    ushort* __restrict__ xb16) {
  __shared__ float Ss[T_LEN * DINP];
  if (blockIdx.x >= 8202) {   // ---- xb16 path (one block per b) ----
    const int b = blockIdx.x - 8202, tid = threadIdx.x;
    for (int i = tid; i < T_LEN * DINP; i += 256) {
      int t = i / DINP, j = i - t * DINP;
      Ss[i] = src[((size_t)t * B_N + b) * 72 + j];
    }
    __syncthreads();
    for (int i = tid; i < DINP * T_LEN; i += 256) {
      int ii = i / T_LEN, t = i - ii * T_LEN;
      float v = Ss[t * DINP + ii];
      float4 r = ((const float4*)R_u)[ii];
      ushort4 o;
      o.x = f2bf(fmaxf(v * r.x, 0.f)); o.y = f2bf(fmaxf(v * r.y, 0.f));
      o.z = f2bf(fmaxf(v * r.z, 0.f)); o.w = f2bf(fmaxf(v * r.w, 0.f));
      ushort* row = xb16 + (size_t)(b * DINP + ii) * KPG;
      *(ushort4*)(row + 4 * t) = o;
      if (t == 0) { ushort4 z = {0, 0, 0, 0}; *(ushort4*)(row + 860) = z; }
    }
    return;
  }
  int i = blockIdx.x * 256 + threadIdx.x;
  if (i < 746496) { int n = i / KPG, k = i % KPG;
    wv1b[i] = (n < 860 && k < 860) ? f2bf(Wv1[n * 860 + k]) : (ushort)0; return; }
  i -= 746496;
  if (i < 746496) { int n = i / KPG, k = i % KPG;
    wv2b[i] = (n < 860 && k < 860) ? f2bf(Wv2[n * 860 + k]) : (ushort)0; return; }
  i -= 746496;
  if (i < 153600) { ipwb[i] = f2bf(ipw[i]); return; }
  i -= 153600;
  if (i < 51200)  { owb[i] = f2bf(ow[i]); return; }
  i -= 51200;
  if (i < 40960)  { l1wb[i] = f2bf(l1w[i]); return; }
  i -= 40960;
  if (i < 40960)  { l2wb[i] = f2bf(l2w[i]); return; }
  i -= 40960;
  if (i < 110592) { v2acc[i] = 0.f; return; }
  i -= 110592;
  if (i < 20480)  { int b = i / D_TR, d = i - b * D_TR;   // zero featacc cols < 160
    featacc[b * D_FIN + d] = 0.f; return; }
  i -= 20480;
  if (i < 4608)   { int b = i / DINP, ii = i - b * DINP;  // emb -> featacc cols 160..195
    float s = emb_b[ii];
    #pragma unroll
    for (int k = 0; k < 9; k++) s = fmaf(stat[b * 9 + k], emb_w[ii * 9 + k], s);
    featacc[b * D_FIN + D_TR + ii] = s; return; }
  i -= 4608;
  if (i < 184320) {  // zero obuf16 pad rows t in [215,224)
    int b = i / 1440, rem = i % 1440;
    int t = 215 + rem / 160, cc = rem % 160;
    obuf16[((size_t)b * TP + t) * D_TR + cc] = 0; return;
  }
}

// s1_16[b,n] = bf16( (1/36) sum_i V1b[b*36+i, n] ), stride KPG, zero-pad
__global__ __launch_bounds__(256) void k_red_s1(const ushort* __restrict__ V1b, ushort* __restrict__ s1) {
  int idx = blockIdx.x * 256 + threadIdx.x;
  if (idx >= B_N * KPG) return;
  int b = idx / KPG, n = idx % KPG;
  float s = 0.f;
  if (n < 860) {
    #pragma unroll 4
    for (int i = 0; i < DINP; i++) s += bf2f(V1b[((size_t)b * DINP + i) * 860 + n]);
    s *= (1.0f / 36.0f);
  }
  s1[idx] = (n < 860) ? f2bf(s) : (ushort)0;
}

// x16[b,t,*] (b-major) from relu(v2acc + bv2) and inline pe; pad rows zeroed
__global__ __launch_bounds__(256) void k_buildx(const float* __restrict__ v2acc,
    const float* __restrict__ bv2, const float* __restrict__ times,
    ushort* __restrict__ x16) {
  int idx = blockIdx.x * 256 + threadIdx.x;
  if (idx >= B_N * TP * 40) return;
  int c = idx % 40;
  int r = idx / 40;            // r = b*224 + t
  int t = r % TP, b = r / TP;
  float4 f = {0.f, 0.f, 0.f, 0.f};
  if (t < T_LEN) {
    if (c < 36) {
      float4 a = *(const float4*)&v2acc[(size_t)b * KPG + 4 * t];
      float4 bb = *(const float4*)&bv2[4 * t];
      f.x = fmaxf(a.x + bb.x, 0.f); f.y = fmaxf(a.y + bb.y, 0.f);
      f.z = fmaxf(a.z + bb.z, 0.f); f.w = fmaxf(a.w + bb.w, 0.f);
    } else {
      float tm = times[t * B_N + b];
      int j0 = (c - 36) * 4;
      bool is_sin = j0 < 8;
      int kb = j0 & 7;
      float o[4];
      #pragma unroll
      for (int qq = 0; qq < 4; qq++) {
        float ts = expf((float)(kb + qq) * 0.76723400f);  // 215^(k/7)
        float sc = tm / ts;
        o[qq] = is_sin ? sinf(sc) : cosf(sc);
      }
      f.x = o[0]; f.y = o[1]; f.z = o[2]; f.w = o[3];
    }
  }
  ushort4 h = {f2bf(f.x), f2bf(f.y), f2bf(f.z), f2bf(f.w)};
  *(ushort4*)(x16 + (size_t)r * D_TR + 4 * c) = h;
}

// ---------------- bf16 MFMA GEMM: C = act(A[M,KP] @ W[N,KP]^T + bias), BN templated ----------------
template <int RELU, int SPLIT, int WMODE, int BNT>
__global__ __launch_bounds__(256) void gemm_bf16(const ushort* __restrict__ A,
    const ushort* __restrict__ W, const float* __restrict__ bias, void* __restrict__ Cv,
    int KP, int ldc, int ncols, int kts) {
  __shared__ ushort As[128 * 32];
  __shared__ ushort Ws[BNT * 32];
  constexpr int NJ = BNT / 16;
  const int tid = threadIdx.x;
  const int wave = tid >> 6, lane = tid & 63;
  const int lr = lane & 15, hi = lane >> 4;
  const int m0 = blockIdx.y * 128, n0 = blockIdx.x * BNT;
  const int kt0 = blockIdx.z * kts;

  f32x4 acc[2][NJ];
  #pragma unroll
  for (int i = 0; i < 2; i++)
    #pragma unroll
    for (int j = 0; j < NJ; j++) acc[i][j] = (f32x4){0.f, 0.f, 0.f, 0.f};

  const int ar = tid >> 2, g = tid & 3;
  const size_t abase0 = (size_t)(m0 + ar) * KP;
  const size_t abase1 = (size_t)(m0 + ar + 64) * KP;
  const size_t bbase0 = (size_t)(n0 + ar) * KP;
  const size_t bbase1 = (size_t)(n0 + ar + 64) * KP;
  const int awb0 = ar * 64 + ((g * 16) ^ ((ar & 3) << 4));
  const int awb1 = awb0 + 64 * 64;

  const int arow0 = wave * 32 + lr;
  const int arb0 = arow0 * 64 + ((hi * 16) ^ ((arow0 & 3) << 4));
  const int arb1 = (arow0 + 16) * 64 + ((hi * 16) ^ (((arow0 + 16) & 3) << 4));
  int brb[NJ];
  #pragma unroll
  for (int j = 0; j < NJ; j++)
    brb[j] = (j * 16 + lr) * 64 + ((hi * 16) ^ ((lr & 3) << 4));

  for (int kt = 0; kt < kts; ++kt) {
    const int k0 = (kt0 + kt) * 32;
    uint4 va0 = *(const uint4*)(A + abase0 + k0 + g * 8);
    uint4 va1 = *(const uint4*)(A + abase1 + k0 + g * 8);
    uint4 vb0 = *(const uint4*)(W + bbase0 + k0 + g * 8);
    uint4 vb1;
    if constexpr (BNT == 128) vb1 = *(const uint4*)(W + bbase1 + k0 + g * 8);
    if (kt) __syncthreads();
    *(uint4*)((char*)As + awb0) = va0;
    *(uint4*)((char*)As + awb1) = va1;
    *(uint4*)((char*)Ws + awb0) = vb0;
    if constexpr (BNT == 128) *(uint4*)((char*)Ws + awb1) = vb1;
    __syncthreads();
    short8v a0 = *(const short8v*)((const char*)As + arb0);
    short8v a1 = *(const short8v*)((const char*)As + arb1);
    #pragma unroll
    for (int j = 0; j < NJ; j++) {
      short8v bf = *(const short8v*)((const char*)Ws + brb[j]);
      acc[0][j] = __builtin_amdgcn_mfma_f32_16x16x32_bf16(a0, bf, acc[0][j], 0, 0, 0);
      acc[1][j] = __builtin_amdgcn_mfma_f32_16x16x32_bf16(a1, bf, acc[1][j], 0, 0, 0);
    }
  }

  #pragma unroll
  for (int i = 0; i < 2; i++) {
    #pragma unroll
    for (int j = 0; j < NJ; j++) {
      int col = n0 + j * 16 + lr;
      int row = m0 + wave * 32 + i * 16 + hi * 4;
      if (col < ncols) {
        if (SPLIT) {
          #pragma unroll
          for (int r = 0; r < 4; r++)
            atomicAdd((float*)Cv + (size_t)(row + r) * ldc + col, acc[i][j][r]);
        } else {
          float bb = bias ? bias[col] : 0.f;
          #pragma unroll
          for (int r = 0; r < 4; r++) {
            float xv = acc[i][j][r] + bb;
            if (RELU) xv = fmaxf(xv, 0.f);
            if (WMODE == 0) ((float*)Cv)[(size_t)(row + r) * ldc + col] = xv;
            else            ((ushort*)Cv)[(size_t)(row + r) * ldc + col] = f2bf(xv);
          }
        }
      }
    }
  }
}

// ---------------- qkv GEMM (BN=128): writes Q,K to qkvB[b-major][480]; V transposed to Vt ----------------
__global__ __launch_bounds__(256) void gemm_qkv(const ushort* __restrict__ A,
    const ushort* __restrict__ W, const float* __restrict__ bias,
    ushort* __restrict__ qkvB, ushort* __restrict__ Vt, int kts) {
  __shared__ ushort As[128 * 32];
  __shared__ ushort Ws[128 * 32];
  const int KP = 160;
  const int tid = threadIdx.x;
  const int wave = tid >> 6, lane = tid & 63;
  const int lr = lane & 15, hi = lane >> 4;
  const int m0 = blockIdx.y * 128, n0 = blockIdx.x * 128;

  f32x4 acc[2][8];
  #pragma unroll
  for (int i = 0; i < 2; i++)
    #pragma unroll
    for (int j = 0; j < 8; j++) acc[i][j] = (f32x4){0.f, 0.f, 0.f, 0.f};

  const int ar = tid >> 2, g = tid & 3;
  const size_t abase0 = (size_t)(m0 + ar) * KP;
  const size_t abase1 = (size_t)(m0 + ar + 64) * KP;
  const size_t bbase0 = (size_t)(n0 + ar) * KP;
  const size_t bbase1 = (size_t)(n0 + ar + 64) * KP;
  const int awb0 = ar * 64 + ((g * 16) ^ ((ar & 3) << 4));
  const int awb1 = awb0 + 64 * 64;

  const int arow0 = wave * 32 + lr;
  const int arb0 = arow0 * 64 + ((hi * 16) ^ ((arow0 & 3) << 4));
  const int arb1 = (arow0 + 16) * 64 + ((hi * 16) ^ (((arow0 + 16) & 3) << 4));
  int brb[8];
  #pragma unroll
  for (int j = 0; j < 8; j++)
    brb[j] = (j * 16 + lr) * 64 + ((hi * 16) ^ ((lr & 3) << 4));

  for (int kt = 0; kt < kts; ++kt) {
    const int k0 = kt * 32;
    uint4 va0 = *(const uint4*)(A + abase0 + k0 + g * 8);
    uint4 va1 = *(const uint4*)(A + abase1 + k0 + g * 8);
    uint4 vb0 = *(const uint4*)(W + bbase0 + k0 + g * 8);
    uint4 vb1 = *(const uint4*)(W + bbase1 + k0 + g * 8);
    if (kt) __syncthreads();
    *(uint4*)((char*)As + awb0) = va0;
    *(uint4*)((char*)As + awb1) = va1;
    *(uint4*)((char*)Ws + awb0) = vb0;
    *(uint4*)((char*)Ws + awb1) = vb1;
    __syncthreads();
    short8v a0 = *(const short8v*)((const char*)As + arb0);
    short8v a1 = *(const short8v*)((const char*)As + arb1);
    #pragma unroll
    for (int j = 0; j < 8; j++) {
      short8v bf = *(const short8v*)((const char*)Ws + brb[j]);
      acc[0][j] = __builtin_amdgcn_mfma_f32_16x16x32_bf16(a0, bf, acc[0][j], 0, 0, 0);
      acc[1][j] = __builtin_amdgcn_mfma_f32_16x16x32_bf16(a1, bf, acc[1][j], 0, 0, 0);
    }
  }

  #pragma unroll
  for (int i = 0; i < 2; i++) {
    const int row = m0 + wave * 32 + i * 16 + hi * 4;   // = b*224 + t0 (4 consecutive t)
    const int b = row / TP, t0 = row - b * TP;
    #pragma unroll
    for (int j = 0; j < 8; j++) {
      int col = n0 + j * 16 + lr;
      if (col < 320) {               // Q or K
        float bb = bias[col];
        #pragma unroll
        for (int r = 0; r < 4; r++)
          qkvB[(size_t)(row + r) * 480 + col] = f2bf(acc[i][j][r] + bb);
      } else if (col < 480) {        // V: transposed packed store
        float bb = bias[col];
        int dg = col - 320;
        int hh = dg / 40, dd = dg - hh * 40;
        ushort4 pv;
        pv.x = f2bf(acc[i][j][0] + bb); pv.y = f2bf(acc[i][j][1] + bb);
        pv.z = f2bf(acc[i][j][2] + bb); pv.w = f2bf(acc[i][j][3] + bb);
        *(ushort4*)(Vt + (((size_t)(b * 4 + hh) * 48 + dd) * TP + t0)) = pv;
      }
    }
  }
}

// ---------------- fused GEMM(N=160) + bias + bf16 residual + LayerNorm ----------------
// featacc == nullptr: write LN output to x16. featacc != nullptr (final stage):
// no writes, masked-sum LN outputs into featacc via atomics.
__global__ __launch_bounds__(256) void gemm_ln(const ushort* __restrict__ A,
    const ushort* __restrict__ W, const float* __restrict__ bias,
    const float* __restrict__ gam, const float* __restrict__ bet,
    ushort* __restrict__ x16, int KP, int kts,
    const int* __restrict__ lengths, float* __restrict__ featacc) {
  __shared__ ushort As[64 * 32];
  __shared__ ushort Ws[160 * 32];
  const int tid = threadIdx.x;
  const int wave = tid >> 6, lane = tid & 63;
  const int lr = lane & 15, hi = lane >> 4;
  const int m0 = blockIdx.x * 64;

  f32x4 acc[10];
  #pragma unroll
  for (int j = 0; j < 10; j++) acc[j] = (f32x4){0.f, 0.f, 0.f, 0.f};

  const int ar = tid >> 2, g = tid & 3;
  const size_t abase = (size_t)(m0 + ar) * KP;
  const int awb = ar * 64 + ((g * 16) ^ ((ar & 3) << 4));
  const int wr0 = tid >> 2,         ws0 = tid & 3;
  const int wr1 = (tid + 256) >> 2, ws1 = (tid + 256) & 3;
  const int wr2 = (tid + 512) >> 2, ws2 = (tid + 512) & 3;
  const int wwb0 = wr0 * 64 + ((ws0 * 16) ^ ((wr0 & 3) << 4));
  const int wwb1 = wr1 * 64 + ((ws1 * 16) ^ ((wr1 & 3) << 4));
  const int wwb2 = wr2 * 64 + ((ws2 * 16) ^ ((wr2 & 3) << 4));

  const int arow = wave * 16 + lr;
  const int arb = arow * 64 + ((hi * 16) ^ ((arow & 3) << 4));
  int brb[10];
  #pragma unroll
  for (int j = 0; j < 10; j++)
    brb[j] = (j * 16 + lr) * 64 + ((hi * 16) ^ ((lr & 3) << 4));

  for (int kt = 0; kt < kts; ++kt) {
    const int k0 = kt * 32;
    uint4 va = *(const uint4*)(A + abase + k0 + g * 8);
    uint4 w0 = *(const uint4*)(W + (size_t)wr0 * KP + k0 + ws0 * 8);
    uint4 w1 = *(const uint4*)(W + (size_t)wr1 * KP + k0 + ws1 * 8);
    uint4 w2;
    if (tid < 128) w2 = *(const uint4*)(W + (size_t)wr2 * KP + k0 + ws2 * 8);
    if (kt) __syncthreads();
    *(uint4*)((char*)As + awb) = va;
    *(uint4*)((char*)Ws + wwb0) = w0;
    *(uint4*)((char*)Ws + wwb1) = w1;
    if (tid < 128) *(uint4*)((char*)Ws + wwb2) = w2;
    __syncthreads();
    short8v a0 = *(const short8v*)((const char*)As + arb);
    #pragma unroll
    for (int j = 0; j < 10; j++) {
      short8v bf = *(const short8v*)((const char*)Ws + brb[j]);
      acc[j] = __builtin_amdgcn_mfma_f32_16x16x32_bf16(a0, bf, acc[j], 0, 0, 0);
    }
  }

  const int rb = m0 + wave * 16 + hi * 4;
  float s[4] = {0.f, 0.f, 0.f, 0.f};
  #pragma unroll
  for (int j = 0; j < 10; j++) {
    const int col = j * 16 + lr;
    const float bb = bias[col];
    #pragma unroll
    for (int r = 0; r < 4; r++) {
      float v = acc[j][r] + bb + bf2f(x16[(size_t)(rb + r) * D_TR + col]);
      acc[j][r] = v;
      s[r] += v;
    }
  }
  #pragma unroll
  for (int r = 0; r < 4; r++) {
    s[r] += __shfl_xor(s[r], 1, 64);
    s[r] += __shfl_xor(s[r], 2, 64);
    s[r] += __shfl_xor(s[r], 4, 64);
    s[r] += __shfl_xor(s[r], 8, 64);
  }
  float mu[4], q2[4] = {0.f, 0.f, 0.f, 0.f};
  #pragma unroll
  for (int r = 0; r < 4; r++) mu[r] = s[r] * (1.0f / 160.0f);
  #pragma unroll
  for (int j = 0; j < 10; j++)
    #pragma unroll
    for (int r = 0; r < 4; r++) {
      float d = acc[j][r] - mu[r];
      q2[r] += d * d;
    }
  #pragma unroll
  for (int r = 0; r < 4; r++) {
    q2[r] += __shfl_xor(q2[r], 1, 64);
    q2[r] += __shfl_xor(q2[r], 2, 64);
    q2[r] += __shfl_xor(q2[r], 4, 64);
    q2[r] += __shfl_xor(q2[r], 8, 64);
  }
  float rstd[4];
  #pragma unroll
  for (int r = 0; r < 4; r++) rstd[r] = rsqrtf(q2[r] * (1.0f / 160.0f) + 1e-5f);

  if (featacc == nullptr) {
    #pragma unroll
    for (int j = 0; j < 10; j++) {
      const int col = j * 16 + lr;
      const float gc = gam[col], bc = bet[col];
      #pragma unroll
      for (int r = 0; r < 4; r++) {
        float o = (acc[j][r] - mu[r]) * rstd[r] * gc + bc;
        x16[(size_t)(rb + r) * D_TR + col] = f2bf(o);
      }
    }
  } else {
    const int b = rb / TP, t0 = rb - b * TP;
    int L = lengths[b]; if (L > T_LEN) L = T_LEN;
    #pragma unroll
    for (int j = 0; j < 10; j++) {
      const int col = j * 16 + lr;
      const float gc = gam[col], bc = bet[col];
      float sacc = 0.f;
      #pragma unroll
      for (int r = 0; r < 4; r++) {
        float o = (acc[j][r] - mu[r]) * rstd[r] * gc + bc;
        if (t0 + r < L) sacc += o;
      }
      if (t0 < L) atomicAdd(&featacc[b * D_FIN + col], sacc);
    }
  }
}

// ---------------- barrier-free 1-wave flash attention (b-major qkv + Vt) ----------------
__global__ __launch_bounds__(64) void k_attn4(const ushort* __restrict__ qkvB,
    const ushort* __restrict__ Vt, const int* __restrict__ lengths,
    ushort* __restrict__ o16) {
  __shared__ ushort SP[16 * 232];
  const int bh = blockIdx.x;
  const int b = bh >> 2, h = bh & 3;
  int L = lengths[b]; if (L > T_LEN) L = T_LEN;
  const int q0 = blockIdx.y << 4;
  if (q0 >= L) return;
  const int lane = threadIdx.x;
  const int lr = lane & 15, hi = lane >> 4;
  const int nk16 = (L + 15) >> 4;
  const int nkt  = (L + 31) >> 5;
  const float SC = 0.15811388300841898f;  // 1/sqrt(40)

  const ushort* qrow = qkvB + ((size_t)b * TP + q0) * 480 + h * 40;
  uint4 qa0u = *(const uint4*)(qrow + lr * 480 + hi * 8);
  uint4 qa1u = {0, 0, 0, 0};
  if (hi == 0) qa1u = *(const uint4*)(qrow + lr * 480 + 32);
  short8v qa0 = *(short8v*)&qa0u;
  short8v qa1 = *(short8v*)&qa1u;

  f32x4 c[14];
  #pragma unroll
  for (int kt = 0; kt < 14; ++kt) {
    c[kt] = (f32x4){0.f, 0.f, 0.f, 0.f};
    if (kt < nk16) {
      const ushort* krow = qkvB + ((size_t)b * TP + kt * 16) * 480 + 160 + h * 40;
      uint4 kb0u = *(const uint4*)(krow + lr * 480 + hi * 8);
      uint4 kb1u = {0, 0, 0, 0};
      if (hi == 0) kb1u = *(const uint4*)(krow + lr * 480 + 32);
      c[kt] = __builtin_amdgcn_mfma_f32_16x16x32_bf16(qa0, *(short8v*)&kb0u, c[kt], 0, 0, 0);
      c[kt] = __builtin_amdgcn_mfma_f32_16x16x32_bf16(qa1, *(short8v*)&kb1u, c[kt], 0, 0, 0);
    }
  }

  float mx[4] = {-1e30f, -1e30f, -1e30f, -1e30f};
  #pragma unroll
  for (int kt = 0; kt < 14; ++kt) {
    if (kt < nk16) {
      bool valid = (kt * 16 + lr) < L;
      #pragma unroll
      for (int r = 0; r < 4; r++) {
        float v = valid ? c[kt][r] : -1e30f;
        mx[r] = fmaxf(mx[r], v);
      }
    }
  }
  #pragma unroll
  for (int r = 0; r < 4; r++) {
    mx[r] = fmaxf(mx[r], __shfl_xor(mx[r], 1, 64));
    mx[r] = fmaxf(mx[r], __shfl_xor(mx[r], 2, 64));
    mx[r] = fmaxf(mx[r], __shfl_xor(mx[r], 4, 64));
    mx[r] = fmaxf(mx[r], __shfl_xor(mx[r], 8, 64));
  }
  float sum[4] = {0.f, 0.f, 0.f, 0.f};
  #pragma unroll
  for (int kt = 0; kt < 14; ++kt) {
    if (kt < nk16) {
      bool valid = (kt * 16 + lr) < L;
      #pragma unroll
      for (int r = 0; r < 4; r++) {
        float p = valid ? __expf(SC * (c[kt][r] - mx[r])) : 0.f;
        sum[r] += p;
        c[kt][r] = p;
      }
    }
  }
  #pragma unroll
  for (int r = 0; r < 4; r++) {
    sum[r] += __shfl_xor(sum[r], 1, 64);
    sum[r] += __shfl_xor(sum[r], 2, 64);
    sum[r] += __shfl_xor(sum[r], 4, 64);
    sum[r] += __shfl_xor(sum[r], 8, 64);
  }

  const int nk16w = nkt * 2;
  #pragma unroll
  for (int kt = 0; kt < 14; ++kt) {
    if (kt < nk16w) {
      #pragma unroll
      for (int r = 0; r < 4; r++)
        SP[(hi * 4 + r) * 232 + kt * 16 + lr] = f2bf(c[kt][r]);
    }
  }
  __syncthreads();

  f32x4 o0 = {0.f, 0.f, 0.f, 0.f}, o1 = o0, o2 = o0;
  const ushort* vbase = Vt + (size_t)bh * 48 * TP;
  #pragma unroll
  for (int kt = 0; kt < 7; ++kt) {
    if (kt < nkt) {
      short8v pa = *(const short8v*)((const char*)SP + lr * 464 + kt * 64 + hi * 16);
      const ushort* vb = vbase + kt * 32 + hi * 8;
      short8v v0 = *(const short8v*)(vb + (size_t)lr * TP);
      short8v v1 = *(const short8v*)(vb + (size_t)(16 + lr) * TP);
      short8v v2 = *(const short8v*)(vb + (size_t)(32 + lr) * TP);
      o0 = __builtin_amdgcn_mfma_f32_16x16x32_bf16(pa, v0, o0, 0, 0, 0);
      o1 = __builtin_amdgcn_mfma_f32_16x16x32_bf16(pa, v1, o1, 0, 0, 0);
      o2 = __builtin_amdgcn_mfma_f32_16x16x32_bf16(pa, v2, o2, 0, 0, 0);
    }
  }

  #pragma unroll
  for (int r = 0; r < 4; r++) {
    int t = q0 + hi * 4 + r;
    if (t < T_LEN) {
      float inv = 1.0f / sum[r];
      ushort* op = o16 + ((size_t)b * TP + t) * D_TR + h * 40;
      op[lr]      = f2bf(o0[r] * inv);
      op[16 + lr] = f2bf(o1[r] * inv);
      if (lr < 8) op[32 + lr] = f2bf(o2[r] * inv);
    }
  }
}

// ---------------- head: (feat scale) -> mlp1 -> logits, one block per b ----------------
__global__ __launch_bounds__(256) void k_head2(const float* __restrict__ featacc,
    const int* __restrict__ lengths, const float* __restrict__ m1w,
    const float* __restrict__ m1b, const float* __restrict__ m2w,
    const float* __restrict__ m2b, float* __restrict__ out) {
  __shared__ float feat[196];
  __shared__ float m1o_s[196];
  __shared__ float r0[4], r1[4];
  const int b = blockIdx.x, tid = threadIdx.x;
  int L = lengths[b]; if (L > T_LEN) L = T_LEN;
  const float inv = 1.0f / (float)(L + 1);
  if (tid < D_FIN)
    feat[tid] = featacc[(size_t)b * D_FIN + tid] * (tid < D_TR ? inv : 1.f);
  __syncthreads();
  if (tid < D_FIN) {
    float s = m1b[tid];
    const float* wr = m1w + (size_t)tid * D_FIN;
    #pragma unroll 4
    for (int k = 0; k < D_FIN; k++) s = fmaf(feat[k], wr[k], s);
    m1o_s[tid] = fmaxf(s, 0.f);
  }
  __syncthreads();
  float p0 = 0.f, p1 = 0.f;
  if (tid < D_FIN) {
    p0 = m1o_s[tid] * m2w[tid];
    p1 = m1o_s[tid] * m2w[D_FIN + tid];
  }
  #pragma unroll
  for (int off = 32; off; off >>= 1) {
    p0 += __shfl_xor(p0, off, 64);
    p1 += __shfl_xor(p1, off, 64);
  }
  int w = tid >> 6;
  if ((tid & 63) == 0) { r0[w] = p0; r1[w] = p1; }
  __syncthreads();
  if (tid == 0) out[2 * b]     = r0[0] + r0[1] + r0[2] + r0[3] + m2b[0];
  if (tid == 1) out[2 * b + 1] = r1[0] + r1[1] + r1[2] + r1[3] + m2b[1];
  if (b == 0 && tid == 2) out[256] = 0.f;  // distance == 0 exactly
}

// ---------------- launch ----------------
extern "C" void kernel_launch(void* const* d_in, const int* in_sizes, int n_in,
                              void* d_out, int out_size, void* d_ws, size_t ws_size,
                              hipStream_t stream) {
  const float* src   = (const float*)d_in[0];
  const float* stat  = (const float*)d_in[1];
  const float* times = (const float*)d_in[2];
  const int*   lens  = (const int*)d_in[3];
  const float* R_u   = (const float*)d_in[4];
  const float* emb_w = (const float*)d_in[5];
  const float* emb_b = (const float*)d_in[6];
  const float* Wv1   = (const float*)d_in[7];
  const float* bv1   = (const float*)d_in[8];
  const float* Wv2   = (const float*)d_in[9];
  const float* bv2   = (const float*)d_in[10];
  const float* ipw   = (const float*)d_in[11];
  const float* ipb   = (const float*)d_in[12];
  const float* ow    = (const float*)d_in[13];
  const float* ob    = (const float*)d_in[14];
  const float* l1w   = (const float*)d_in[15];
  const float* l1b   = (const float*)d_in[16];
  const float* l2w   = (const float*)d_in[17];
  const float* l2b   = (const float*)d_in[18];
  const float* ln1s  = (const float*)d_in[19];
  const float* ln1bb = (const float*)d_in[20];
  const float* ln2s  = (const float*)d_in[21];
  const float* ln2bb = (const float*)d_in[22];
  const float* m1w   = (const float*)d_in[23];
  const float* m1b   = (const float*)d_in[24];
  const float* m2w   = (const float*)d_in[25];
  const float* m2b   = (const float*)d_in[26];
  float* out = (float*)d_out;

  // ---- workspace layout (bytes) ----
  char* p = (char*)d_ws;
  ushort* x16    = (ushort*)p;  p += 9175040;   // 28672 x 160 bf16 (b-major)
  float*  v2acc  = (float*)p;   p += 442368;    // 128 x 864 fp32
  ushort* s1b    = (ushort*)p;  p += 221184;    // 128 x 864 bf16
  ushort* obuf16 = (ushort*)p;  p += 9175040;   // 28672 x 160 bf16 (b-major)
  ushort* wv1b   = (ushort*)p;  p += 1492992;   // 864 x 864 bf16
  ushort* wv2b   = (ushort*)p;  p += 1492992;
  ushort* ipwb   = (ushort*)p;  p += 307200;    // 2 x 480 x 160
  ushort* owb    = (ushort*)p;  p += 102400;    // 2 x 160 x 160
  ushort* l1wb   = (ushort*)p;  p += 81920;     // 2 x 128 x 160
  ushort* l2wb   = (ushort*)p;  p += 81920;     // 2 x 160 x 128
  float*  featacc= (float*)p;   p += 100352;    // 128 x 196 fp32
  char*   R2     = p;
  ushort* xb16   = (ushort*)R2;                  // phase A: 4608 x 864 bf16 (7.96 MB)
  ushort* V1b    = (ushort*)(R2 + 7962624);      // phase A: 4608 x 860 bf16 (7.93 MB)
  ushort* qkvB   = (ushort*)R2;                  // phase B: 128 x 224 x 480 bf16 (27.5 MB)
  ushort* ffb16  = (ushort*)R2;                  // aliases qkvB (dead after attention)
  ushort* Vt     = (ushort*)(R2 + 27525120);     // 512 x 48 x 224 bf16 (11 MB)

  k_prep<<<8330, 256, 0, stream>>>(Wv1, Wv2, ipw, ow, l1w, l2w, src, R_u,
                                   stat, emb_w, emb_b,
                                   wv1b, wv2b, ipwb, owb, l1wb, l2wb,
                                   v2acc, featacc, obuf16, xb16);

  // V1b = bf16(relu(xb @ Wv1^T + bv1)), BN=128
  gemm_bf16<1, 0, 1, 128><<<dim3(7, 36, 1), 256, 0, stream>>>(
      xb16, wv1b, bv1, V1b, KPG, 860, 860, 27);
  k_red_s1<<<432, 256, 0, stream>>>(V1b, s1b);
  gemm_bf16<0, 1, 0, 64><<<dim3(14, 1, 9), 256, 0, stream>>>(
      s1b, wv2b, nullptr, v2acc, KPG, KPG, KPG, 3);
  k_buildx<<<4480, 256, 0, stream>>>(v2acc, bv2, times, x16);

  for (int l = 0; l < 2; l++) {
    gemm_qkv<<<dim3(4, 224, 1), 256, 0, stream>>>(
        x16, ipwb + (size_t)l * 76800, ipb + l * 480, qkvB, Vt, 5);
    k_attn4<<<dim3(512, 14), 64, 0, stream>>>(qkvB, Vt, lens, obuf16);
    gemm_ln<<<448, 256, 0, stream>>>(obuf16, owb + (size_t)l * 25600, ob + l * 160,
                                     ln1s + l * 160, ln1bb + l * 160, x16, 160, 5,
                                     lens, nullptr);
    gemm_bf16<1, 0, 1, 64><<<dim3(2, 224, 1), 256, 0, stream>>>(
        x16, l1wb + (size_t)l * 20480, l1b + l * 128, ffb16, 160, 128, 128, 5);
    gemm_ln<<<448, 256, 0, stream>>>(ffb16, l2wb + (size_t)l * 20480, l2b + l * 160,
                                     ln2s + l * 160, ln2bb + l * 160, x16, 128, 4,
                                     lens, (l == 1) ? featacc : nullptr);
  }

  k_head2<<<128, 256, 0, stream>>>(featacc, lens, m1w, m1b, m2w, m2b, out);
}